// Round 12
// baseline (2756.063 us; speedup 1.0000x reference)
//
#include <hip/hip_runtime.h>
#include <math.h>

#define B_ 2
#define L_ 4096
#define D_ 1024
#define H_ 4
#define DH 256
#define CHUNKSZ 32
#define NCH (L_/CHUNKSZ)      // 128
#define BL (B_*L_)            // 8192
#define BLD (B_*L_*D_)        // 8388608

typedef __attribute__((ext_vector_type(8))) short bf16x8;
typedef __attribute__((ext_vector_type(4))) float f32x4;

__device__ __forceinline__ float sigmf(float x) { return 1.f / (1.f + expf(-x)); }
__device__ __forceinline__ float geluf(float x) { return 0.5f * x * (1.f + erff(x * 0.70710678118654752f)); }
__device__ __forceinline__ unsigned short f2bf(float f) {
  unsigned int u = __float_as_uint(f);
  unsigned int r = (u + 0x7FFFu + ((u >> 16) & 1u)) >> 16;
  return (unsigned short)r;
}
__device__ __forceinline__ unsigned int pk2bf(float a, float b) {
  return ((unsigned int)f2bf(b) << 16) | (unsigned int)f2bf(a);
}

// ---------------- f32 -> bf16 elementwise (n multiple of 4) ----------------
__global__ __launch_bounds__(256)
void cvt_bf16(const float* __restrict__ x, unsigned short* __restrict__ y, long n) {
  long i = ((long)blockIdx.x * 256 + threadIdx.x) * 4;
  if (i >= n) return;
  float4 v = *reinterpret_cast<const float4*>(&x[i]);
  ushort4 o;
  o.x = f2bf(v.x); o.y = f2bf(v.y); o.z = f2bf(v.z); o.w = f2bf(v.w);
  *reinterpret_cast<ushort4*>(&y[i]) = o;
}

// ---------------- W[k][n] f32 -> Wt[n][k] bf16 (32x32 tiles) ----------------
__global__ __launch_bounds__(256)
void wconv_t(const float* __restrict__ W, unsigned short* __restrict__ Wt, int N) {
  __shared__ float tile[32][33];
  int kb = blockIdx.y * 32, nb = blockIdx.x * 32;
  int tx = threadIdx.x & 31, ty = threadIdx.x >> 5;
  for (int i = 0; i < 32; i += 8)
    tile[ty + i][tx] = W[(long)(kb + ty + i) * N + nb + tx];
  __syncthreads();
  for (int i = 0; i < 32; i += 8)
    Wt[(long)(nb + ty + i) * 1024 + kb + tx] = f2bf(tile[tx][ty + i]);
}

// ---------------- bf16 MFMA GEMM: C[8192][N] = A[8192][1024] @ Bt[N][1024]^T ----------------
__global__ __launch_bounds__(256)
void gemm_bf16(const unsigned short* __restrict__ A, const unsigned short* __restrict__ Bt,
               float* __restrict__ C, int N) {
  __shared__ unsigned short Al[128 * 32];
  __shared__ unsigned short Bl[128 * 32];
  const int K = 1024;
  int bm = blockIdx.y * 128, bn = blockIdx.x * 128;
  int tid = threadIdx.x;
  int lane = tid & 63, wid = tid >> 6;
  int wr = wid >> 1, wc = wid & 1;
  int l15 = lane & 15, l4 = lane >> 4;
  f32x4 acc[4][4];
#pragma unroll
  for (int i = 0; i < 4; ++i)
#pragma unroll
    for (int j = 0; j < 4; ++j) { acc[i][j].x = 0.f; acc[i][j].y = 0.f; acc[i][j].z = 0.f; acc[i][j].w = 0.f; }
  for (int k0 = 0; k0 < K; k0 += 32) {
    __syncthreads();
#pragma unroll
    for (int i = 0; i < 2; ++i) {
      int idx = tid + i * 256;
      int r = idx >> 2, sl = idx & 3;
      int src = sl ^ ((r >> 1) & 3);
      __builtin_amdgcn_global_load_lds(
          (const __attribute__((address_space(1))) unsigned int*)&A[(long)(bm + r) * K + k0 + src * 8],
          (__attribute__((address_space(3))) unsigned int*)&Al[idx * 8], 16, 0, 0);
      __builtin_amdgcn_global_load_lds(
          (const __attribute__((address_space(1))) unsigned int*)&Bt[(long)(bn + r) * K + k0 + src * 8],
          (__attribute__((address_space(3))) unsigned int*)&Bl[idx * 8], 16, 0, 0);
    }
    __syncthreads();
    bf16x8 af[4], bfr[4];
#pragma unroll
    for (int fi = 0; fi < 4; ++fi) {
      int r = wr * 64 + fi * 16 + l15;
      af[fi] = *reinterpret_cast<const bf16x8*>(&Al[r * 32 + (l4 ^ ((r >> 1) & 3)) * 8]);
    }
#pragma unroll
    for (int fj = 0; fj < 4; ++fj) {
      int r = wc * 64 + fj * 16 + l15;
      bfr[fj] = *reinterpret_cast<const bf16x8*>(&Bl[r * 32 + (l4 ^ ((r >> 1) & 3)) * 8]);
    }
#pragma unroll
    for (int fi = 0; fi < 4; ++fi)
#pragma unroll
      for (int fj = 0; fj < 4; ++fj)
        acc[fi][fj] = __builtin_amdgcn_mfma_f32_16x16x32_bf16(af[fi], bfr[fj], acc[fi][fj], 0, 0, 0);
  }
#pragma unroll
  for (int fi = 0; fi < 4; ++fi) {
    int rb = bm + wr * 64 + fi * 16 + l4 * 4;
#pragma unroll
    for (int fj = 0; fj < 4; ++fj) {
      int cb = bn + wc * 64 + fj * 16 + l15;
#pragma unroll
      for (int j = 0; j < 4; ++j)
        C[(long)(rb + j) * N + cb] = acc[fi][fj][j];
    }
  }
}

// ---------------- tiled depthwise causal conv, sliding-window (8 consecutive outputs/group) ----------------
#define CTL 128
template<int K>
__global__ __launch_bounds__(256)
void dwconv_tiled(const float* __restrict__ x, const float* __restrict__ w,
                  float* __restrict__ y, int do_silu) {
  __shared__ float tile[(CTL + K - 1) * 64];
  int bid = blockIdx.x;
  int ct = bid & 15;
  int lt = (bid >> 4) & 31;
  int b  = bid >> 9;
  int c0 = ct * 64;
  int l0 = lt * CTL;
  int tid = threadIdx.x;
  const int rows = CTL + K - 1;
  for (int i = tid; i < rows * 16; i += 256) {
    int rr = i >> 4, c4 = i & 15;
    int l = l0 - (K - 1) + rr;
    float4 v = make_float4(0.f, 0.f, 0.f, 0.f);
    if (l >= 0) v = *reinterpret_cast<const float4*>(&x[((long)b * L_ + l) * D_ + c0 + c4 * 4]);
    *reinterpret_cast<float4*>(&tile[rr * 64 + c4 * 4]) = v;
  }
  __syncthreads();
  int c = tid & 63;
  int wv = tid >> 6;
  float wreg[K];
#pragma unroll
  for (int j = 0; j < K; ++j) wreg[j] = w[(long)(c0 + c) * K + j];
#pragma unroll
  for (int g = 0; g < 4; ++g) {
    int lo_base = g * 32 + wv * 8;
    float win[8];
#pragma unroll
    for (int r = 0; r < 8; ++r) win[r] = tile[(lo_base + r) * 64 + c];
    float acc[8] = {0.f, 0.f, 0.f, 0.f, 0.f, 0.f, 0.f, 0.f};
#pragma unroll
    for (int j = 0; j < K; ++j) {
#pragma unroll
      for (int r = 0; r < 8; ++r) acc[r] = fmaf(wreg[j], win[r], acc[r]);
      if (j < K - 1) {
#pragma unroll
        for (int r = 0; r < 7; ++r) win[r] = win[r + 1];
        win[7] = tile[(lo_base + j + 8) * 64 + c];
      }
    }
#pragma unroll
    for (int r = 0; r < 8; ++r) {
      float v = acc[r];
      if (do_silu) v = v * sigmf(v);
      y[((long)b * L_ + l0 + lo_base + r) * D_ + c0 + c] = v;
    }
  }
}

// ---------------- wave-parallel l2norm: 4 rows/block, shuffle reduce ----------------
__global__ __launch_bounds__(256)
void l2norm_wave(float* __restrict__ x) {
  long row = (long)blockIdx.x * 4 + (threadIdx.x >> 6);
  int lane = threadIdx.x & 63;
  float4 v = *reinterpret_cast<const float4*>(&x[row * 256 + lane * 4]);
  float q = v.x * v.x + v.y * v.y + v.z * v.z + v.w * v.w;
#pragma unroll
  for (int st = 32; st > 0; st >>= 1) q += __shfl_xor(q, st);
  float inv = rsqrtf(q + 1e-6f);
  v.x *= inv; v.y *= inv; v.z *= inv; v.w *= inv;
  *reinterpret_cast<float4*>(&x[row * 256 + lane * 4]) = v;
}

// ---------------- fused beta/resg GEMV ----------------
__global__ __launch_bounds__(256)
void beta_res_gemv(const float* __restrict__ hs, const float* __restrict__ Wb,
                   const float* __restrict__ Wres, const float* __restrict__ bres,
                   float* __restrict__ beta, float* __restrict__ resg) {
  long m = blockIdx.x;
  int n = threadIdx.x >> 6, lane = threadIdx.x & 63;
  float ab = 0.f, ar = 0.f;
  for (int k0 = lane * 4; k0 < 1024; k0 += 256) {
    float4 x = *reinterpret_cast<const float4*>(&hs[m * 1024 + k0]);
    ab += x.x * Wb[(k0 + 0) * 4 + n] + x.y * Wb[(k0 + 1) * 4 + n]
        + x.z * Wb[(k0 + 2) * 4 + n] + x.w * Wb[(k0 + 3) * 4 + n];
    ar += x.x * Wres[(k0 + 0) * 4 + n] + x.y * Wres[(k0 + 1) * 4 + n]
        + x.z * Wres[(k0 + 2) * 4 + n] + x.w * Wres[(k0 + 3) * 4 + n];
  }
#pragma unroll
  for (int st = 32; st > 0; st >>= 1) { ab += __shfl_xor(ab, st); ar += __shfl_xor(ar, st); }
  if (lane == 0) {
    beta[m * 4 + n] = sigmf(ab);
    resg[m * 4 + n] = sigmf(ar + bres[n]);
  }
}

// ---------------- per-chunk: inv, u (f32), and bf16 operands for the scan ----------------
__global__ __launch_bounds__(256)
void chunk_uw(const float* __restrict__ qn, const float* __restrict__ kn,
              const float* __restrict__ v, const float* __restrict__ beta,
              float* __restrict__ u,
              unsigned short* __restrict__ q_bf, unsigned short* __restrict__ w_bf,
              unsigned short* __restrict__ kT_bf, unsigned short* __restrict__ at_bf) {
  __shared__ float skT[256][33];
  __shared__ float sinv[32][33];
  __shared__ float sbeta[32];
  int blk = blockIdx.x;
  int ci = blk % NCH;
  int bh = blk / NCH;
  int h = bh % H_;
  int b = bh / H_;
  long base = ((long)b * L_ + (long)ci * CHUNKSZ) * D_ + h * DH;
  long brow = (long)b * L_ + (long)ci * CHUNKSZ;
  long obase = (long)blk * 8192;
  int tid = threadIdx.x;
  for (int i = tid; i < 32 * 256; i += 256) {
    int r = i >> 8, c = i & 255;
    skT[c][r] = kn[base + (long)r * D_ + c];
  }
  if (tid < 32) sbeta[tid] = beta[(brow + tid) * H_ + h];
  __syncthreads();
  for (int i = tid; i < 8192; i += 256)
    kT_bf[obase + i] = f2bf(skT[i >> 5][i & 31]);
  for (int i = tid; i < 8192; i += 256)
    q_bf[obase + i] = f2bf(qn[base + (long)(i >> 8) * D_ + (i & 255)]);
  int j = tid & 31, i0 = tid >> 5;
  for (int r = 0; r < 4; ++r) {
    int i = i0 + (r << 3);
    float acc = 0.f;
    for (int d = 0; d < 256; ++d) acc += skT[d][i] * skT[d][j];
    sinv[i][j] = (i > j) ? -acc * sbeta[i] : 0.f;
  }
  __syncthreads();
  for (int i = 1; i < 32; ++i) {
    float val = 0.f;
    if (tid < 32) {
      for (int t = 0; t < i; ++t) val += sinv[i][t] * sinv[t][tid];
    }
    __syncthreads();
    if (tid < 32) sinv[i][tid] += val;
    __syncthreads();
  }
  if (tid < 32) sinv[tid][tid] += 1.f;
  long abase = (long)blk * 1024;
  for (int r = 0; r < 4; ++r) {
    int i = i0 + (r << 3);
    const float* qrow = qn + base + (long)i * D_;
    float acc = 0.f;
    for (int d = 0; d < 256; ++d) acc += qrow[d] * skT[d][j];
    at_bf[abase + i * 32 + j] = f2bf((i >= j) ? acc : 0.f);
  }
  __syncthreads();
  int c = tid;
  float vt[32], kt[32];
#pragma unroll
  for (int t = 0; t < 32; ++t) {
    vt[t] = v[base + t * D_ + c] * sbeta[t];
    kt[t] = skT[c][t] * sbeta[t];
  }
#pragma unroll
  for (int i2 = 0; i2 < 32; ++i2) {
    float au = 0.f, aw = 0.f;
#pragma unroll
    for (int t = 0; t <= i2; ++t) {
      float f = sinv[i2][t];
      au += f * vt[t];
      aw += f * kt[t];
    }
    u[base + i2 * D_ + c] = au;
    w_bf[obase + i2 * 256 + c] = f2bf(aw);
  }
}

// ---------------- MFMA scan: 16 blocks x 8 waves (2 waves/SIMD co-resident) ----------------
// Each wave = one independent (bh, cg) task: owns 16 cols, full K, S f32 in accumulators,
// private LDS slice. Barrier-free; peeled branch-free prefetch pipeline (1 chunk ahead).
// 2 waves/SIMD -> one wave's memory/MFMA latency hides under the other's compute (m114).
// Block -> bh mapping concentrates shared q/w/kT operand streams per CU for L1/L2 reuse.
// `out` aliases `u` (u reads precede out stores in program order; disjoint cols across waves).
__global__ __launch_bounds__(512, 1)
void delta_scan(const unsigned short* __restrict__ qb, const unsigned short* __restrict__ wbf,
                const unsigned short* __restrict__ ktb, const unsigned short* __restrict__ atb,
                const float* u, float* out) {
  __shared__ unsigned short sB_all[8][16 * 264];   // per-wave S^T staging
  __shared__ unsigned short su2_all[8][16 * 40];   // per-wave u2^T
  int wid = threadIdx.x >> 6;
  int lane = threadIdx.x & 63;
  int bh = blockIdx.x >> 1;                         // 0..7
  int cg = (blockIdx.x & 1) * 8 + wid;              // 0..15
  int h = bh & 3, b = bh >> 2;
  int l15 = lane & 15, l4 = lane >> 4;
  int colw = cg * 16;
  unsigned short* sB = sB_all[wid];
  unsigned short* su2 = su2_all[wid];

  f32x4 zero4; zero4.x = 0.f; zero4.y = 0.f; zero4.z = 0.f; zero4.w = 0.f;
  f32x4 acc[16];
#pragma unroll
  for (int t = 0; t < 16; ++t) acc[t] = zero4;

  uint4 wf[2][8];
  float ru[2][4];
  uint4 qf[2][8];
  uint4 kfa[8], kfb[8];
  uint4 af[2];

#define LOAD_W(CI) do {                                                          \
    long o8_ = ((long)bh * NCH + (CI)) * 8192;                                   \
    _Pragma("unroll")                                                            \
    for (int m_ = 0; m_ < 2; ++m_)                                               \
      _Pragma("unroll")                                                          \
      for (int kc_ = 0; kc_ < 8; ++kc_)                                          \
        wf[m_][kc_] = *reinterpret_cast<const uint4*>(                           \
            &wbf[o8_ + (16 * m_ + l15) * 256 + kc_ * 32 + l4 * 8]);              \
  } while (0)

#define LOAD_U(CI) do {                                                          \
    long ub_ = ((long)b * L_ + (long)(CI) * CHUNKSZ) * D_ + h * DH + colw;       \
    _Pragma("unroll")                                                            \
    for (int m_ = 0; m_ < 2; ++m_)                                               \
      _Pragma("unroll")                                                          \
      for (int r_ = 0; r_ < 4; ++r_)                                             \
        ru[m_][r_] = u[ub_ + (long)(16 * m_ + 4 * l4 + r_) * D_ + l15];          \
  } while (0)

#define LOAD_Q(CI) do {                                                          \
    long o8_ = ((long)bh * NCH + (CI)) * 8192;                                   \
    _Pragma("unroll")                                                            \
    for (int m_ = 0; m_ < 2; ++m_)                                               \
      _Pragma("unroll")                                                          \
      for (int kc_ = 0; kc_ < 8; ++kc_)                                          \
        qf[m_][kc_] = *reinterpret_cast<const uint4*>(                           \
            &qb[o8_ + (16 * m_ + l15) * 256 + kc_ * 32 + l4 * 8]);               \
  } while (0)

#define LOAD_KA(CI) do {                                                         \
    long o8_ = ((long)bh * NCH + (CI)) * 8192;                                   \
    _Pragma("unroll")                                                            \
    for (int dt_ = 0; dt_ < 8; ++dt_)                                            \
      kfa[dt_] = *reinterpret_cast<const uint4*>(                                \
          &ktb[o8_ + (16 * dt_ + l15) * 32 + l4 * 8]);                           \
  } while (0)

#define LOAD_KB(CI) do {                                                         \
    long o8_ = ((long)bh * NCH + (CI)) * 8192;                                   \
    _Pragma("unroll")                                                            \
    for (int dt_ = 0; dt_ < 8; ++dt_)                                            \
      kfb[dt_] = *reinterpret_cast<const uint4*>(                                \
          &ktb[o8_ + (16 * (dt_ + 8) + l15) * 32 + l4 * 8]);                     \
  } while (0)

#define LOAD_A(CI) do {                                                          \
    long oa_ = ((long)bh * NCH + (CI)) * 1024;                                   \
    _Pragma("unroll")                                                            \
    for (int m_ = 0; m_ < 2; ++m_)                                               \
      af[m_] = *reinterpret_cast<const uint4*>(                                  \
          &atb[oa_ + (16 * m_ + l15) * 32 + l4 * 8]);                            \
  } while (0)

#define SCAN_BODY(CI, PF) do {                                                   \
    long ub = ((long)b * L_ + (long)(CI) * CHUNKSZ) * D_ + h * DH + colw;        \
    _Pragma("unroll")                                                            \
    for (int dt = 0; dt < 16; ++dt) {                                            \
      uint2 pv;                                                                  \
      pv.x = pk2bf(acc[dt].x, acc[dt].y);                                        \
      pv.y = pk2bf(acc[dt].z, acc[dt].w);                                        \
      *reinterpret_cast<uint2*>(&sB[l15 * 264 + dt * 16 + l4 * 4]) = pv;         \
    }                                                                            \
    bf16x8 sf[8];                                                                \
    _Pragma("unroll")                                                            \
    for (int kc = 0; kc < 8; ++kc)                                               \
      sf[kc] = *reinterpret_cast<const bf16x8*>(&sB[l15 * 264 + kc * 32 + l4 * 8]); \
    f32x4 wa[2][2];                                                              \
    wa[0][0] = zero4; wa[0][1] = zero4; wa[1][0] = zero4; wa[1][1] = zero4;      \
    _Pragma("unroll")                                                            \
    for (int kc = 0; kc < 8; ++kc) {                                             \
      _Pragma("unroll")                                                          \
      for (int m = 0; m < 2; ++m)                                                \
        wa[m][kc & 1] = __builtin_amdgcn_mfma_f32_16x16x32_bf16(                 \
            *reinterpret_cast<bf16x8*>(&wf[m][kc]), sf[kc], wa[m][kc & 1], 0, 0, 0); \
    }                                                                            \
    if (PF) LOAD_W((CI) + 1);                                                    \
    _Pragma("unroll")                                                            \
    for (int m = 0; m < 2; ++m) {                                                \
      f32x4 wsum = wa[m][0] + wa[m][1];                                          \
      uint2 pv;                                                                  \
      pv.x = pk2bf(ru[m][0] - wsum.x, ru[m][1] - wsum.y);                        \
      pv.y = pk2bf(ru[m][2] - wsum.z, ru[m][3] - wsum.w);                        \
      *reinterpret_cast<uint2*>(&su2[l15 * 40 + m * 16 + l4 * 4]) = pv;          \
    }                                                                            \
    if (PF) LOAD_U((CI) + 1);                                                    \
    bf16x8 u2f = *reinterpret_cast<const bf16x8*>(&su2[l15 * 40 + l4 * 8]);      \
    _Pragma("unroll")                                                            \
    for (int dt = 0; dt < 8; ++dt)                                               \
      acc[dt] = __builtin_amdgcn_mfma_f32_16x16x32_bf16(                         \
          *reinterpret_cast<bf16x8*>(&kfa[dt]), u2f, acc[dt], 0, 0, 0);          \
    if (PF) LOAD_KA((CI) + 1);                                                   \
    _Pragma("unroll")                                                            \
    for (int dt = 0; dt < 8; ++dt)                                               \
      acc[dt + 8] = __builtin_amdgcn_mfma_f32_16x16x32_bf16(                     \
          *reinterpret_cast<bf16x8*>(&kfb[dt]), u2f, acc[dt + 8], 0, 0, 0);      \
    if (PF) LOAD_KB((CI) + 1);                                                   \
    f32x4 qa[2][2];                                                              \
    qa[0][0] = zero4; qa[0][1] = zero4; qa[1][0] = zero4; qa[1][1] = zero4;      \
    _Pragma("unroll")                                                            \
    for (int kc = 0; kc < 8; ++kc) {                                             \
      _Pragma("unroll")                                                          \
      for (int m = 0; m < 2; ++m)                                                \
        qa[m][kc & 1] = __builtin_amdgcn_mfma_f32_16x16x32_bf16(                 \
            *reinterpret_cast<bf16x8*>(&qf[m][kc]), sf[kc], qa[m][kc & 1], 0, 0, 0); \
    }                                                                            \
    if (PF) LOAD_Q((CI) + 1);                                                    \
    _Pragma("unroll")                                                            \
    for (int m = 0; m < 2; ++m) {                                                \
      f32x4 qacc = qa[m][0] + qa[m][1];                                          \
      f32x4 dv = __builtin_amdgcn_mfma_f32_16x16x32_bf16(                        \
          *reinterpret_cast<bf16x8*>(&af[m]), u2f, qacc, 0, 0, 0);               \
      _Pragma("unroll")                                                          \
      for (int r = 0; r < 4; ++r)                                                \
        out[ub + (long)(16 * m + 4 * l4 + r) * D_ + l15] = dv[r];                \
    }                                                                            \
    if (PF) LOAD_A((CI) + 1);                                                    \
  } while (0)

  LOAD_W(0); LOAD_U(0); LOAD_Q(0); LOAD_KA(0); LOAD_KB(0); LOAD_A(0);

  for (int ci = 0; ci < NCH - 1; ++ci) {
    SCAN_BODY(ci, 1);
  }
  SCAN_BODY(NCH - 1, 0);

#undef LOAD_W
#undef LOAD_U
#undef LOAD_Q
#undef LOAD_KA
#undef LOAD_KB
#undef LOAD_A
#undef SCAN_BODY
}

// ---------------- fused head stats x4 tensors: wave w -> tensor w ----------------
__global__ __launch_bounds__(256)
void head_stats4(const float* __restrict__ t0, const float* __restrict__ t1,
                 const float* __restrict__ t2, const float* __restrict__ t3,
                 float* __restrict__ outp) {
  long bl = blockIdx.x;
  int w = threadIdx.x >> 6, lane = threadIdx.x & 63;
  const float* x = (w == 0) ? t0 : (w == 1) ? t1 : (w == 2) ? t2 : t3;
  float m = 0.f, vv = 0.f, am = 0.f, l2 = 0.f;
#pragma unroll
  for (int h = 0; h < 4; ++h) {
    float4 v = *reinterpret_cast<const float4*>(&x[bl * 1024 + h * 256 + lane * 4]);
    float s = v.x + v.y + v.z + v.w;
    float q = v.x * v.x + v.y * v.y + v.z * v.z + v.w * v.w;
    float a = fabsf(v.x) + fabsf(v.y) + fabsf(v.z) + fabsf(v.w);
#pragma unroll
    for (int st = 32; st > 0; st >>= 1) {
      s += __shfl_xor(s, st); q += __shfl_xor(q, st); a += __shfl_xor(a, st);
    }
    float mean = s * (1.f / 256.f);
    m += mean;
    vv += q * (1.f / 256.f) - mean * mean;
    am += a * (1.f / 256.f);
    l2 += sqrtf(q);
  }
  if (lane == 0) {
    float* o = outp + bl * 16 + w * 4;
    o[0] = m * 0.25f; o[1] = vv * 0.25f; o[2] = am * 0.25f; o[3] = l2 * 0.25f;
  }
}

// ---------------- gate: gelu(g + bg1 + stats@Wtail) @ Wg2 + bg2 -> softmax p (fused) ----------------
__global__ __launch_bounds__(256)
void gate_fused(const float* __restrict__ g, const float* __restrict__ stats,
                const float* __restrict__ Wg1t, const float* __restrict__ bg1,
                const float* __restrict__ Wg2, const float* __restrict__ bg2,
                const float* __restrict__ temp_in, float* __restrict__ p) {
  __shared__ float red[4][4];
  long m = blockIdx.x;
  int tid = threadIdx.x;
  int c0 = tid * 4;
  float4 gv = *reinterpret_cast<const float4*>(&g[m * 1024 + c0]);
  float st[16];
#pragma unroll
  for (int k = 0; k < 16; ++k) st[k] = stats[m * 16 + k];
  float la[4] = {0.f, 0.f, 0.f, 0.f};
  float gvv[4] = {gv.x, gv.y, gv.z, gv.w};
#pragma unroll
  for (int j = 0; j < 4; ++j) {
    int c = c0 + j;
    float s = gvv[j] + bg1[c];
#pragma unroll
    for (int k = 0; k < 16; ++k) s += st[k] * Wg1t[(long)k * 1024 + c];
    float ge = geluf(s);
#pragma unroll
    for (int n = 0; n < 4; ++n) la[n] += ge * Wg2[c * 4 + n];
  }
#pragma unroll
  for (int stp = 32; stp > 0; stp >>= 1)
#pragma unroll
    for (int n = 0; n < 4; ++n) la[n] += __shfl_xor(la[n], stp);
  int w = tid >> 6;
  if ((tid & 63) == 0) {
#pragma unroll
    for (int n = 0; n < 4; ++n) red[w][n] = la[n];
  }
  __syncthreads();
  if (tid == 0) {
    float temp = log1pf(expf(temp_in[0]));
    float l[4];
#pragma unroll
    for (int n = 0; n < 4; ++n)
      l[n] = (red[0][n] + red[1][n] + red[2][n] + red[3][n] + bg2[n]) / temp;
    float mx = fmaxf(fmaxf(l[0], l[1]), fmaxf(l[2], l[3]));
    float e[4], s = 0.f;
#pragma unroll
    for (int n = 0; n < 4; ++n) { e[n] = expf(l[n] - mx); s += e[n]; }
    float s2 = 0.f;
#pragma unroll
    for (int n = 0; n < 4; ++n) { e[n] = fmaxf(e[n] / s, 0.02f); s2 += e[n]; }
#pragma unroll
    for (int n = 0; n < 4; ++n) p[m * 4 + n] = e[n] / s2;
  }
}

// ---------------- combine + og stats (o, v_direct) fused; block per (b,l) row ----------------
__global__ __launch_bounds__(256)
void combine_ogstats(const float* __restrict__ ls, const float* __restrict__ ll,
                     const float* __restrict__ dd, const float* __restrict__ vd,
                     const float* __restrict__ p, const float* __restrict__ resg,
                     const float* __restrict__ crl, float* __restrict__ o,
                     float* __restrict__ og8) {
  __shared__ float part[4][8];
  long bl = blockIdx.x;
  int h = threadIdx.x >> 6, lane = threadIdx.x & 63;
  long base = bl * 1024 + h * 256 + lane * 4;
  float4 lsv = *reinterpret_cast<const float4*>(&ls[base]);
  float4 llv = *reinterpret_cast<const float4*>(&ll[base]);
  float4 ddv = *reinterpret_cast<const float4*>(&dd[base]);
  float4 vdv = *reinterpret_cast<const float4*>(&vd[base]);
  float p0 = p[bl * 4 + 0], p1 = p[bl * 4 + 1], p2 = p[bl * 4 + 2], p3 = p[bl * 4 + 3];
  float sg = sigmf(crl[h]) * resg[bl * 4 + h];
  float c0 = p0 + sg;
  float4 ov;
  ov.x = c0 * lsv.x + p1 * llv.x + p2 * ddv.x + p3 * vdv.x;
  ov.y = c0 * lsv.y + p1 * llv.y + p2 * ddv.y + p3 * vdv.y;
  ov.z = c0 * lsv.z + p1 * llv.z + p2 * ddv.z + p3 * vdv.z;
  ov.w = c0 * lsv.w + p1 * llv.w + p2 * ddv.w + p3 * vdv.w;
  *reinterpret_cast<float4*>(&o[base]) = ov;
  float s = ov.x + ov.y + ov.z + ov.w;
  float q = ov.x * ov.x + ov.y * ov.y + ov.z * ov.z + ov.w * ov.w;
  float a = fabsf(ov.x) + fabsf(ov.y) + fabsf(ov.z) + fabsf(ov.w);
  float sv = vdv.x + vdv.y + vdv.z + vdv.w;
  float qv = vdv.x * vdv.x + vdv.y * vdv.y + vdv.z * vdv.z + vdv.w * vdv.w;
  float av = fabsf(vdv.x) + fabsf(vdv.y) + fabsf(vdv.z) + fabsf(vdv.w);
#pragma unroll
  for (int st = 32; st > 0; st >>= 1) {
    s += __shfl_xor(s, st); q += __shfl_xor(q, st); a += __shfl_xor(a, st);
    sv += __shfl_xor(sv, st); qv += __shfl_xor(qv, st); av += __shfl_xor(av, st);
  }
  if (lane == 0) {
    float mo = s * (1.f / 256.f), mv = sv * (1.f / 256.f);
    part[h][0] = mo; part[h][1] = q * (1.f / 256.f) - mo * mo;
    part[h][2] = a * (1.f / 256.f); part[h][3] = sqrtf(q);
    part[h][4] = mv; part[h][5] = qv * (1.f / 256.f) - mv * mv;
    part[h][6] = av * (1.f / 256.f); part[h][7] = sqrtf(qv);
  }
  __syncthreads();
  if (threadIdx.x < 8) {
    int t = threadIdx.x;
    og8[bl * 8 + t] = 0.25f * (part[0][t] + part[1][t] + part[2][t] + part[3][t]);
  }
}

// ---------------- og: gelu(g + bog1 + og8@Wtail) @ Wog2 + bog2 -> sigmoid (fused) ----------------
__global__ __launch_bounds__(256)
void og_gate_fused(const float* __restrict__ g, const float* __restrict__ og8,
                   const float* __restrict__ Wog1t, const float* __restrict__ bog1,
                   const float* __restrict__ Wog2, const float* __restrict__ bog2,
                   float* __restrict__ ogv) {
  __shared__ float red[4];
  long m = blockIdx.x;
  int tid = threadIdx.x;
  int c0 = tid * 2;
  float2 gv = *reinterpret_cast<const float2*>(&g[m * 512 + c0]);
  float st[8];
#pragma unroll
  for (int k = 0; k < 8; ++k) st[k] = og8[m * 8 + k];
  float a = 0.f;
  float gvv[2] = {gv.x, gv.y};
#pragma unroll
  for (int j = 0; j < 2; ++j) {
    int c = c0 + j;
    float s = gvv[j] + bog1[c];
#pragma unroll
    for (int k = 0; k < 8; ++k) s += st[k] * Wog1t[(long)k * 512 + c];
    a += geluf(s) * Wog2[c];
  }
#pragma unroll
  for (int stp = 32; stp > 0; stp >>= 1) a += __shfl_xor(a, stp);
  int w = tid >> 6;
  if ((tid & 63) == 0) red[w] = a;
  __syncthreads();
  if (tid == 0) ogv[m] = sigmf(red[0] + red[1] + red[2] + red[3] + bog2[0]);
}

// ---------------- wave-parallel scale+rmsnorm, writes bf16 directly ----------------
__global__ __launch_bounds__(256)
void scale_rmsnorm_bf16(const float* __restrict__ o, const float* __restrict__ og,
                        const float* __restrict__ nw, unsigned short* __restrict__ xb) {
  long row = (long)blockIdx.x * 4 + (threadIdx.x >> 6);
  long bl = row >> 2;
  int lane = threadIdx.x & 63;
  float g = og[bl];
  float4 v = *reinterpret_cast<const float4*>(&o[row * 256 + lane * 4]);
  v.x *= g; v.y *= g; v.z *= g; v.w *= g;
  float q = v.x * v.x + v.y * v.y + v.z * v.z + v.w * v.w;
#pragma unroll
  for (int st = 32; st > 0; st >>= 1) q += __shfl_xor(q, st);
  float scale = rsqrtf(q * (1.f / 256.f) + 1e-5f);
  float4 w4 = *reinterpret_cast<const float4*>(&nw[lane * 4]);
  ushort4 r;
  r.x = f2bf(v.x * scale * w4.x);
  r.y = f2bf(v.y * scale * w4.y);
  r.z = f2bf(v.z * scale * w4.z);
  r.w = f2bf(v.w * scale * w4.w);
  *reinterpret_cast<ushort4*>(&xb[row * 256 + lane * 4]) = r;
}

extern "C" void kernel_launch(void* const* d_in, const int* in_sizes, int n_in,
                              void* d_out, int out_size, void* d_ws, size_t ws_size,
                              hipStream_t stream) {
  const float* hs       = (const float*)d_in[0];
  const float* Wq       = (const float*)d_in[1];
  const float* Wk       = (const float*)d_in[2];
  const float* Wv       = (const float*)d_in[3];
  const float* Wb       = (const float*)d_in[4];
  const float* wq_conv  = (const float*)d_in[5];
  const float* wk_conv  = (const float*)d_in[6];
  const float* wv_conv  = (const float*)d_in[7];
  const float* fir_long = (const float*)d_in[8];
  const float* fir_short= (const float*)d_in[9];
  const float* Wg1      = (const float*)d_in[10];
  const float* bg1      = (const float*)d_in[11];
  const float* Wg2      = (const float*)d_in[12];
  const float* bg2      = (const float*)d_in[13];
  const float* logit_temp     = (const float*)d_in[14];
  const float* conv_res_logit = (const float*)d_in[15];
  const float* Wres     = (const float*)d_in[16];
  const float* bres     = (const float*)d_in[17];
  const float* Wog1     = (const float*)d_in[18];
  const float* bog1     = (const float*)d_in[19];
  const float* Wog2     = (const float*)d_in[20];
  const float* bog2     = (const float*)d_in[21];
  const float* norm_w   = (const float*)d_in[22];
  const float* Wo       = (const float*)d_in[23];
  float* out = (float*)d_out;
  float* ws = (float*)d_ws;

  float* b0 = ws;             // qlin -> kn -> gate_hidden -> o_mix
  float* b1 = ws + 1L * BLD;  // klin -> v_in (v_direct)
  float* b2 = ws + 2L * BLD;  // vlin -> u -> delta_out -> og_hidden
  float* b3 = ws + 3L * BLD;  // qn -> local_long
  float* b4 = ws + 4L * BLD;  // w_bf (bf16, first half) -> local_short
  float* sm = ws + 5L * BLD;
  float* beta    = sm;
  float* resg    = beta + BL * H_;
  float* stats16 = resg + BL * H_;
  float* og8     = stats16 + BL * 16;
  float* logits  = og8 + BL * 8;
  float* pbuf    = logits + BL * 4;
  float* ogv     = pbuf + BL * 4;
  unsigned short* q_bfg  = (unsigned short*)(ogv + BL);   // BLD bf16
  unsigned short* kT_bfg = q_bfg + (long)BLD;             // BLD bf16
  unsigned short* at_bfg = kT_bfg + (long)BLD;            // 1M bf16
  unsigned short* hsb  = at_bfg + 1024L * 1024;           // BLD bf16
  unsigned short* wtq  = hsb + (long)BLD;
  unsigned short* wtk  = wtq + 1024L * 1024;
  unsigned short* wtv  = wtk + 1024L * 1024;
  unsigned short* wtg1 = wtv + 1024L * 1024;
  unsigned short* wto  = wtg1 + 1024L * 1024;
  unsigned short* wtog1= wto + 1024L * 1024;
  unsigned short* w_bfg = (unsigned short*)b4;            // bf16 w inside b4
  unsigned short* xb    = q_bfg;                          // reuse (q_bf dead after scan)

  size_t needed = (5L * BLD + BL * 41) * 4
                + (3L * BLD + 1024L * 1024 + 5L * 1024 * 1024 + 512L * 1024) * 2;
  if (ws_size < needed) return;

  dim3 blk(256);
  // 0. preconvert
  wconv_t<<<dim3(32, 32), blk, 0, stream>>>(Wq, wtq, 1024);
  wconv_t<<<dim3(32, 32), blk, 0, stream>>>(Wk, wtk, 1024);
  wconv_t<<<dim3(32, 32), blk, 0, stream>>>(Wv, wtv, 1024);
  wconv_t<<<dim3(32, 32), blk, 0, stream>>>(Wg1, wtg1, 1024);
  wconv_t<<<dim3(32, 32), blk, 0, stream>>>(Wo, wto, 1024);
  wconv_t<<<dim3(16, 32), blk, 0, stream>>>(Wog1, wtog1, 512);
  cvt_bf16<<<BLD / 1024, blk, 0, stream>>>(hs, hsb, BLD);
  // 1. projections
  gemm_bf16<<<dim3(8, 64), blk, 0, stream>>>(hsb, wtq, b0, 1024);
  gemm_bf16<<<dim3(8, 64), blk, 0, stream>>>(hsb, wtk, b1, 1024);
  gemm_bf16<<<dim3(8, 64), blk, 0, stream>>>(hsb, wtv, b2, 1024);
  // 2. conv + silu (sliding-window tiled)
  dwconv_tiled<4><<<1024, blk, 0, stream>>>(b0, wq_conv, b3, 1);
  dwconv_tiled<4><<<1024, blk, 0, stream>>>(b1, wk_conv, b0, 1);
  dwconv_tiled<4><<<1024, blk, 0, stream>>>(b2, wv_conv, b1, 1);
  // 3. beta + res gate (fused wave GEMV)
  beta_res_gemv<<<BL, blk, 0, stream>>>(hs, Wb, Wres, bres, beta, resg);
  // 4. l2norm (wave-parallel)
  l2norm_wave<<<BL * H_ / 4, blk, 0, stream>>>(b3);
  l2norm_wave<<<BL * H_ / 4, blk, 0, stream>>>(b0);
  // 5-6. delta rule (u->b2; bf16 operands; scan writes delta_out in place over u)
  chunk_uw<<<B_ * H_ * NCH, blk, 0, stream>>>(b3, b0, b1, beta, b2, q_bfg, w_bfg, kT_bfg, at_bfg);
  delta_scan<<<16, dim3(512), 0, stream>>>(q_bfg, w_bfg, kT_bfg, at_bfg, b2, b2);
  // 7. local convs
  dwconv_tiled<64><<<1024, blk, 0, stream>>>(b1, fir_long, b3, 0);
  dwconv_tiled<5><<<1024, blk, 0, stream>>>(b1, fir_short, b4, 0);
  // 8. stats16 fused (ls=b4, ll=b3, dd=b2, vd=b1)
  head_stats4<<<BL, blk, 0, stream>>>(b4, b3, b2, b1, stats16);
  // 9. gate hidden + gate tail + logits + softmax (fused)
  gemm_bf16<<<dim3(8, 64), blk, 0, stream>>>(hsb, wtg1, b0, 1024);
  gate_fused<<<BL, blk, 0, stream>>>(b0, stats16, Wg1 + 1024L * 1024, bg1, Wg2, bg2, logit_temp, pbuf);
  // 10. combine + og stats (fused) -> b0, og8
  combine_ogstats<<<BL, blk, 0, stream>>>(b4, b3, b2, b1, pbuf, resg, conv_res_logit, b0, og8);
  // 11. output gate: gemm + fused tail/gemv/sigmoid
  gemm_bf16<<<dim3(4, 64), blk, 0, stream>>>(hsb, wtog1, b2, 512);
  og_gate_fused<<<BL, blk, 0, stream>>>(b2, og8, Wog1 + 1024L * 512, bog1, Wog2, bog2, ogv);
  // 12. scale + rmsnorm -> bf16 directly
  scale_rmsnorm_bf16<<<BL * H_ / 4, blk, 0, stream>>>(b0, ogv, norm_w, xb);
  // 13. final projection
  gemm_bf16<<<dim3(8, 64), blk, 0, stream>>>(xb, wto, out, 1024);
}

// Round 13
// 947.218 us; speedup vs baseline: 2.9096x; 2.9096x over previous
//
#include <hip/hip_runtime.h>
#include <math.h>

#define B_ 2
#define L_ 4096
#define D_ 1024
#define H_ 4
#define DH 256
#define CHUNKSZ 32
#define NCH (L_/CHUNKSZ)      // 128
#define BL (B_*L_)            // 8192
#define BLD (B_*L_*D_)        // 8388608

typedef __attribute__((ext_vector_type(8))) short bf16x8;
typedef __attribute__((ext_vector_type(4))) float f32x4;

__device__ __forceinline__ float sigmf(float x) { return 1.f / (1.f + expf(-x)); }
__device__ __forceinline__ float geluf(float x) { return 0.5f * x * (1.f + erff(x * 0.70710678118654752f)); }
__device__ __forceinline__ unsigned short f2bf(float f) {
  unsigned int u = __float_as_uint(f);
  unsigned int r = (u + 0x7FFFu + ((u >> 16) & 1u)) >> 16;
  return (unsigned short)r;
}
__device__ __forceinline__ unsigned int pk2bf(float a, float b) {
  return ((unsigned int)f2bf(b) << 16) | (unsigned int)f2bf(a);
}

// ---------------- f32 -> bf16 elementwise (n multiple of 4) ----------------
__global__ __launch_bounds__(256)
void cvt_bf16(const float* __restrict__ x, unsigned short* __restrict__ y, long n) {
  long i = ((long)blockIdx.x * 256 + threadIdx.x) * 4;
  if (i >= n) return;
  float4 v = *reinterpret_cast<const float4*>(&x[i]);
  ushort4 o;
  o.x = f2bf(v.x); o.y = f2bf(v.y); o.z = f2bf(v.z); o.w = f2bf(v.w);
  *reinterpret_cast<ushort4*>(&y[i]) = o;
}

// ---------------- W[k][n] f32 -> Wt[n][k] bf16 (32x32 tiles) ----------------
__global__ __launch_bounds__(256)
void wconv_t(const float* __restrict__ W, unsigned short* __restrict__ Wt, int N) {
  __shared__ float tile[32][33];
  int kb = blockIdx.y * 32, nb = blockIdx.x * 32;
  int tx = threadIdx.x & 31, ty = threadIdx.x >> 5;
  for (int i = 0; i < 32; i += 8)
    tile[ty + i][tx] = W[(long)(kb + ty + i) * N + nb + tx];
  __syncthreads();
  for (int i = 0; i < 32; i += 8)
    Wt[(long)(nb + ty + i) * 1024 + kb + tx] = f2bf(tile[tx][ty + i]);
}

// ---------------- bf16 MFMA GEMM: C[8192][N] = A[8192][1024] @ Bt[N][1024]^T ----------------
__global__ __launch_bounds__(256)
void gemm_bf16(const unsigned short* __restrict__ A, const unsigned short* __restrict__ Bt,
               float* __restrict__ C, int N) {
  __shared__ unsigned short Al[128 * 32];
  __shared__ unsigned short Bl[128 * 32];
  const int K = 1024;
  int bm = blockIdx.y * 128, bn = blockIdx.x * 128;
  int tid = threadIdx.x;
  int lane = tid & 63, wid = tid >> 6;
  int wr = wid >> 1, wc = wid & 1;
  int l15 = lane & 15, l4 = lane >> 4;
  f32x4 acc[4][4];
#pragma unroll
  for (int i = 0; i < 4; ++i)
#pragma unroll
    for (int j = 0; j < 4; ++j) { acc[i][j].x = 0.f; acc[i][j].y = 0.f; acc[i][j].z = 0.f; acc[i][j].w = 0.f; }
  for (int k0 = 0; k0 < K; k0 += 32) {
    __syncthreads();
#pragma unroll
    for (int i = 0; i < 2; ++i) {
      int idx = tid + i * 256;
      int r = idx >> 2, sl = idx & 3;
      int src = sl ^ ((r >> 1) & 3);
      __builtin_amdgcn_global_load_lds(
          (const __attribute__((address_space(1))) unsigned int*)&A[(long)(bm + r) * K + k0 + src * 8],
          (__attribute__((address_space(3))) unsigned int*)&Al[idx * 8], 16, 0, 0);
      __builtin_amdgcn_global_load_lds(
          (const __attribute__((address_space(1))) unsigned int*)&Bt[(long)(bn + r) * K + k0 + src * 8],
          (__attribute__((address_space(3))) unsigned int*)&Bl[idx * 8], 16, 0, 0);
    }
    __syncthreads();
    bf16x8 af[4], bfr[4];
#pragma unroll
    for (int fi = 0; fi < 4; ++fi) {
      int r = wr * 64 + fi * 16 + l15;
      af[fi] = *reinterpret_cast<const bf16x8*>(&Al[r * 32 + (l4 ^ ((r >> 1) & 3)) * 8]);
    }
#pragma unroll
    for (int fj = 0; fj < 4; ++fj) {
      int r = wc * 64 + fj * 16 + l15;
      bfr[fj] = *reinterpret_cast<const bf16x8*>(&Bl[r * 32 + (l4 ^ ((r >> 1) & 3)) * 8]);
    }
#pragma unroll
    for (int fi = 0; fi < 4; ++fi)
#pragma unroll
      for (int fj = 0; fj < 4; ++fj)
        acc[fi][fj] = __builtin_amdgcn_mfma_f32_16x16x32_bf16(af[fi], bfr[fj], acc[fi][fj], 0, 0, 0);
  }
#pragma unroll
  for (int fi = 0; fi < 4; ++fi) {
    int rb = bm + wr * 64 + fi * 16 + l4 * 4;
#pragma unroll
    for (int fj = 0; fj < 4; ++fj) {
      int cb = bn + wc * 64 + fj * 16 + l15;
#pragma unroll
      for (int j = 0; j < 4; ++j)
        C[(long)(rb + j) * N + cb] = acc[fi][fj][j];
    }
  }
}

// ---------------- tiled depthwise causal conv, sliding-window (8 consecutive outputs/group) ----------------
#define CTL 128
template<int K>
__global__ __launch_bounds__(256)
void dwconv_tiled(const float* __restrict__ x, const float* __restrict__ w,
                  float* __restrict__ y, int do_silu) {
  __shared__ float tile[(CTL + K - 1) * 64];
  int bid = blockIdx.x;
  int ct = bid & 15;
  int lt = (bid >> 4) & 31;
  int b  = bid >> 9;
  int c0 = ct * 64;
  int l0 = lt * CTL;
  int tid = threadIdx.x;
  const int rows = CTL + K - 1;
  for (int i = tid; i < rows * 16; i += 256) {
    int rr = i >> 4, c4 = i & 15;
    int l = l0 - (K - 1) + rr;
    float4 v = make_float4(0.f, 0.f, 0.f, 0.f);
    if (l >= 0) v = *reinterpret_cast<const float4*>(&x[((long)b * L_ + l) * D_ + c0 + c4 * 4]);
    *reinterpret_cast<float4*>(&tile[rr * 64 + c4 * 4]) = v;
  }
  __syncthreads();
  int c = tid & 63;
  int wv = tid >> 6;
  float wreg[K];
#pragma unroll
  for (int j = 0; j < K; ++j) wreg[j] = w[(long)(c0 + c) * K + j];
#pragma unroll
  for (int g = 0; g < 4; ++g) {
    int lo_base = g * 32 + wv * 8;
    float win[8];
#pragma unroll
    for (int r = 0; r < 8; ++r) win[r] = tile[(lo_base + r) * 64 + c];
    float acc[8] = {0.f, 0.f, 0.f, 0.f, 0.f, 0.f, 0.f, 0.f};
#pragma unroll
    for (int j = 0; j < K; ++j) {
#pragma unroll
      for (int r = 0; r < 8; ++r) acc[r] = fmaf(wreg[j], win[r], acc[r]);
      if (j < K - 1) {
#pragma unroll
        for (int r = 0; r < 7; ++r) win[r] = win[r + 1];
        win[7] = tile[(lo_base + j + 8) * 64 + c];
      }
    }
#pragma unroll
    for (int r = 0; r < 8; ++r) {
      float v = acc[r];
      if (do_silu) v = v * sigmf(v);
      y[((long)b * L_ + l0 + lo_base + r) * D_ + c0 + c] = v;
    }
  }
}

// ---------------- wave-parallel l2norm: 4 rows/block, shuffle reduce ----------------
__global__ __launch_bounds__(256)
void l2norm_wave(float* __restrict__ x) {
  long row = (long)blockIdx.x * 4 + (threadIdx.x >> 6);
  int lane = threadIdx.x & 63;
  float4 v = *reinterpret_cast<const float4*>(&x[row * 256 + lane * 4]);
  float q = v.x * v.x + v.y * v.y + v.z * v.z + v.w * v.w;
#pragma unroll
  for (int st = 32; st > 0; st >>= 1) q += __shfl_xor(q, st);
  float inv = rsqrtf(q + 1e-6f);
  v.x *= inv; v.y *= inv; v.z *= inv; v.w *= inv;
  *reinterpret_cast<float4*>(&x[row * 256 + lane * 4]) = v;
}

// ---------------- fused beta/resg GEMV ----------------
__global__ __launch_bounds__(256)
void beta_res_gemv(const float* __restrict__ hs, const float* __restrict__ Wb,
                   const float* __restrict__ Wres, const float* __restrict__ bres,
                   float* __restrict__ beta, float* __restrict__ resg) {
  long m = blockIdx.x;
  int n = threadIdx.x >> 6, lane = threadIdx.x & 63;
  float ab = 0.f, ar = 0.f;
  for (int k0 = lane * 4; k0 < 1024; k0 += 256) {
    float4 x = *reinterpret_cast<const float4*>(&hs[m * 1024 + k0]);
    ab += x.x * Wb[(k0 + 0) * 4 + n] + x.y * Wb[(k0 + 1) * 4 + n]
        + x.z * Wb[(k0 + 2) * 4 + n] + x.w * Wb[(k0 + 3) * 4 + n];
    ar += x.x * Wres[(k0 + 0) * 4 + n] + x.y * Wres[(k0 + 1) * 4 + n]
        + x.z * Wres[(k0 + 2) * 4 + n] + x.w * Wres[(k0 + 3) * 4 + n];
  }
#pragma unroll
  for (int st = 32; st > 0; st >>= 1) { ab += __shfl_xor(ab, st); ar += __shfl_xor(ar, st); }
  if (lane == 0) {
    beta[m * 4 + n] = sigmf(ab);
    resg[m * 4 + n] = sigmf(ar + bres[n]);
  }
}

// ---------------- per-chunk: inv, u (f32), and bf16 operands for the scan ----------------
__global__ __launch_bounds__(256)
void chunk_uw(const float* __restrict__ qn, const float* __restrict__ kn,
              const float* __restrict__ v, const float* __restrict__ beta,
              float* __restrict__ u,
              unsigned short* __restrict__ q_bf, unsigned short* __restrict__ w_bf,
              unsigned short* __restrict__ kT_bf, unsigned short* __restrict__ at_bf) {
  __shared__ float skT[256][33];
  __shared__ float sinv[32][33];
  __shared__ float sbeta[32];
  int blk = blockIdx.x;
  int ci = blk % NCH;
  int bh = blk / NCH;
  int h = bh % H_;
  int b = bh / H_;
  long base = ((long)b * L_ + (long)ci * CHUNKSZ) * D_ + h * DH;
  long brow = (long)b * L_ + (long)ci * CHUNKSZ;
  long obase = (long)blk * 8192;
  int tid = threadIdx.x;
  for (int i = tid; i < 32 * 256; i += 256) {
    int r = i >> 8, c = i & 255;
    skT[c][r] = kn[base + (long)r * D_ + c];
  }
  if (tid < 32) sbeta[tid] = beta[(brow + tid) * H_ + h];
  __syncthreads();
  for (int i = tid; i < 8192; i += 256)
    kT_bf[obase + i] = f2bf(skT[i >> 5][i & 31]);
  for (int i = tid; i < 8192; i += 256)
    q_bf[obase + i] = f2bf(qn[base + (long)(i >> 8) * D_ + (i & 255)]);
  int j = tid & 31, i0 = tid >> 5;
  for (int r = 0; r < 4; ++r) {
    int i = i0 + (r << 3);
    float acc = 0.f;
    for (int d = 0; d < 256; ++d) acc += skT[d][i] * skT[d][j];
    sinv[i][j] = (i > j) ? -acc * sbeta[i] : 0.f;
  }
  __syncthreads();
  for (int i = 1; i < 32; ++i) {
    float val = 0.f;
    if (tid < 32) {
      for (int t = 0; t < i; ++t) val += sinv[i][t] * sinv[t][tid];
    }
    __syncthreads();
    if (tid < 32) sinv[i][tid] += val;
    __syncthreads();
  }
  if (tid < 32) sinv[tid][tid] += 1.f;
  long abase = (long)blk * 1024;
  for (int r = 0; r < 4; ++r) {
    int i = i0 + (r << 3);
    const float* qrow = qn + base + (long)i * D_;
    float acc = 0.f;
    for (int d = 0; d < 256; ++d) acc += qrow[d] * skT[d][j];
    at_bf[abase + i * 32 + j] = f2bf((i >= j) ? acc : 0.f);
  }
  __syncthreads();
  int c = tid;
  float vt[32], kt[32];
#pragma unroll
  for (int t = 0; t < 32; ++t) {
    vt[t] = v[base + t * D_ + c] * sbeta[t];
    kt[t] = skT[c][t] * sbeta[t];
  }
#pragma unroll
  for (int i2 = 0; i2 < 32; ++i2) {
    float au = 0.f, aw = 0.f;
#pragma unroll
    for (int t = 0; t <= i2; ++t) {
      float f = sinv[i2][t];
      au += f * vt[t];
      aw += f * kt[t];
    }
    u[base + i2 * D_ + c] = au;
    w_bf[obase + i2 * 256 + c] = f2bf(aw);
  }
}

// ---------------- MFMA scan (round-11 version): 128 blocks x 1 wave, barrier-free,
// peeled branch-free prefetch pipeline (1 chunk ahead), ~212 VGPR, no spills ----------------
// `out` aliases `u` (u reads precede out stores in program order; disjoint cols across blocks).
__global__ __launch_bounds__(64, 1)
void delta_scan(const unsigned short* __restrict__ qb, const unsigned short* __restrict__ wbf,
                const unsigned short* __restrict__ ktb, const unsigned short* __restrict__ atb,
                const float* u, float* out) {
  __shared__ unsigned short sB[16 * 264];   // S^T staging: [n=16][d=256] pad 264
  __shared__ unsigned short su2[16 * 40];   // u2^T: [n=16][t=32] pad 40
  int blk = blockIdx.x;
  int bh = blk & 7, cg = blk >> 3;
  int h = bh & 3, b = bh >> 2;
  int lane = threadIdx.x;
  int l15 = lane & 15, l4 = lane >> 4;
  int colw = cg * 16;

  f32x4 zero4; zero4.x = 0.f; zero4.y = 0.f; zero4.z = 0.f; zero4.w = 0.f;
  f32x4 acc[16];
#pragma unroll
  for (int t = 0; t < 16; ++t) acc[t] = zero4;

  uint4 wf[2][8];
  float ru[2][4];
  uint4 qf[2][8];
  uint4 kfa[8], kfb[8];
  uint4 af[2];

#define LOAD_W(CI) do {                                                          \
    long o8_ = ((long)bh * NCH + (CI)) * 8192;                                   \
    _Pragma("unroll")                                                            \
    for (int m_ = 0; m_ < 2; ++m_)                                               \
      _Pragma("unroll")                                                          \
      for (int kc_ = 0; kc_ < 8; ++kc_)                                          \
        wf[m_][kc_] = *reinterpret_cast<const uint4*>(                           \
            &wbf[o8_ + (16 * m_ + l15) * 256 + kc_ * 32 + l4 * 8]);              \
  } while (0)

#define LOAD_U(CI) do {                                                          \
    long ub_ = ((long)b * L_ + (long)(CI) * CHUNKSZ) * D_ + h * DH + colw;       \
    _Pragma("unroll")                                                            \
    for (int m_ = 0; m_ < 2; ++m_)                                               \
      _Pragma("unroll")                                                          \
      for (int r_ = 0; r_ < 4; ++r_)                                             \
        ru[m_][r_] = u[ub_ + (long)(16 * m_ + 4 * l4 + r_) * D_ + l15];          \
  } while (0)

#define LOAD_Q(CI) do {                                                          \
    long o8_ = ((long)bh * NCH + (CI)) * 8192;                                   \
    _Pragma("unroll")                                                            \
    for (int m_ = 0; m_ < 2; ++m_)                                               \
      _Pragma("unroll")                                                          \
      for (int kc_ = 0; kc_ < 8; ++kc_)                                          \
        qf[m_][kc_] = *reinterpret_cast<const uint4*>(                           \
            &qb[o8_ + (16 * m_ + l15) * 256 + kc_ * 32 + l4 * 8]);               \
  } while (0)

#define LOAD_KA(CI) do {                                                         \
    long o8_ = ((long)bh * NCH + (CI)) * 8192;                                   \
    _Pragma("unroll")                                                            \
    for (int dt_ = 0; dt_ < 8; ++dt_)                                            \
      kfa[dt_] = *reinterpret_cast<const uint4*>(                                \
          &ktb[o8_ + (16 * dt_ + l15) * 32 + l4 * 8]);                           \
  } while (0)

#define LOAD_KB(CI) do {                                                         \
    long o8_ = ((long)bh * NCH + (CI)) * 8192;                                   \
    _Pragma("unroll")                                                            \
    for (int dt_ = 0; dt_ < 8; ++dt_)                                            \
      kfb[dt_] = *reinterpret_cast<const uint4*>(                                \
          &ktb[o8_ + (16 * (dt_ + 8) + l15) * 32 + l4 * 8]);                     \
  } while (0)

#define LOAD_A(CI) do {                                                          \
    long oa_ = ((long)bh * NCH + (CI)) * 1024;                                   \
    _Pragma("unroll")                                                            \
    for (int m_ = 0; m_ < 2; ++m_)                                               \
      af[m_] = *reinterpret_cast<const uint4*>(                                  \
          &atb[oa_ + (16 * m_ + l15) * 32 + l4 * 8]);                            \
  } while (0)

#define SCAN_BODY(CI, PF) do {                                                   \
    long ub = ((long)b * L_ + (long)(CI) * CHUNKSZ) * D_ + h * DH + colw;        \
    _Pragma("unroll")                                                            \
    for (int dt = 0; dt < 16; ++dt) {                                            \
      uint2 pv;                                                                  \
      pv.x = pk2bf(acc[dt].x, acc[dt].y);                                        \
      pv.y = pk2bf(acc[dt].z, acc[dt].w);                                        \
      *reinterpret_cast<uint2*>(&sB[l15 * 264 + dt * 16 + l4 * 4]) = pv;         \
    }                                                                            \
    bf16x8 sf[8];                                                                \
    _Pragma("unroll")                                                            \
    for (int kc = 0; kc < 8; ++kc)                                               \
      sf[kc] = *reinterpret_cast<const bf16x8*>(&sB[l15 * 264 + kc * 32 + l4 * 8]); \
    f32x4 wa[2][2];                                                              \
    wa[0][0] = zero4; wa[0][1] = zero4; wa[1][0] = zero4; wa[1][1] = zero4;      \
    _Pragma("unroll")                                                            \
    for (int kc = 0; kc < 8; ++kc) {                                             \
      _Pragma("unroll")                                                          \
      for (int m = 0; m < 2; ++m)                                                \
        wa[m][kc & 1] = __builtin_amdgcn_mfma_f32_16x16x32_bf16(                 \
            *reinterpret_cast<bf16x8*>(&wf[m][kc]), sf[kc], wa[m][kc & 1], 0, 0, 0); \
    }                                                                            \
    if (PF) LOAD_W((CI) + 1);                                                    \
    _Pragma("unroll")                                                            \
    for (int m = 0; m < 2; ++m) {                                                \
      f32x4 wsum = wa[m][0] + wa[m][1];                                          \
      uint2 pv;                                                                  \
      pv.x = pk2bf(ru[m][0] - wsum.x, ru[m][1] - wsum.y);                        \
      pv.y = pk2bf(ru[m][2] - wsum.z, ru[m][3] - wsum.w);                        \
      *reinterpret_cast<uint2*>(&su2[l15 * 40 + m * 16 + l4 * 4]) = pv;          \
    }                                                                            \
    if (PF) LOAD_U((CI) + 1);                                                    \
    bf16x8 u2f = *reinterpret_cast<const bf16x8*>(&su2[l15 * 40 + l4 * 8]);      \
    _Pragma("unroll")                                                            \
    for (int dt = 0; dt < 8; ++dt)                                               \
      acc[dt] = __builtin_amdgcn_mfma_f32_16x16x32_bf16(                         \
          *reinterpret_cast<bf16x8*>(&kfa[dt]), u2f, acc[dt], 0, 0, 0);          \
    if (PF) LOAD_KA((CI) + 1);                                                   \
    _Pragma("unroll")                                                            \
    for (int dt = 0; dt < 8; ++dt)                                               \
      acc[dt + 8] = __builtin_amdgcn_mfma_f32_16x16x32_bf16(                     \
          *reinterpret_cast<bf16x8*>(&kfb[dt]), u2f, acc[dt + 8], 0, 0, 0);      \
    if (PF) LOAD_KB((CI) + 1);                                                   \
    f32x4 qa[2][2];                                                              \
    qa[0][0] = zero4; qa[0][1] = zero4; qa[1][0] = zero4; qa[1][1] = zero4;      \
    _Pragma("unroll")                                                            \
    for (int kc = 0; kc < 8; ++kc) {                                             \
      _Pragma("unroll")                                                          \
      for (int m = 0; m < 2; ++m)                                                \
        qa[m][kc & 1] = __builtin_amdgcn_mfma_f32_16x16x32_bf16(                 \
            *reinterpret_cast<bf16x8*>(&qf[m][kc]), sf[kc], qa[m][kc & 1], 0, 0, 0); \
    }                                                                            \
    if (PF) LOAD_Q((CI) + 1);                                                    \
    _Pragma("unroll")                                                            \
    for (int m = 0; m < 2; ++m) {                                                \
      f32x4 qacc = qa[m][0] + qa[m][1];                                          \
      f32x4 dv = __builtin_amdgcn_mfma_f32_16x16x32_bf16(                        \
          *reinterpret_cast<bf16x8*>(&af[m]), u2f, qacc, 0, 0, 0);               \
      _Pragma("unroll")                                                          \
      for (int r = 0; r < 4; ++r)                                                \
        out[ub + (long)(16 * m + 4 * l4 + r) * D_ + l15] = dv[r];                \
    }                                                                            \
    if (PF) LOAD_A((CI) + 1);                                                    \
  } while (0)

  LOAD_W(0); LOAD_U(0); LOAD_Q(0); LOAD_KA(0); LOAD_KB(0); LOAD_A(0);

  for (int ci = 0; ci < NCH - 1; ++ci) {
    SCAN_BODY(ci, 1);
  }
  SCAN_BODY(NCH - 1, 0);

#undef LOAD_W
#undef LOAD_U
#undef LOAD_Q
#undef LOAD_KA
#undef LOAD_KB
#undef LOAD_A
#undef SCAN_BODY
}

// ---------------- fused head stats x4 tensors: wave w -> tensor w ----------------
__global__ __launch_bounds__(256)
void head_stats4(const float* __restrict__ t0, const float* __restrict__ t1,
                 const float* __restrict__ t2, const float* __restrict__ t3,
                 float* __restrict__ outp) {
  long bl = blockIdx.x;
  int w = threadIdx.x >> 6, lane = threadIdx.x & 63;
  const float* x = (w == 0) ? t0 : (w == 1) ? t1 : (w == 2) ? t2 : t3;
  float m = 0.f, vv = 0.f, am = 0.f, l2 = 0.f;
#pragma unroll
  for (int h = 0; h < 4; ++h) {
    float4 v = *reinterpret_cast<const float4*>(&x[bl * 1024 + h * 256 + lane * 4]);
    float s = v.x + v.y + v.z + v.w;
    float q = v.x * v.x + v.y * v.y + v.z * v.z + v.w * v.w;
    float a = fabsf(v.x) + fabsf(v.y) + fabsf(v.z) + fabsf(v.w);
#pragma unroll
    for (int st = 32; st > 0; st >>= 1) {
      s += __shfl_xor(s, st); q += __shfl_xor(q, st); a += __shfl_xor(a, st);
    }
    float mean = s * (1.f / 256.f);
    m += mean;
    vv += q * (1.f / 256.f) - mean * mean;
    am += a * (1.f / 256.f);
    l2 += sqrtf(q);
  }
  if (lane == 0) {
    float* o = outp + bl * 16 + w * 4;
    o[0] = m * 0.25f; o[1] = vv * 0.25f; o[2] = am * 0.25f; o[3] = l2 * 0.25f;
  }
}

// ---------------- gate: gelu(g + bg1 + stats@Wtail) @ Wg2 + bg2 -> softmax p (fused) ----------------
__global__ __launch_bounds__(256)
void gate_fused(const float* __restrict__ g, const float* __restrict__ stats,
                const float* __restrict__ Wg1t, const float* __restrict__ bg1,
                const float* __restrict__ Wg2, const float* __restrict__ bg2,
                const float* __restrict__ temp_in, float* __restrict__ p) {
  __shared__ float red[4][4];
  long m = blockIdx.x;
  int tid = threadIdx.x;
  int c0 = tid * 4;
  float4 gv = *reinterpret_cast<const float4*>(&g[m * 1024 + c0]);
  float st[16];
#pragma unroll
  for (int k = 0; k < 16; ++k) st[k] = stats[m * 16 + k];
  float la[4] = {0.f, 0.f, 0.f, 0.f};
  float gvv[4] = {gv.x, gv.y, gv.z, gv.w};
#pragma unroll
  for (int j = 0; j < 4; ++j) {
    int c = c0 + j;
    float s = gvv[j] + bg1[c];
#pragma unroll
    for (int k = 0; k < 16; ++k) s += st[k] * Wg1t[(long)k * 1024 + c];
    float ge = geluf(s);
#pragma unroll
    for (int n = 0; n < 4; ++n) la[n] += ge * Wg2[c * 4 + n];
  }
#pragma unroll
  for (int stp = 32; stp > 0; stp >>= 1)
#pragma unroll
    for (int n = 0; n < 4; ++n) la[n] += __shfl_xor(la[n], stp);
  int w = tid >> 6;
  if ((tid & 63) == 0) {
#pragma unroll
    for (int n = 0; n < 4; ++n) red[w][n] = la[n];
  }
  __syncthreads();
  if (tid == 0) {
    float temp = log1pf(expf(temp_in[0]));
    float l[4];
#pragma unroll
    for (int n = 0; n < 4; ++n)
      l[n] = (red[0][n] + red[1][n] + red[2][n] + red[3][n] + bg2[n]) / temp;
    float mx = fmaxf(fmaxf(l[0], l[1]), fmaxf(l[2], l[3]));
    float e[4], s = 0.f;
#pragma unroll
    for (int n = 0; n < 4; ++n) { e[n] = expf(l[n] - mx); s += e[n]; }
    float s2 = 0.f;
#pragma unroll
    for (int n = 0; n < 4; ++n) { e[n] = fmaxf(e[n] / s, 0.02f); s2 += e[n]; }
#pragma unroll
    for (int n = 0; n < 4; ++n) p[m * 4 + n] = e[n] / s2;
  }
}

// ---------------- combine + og stats (o, v_direct) fused; block per (b,l) row ----------------
__global__ __launch_bounds__(256)
void combine_ogstats(const float* __restrict__ ls, const float* __restrict__ ll,
                     const float* __restrict__ dd, const float* __restrict__ vd,
                     const float* __restrict__ p, const float* __restrict__ resg,
                     const float* __restrict__ crl, float* __restrict__ o,
                     float* __restrict__ og8) {
  __shared__ float part[4][8];
  long bl = blockIdx.x;
  int h = threadIdx.x >> 6, lane = threadIdx.x & 63;
  long base = bl * 1024 + h * 256 + lane * 4;
  float4 lsv = *reinterpret_cast<const float4*>(&ls[base]);
  float4 llv = *reinterpret_cast<const float4*>(&ll[base]);
  float4 ddv = *reinterpret_cast<const float4*>(&dd[base]);
  float4 vdv = *reinterpret_cast<const float4*>(&vd[base]);
  float p0 = p[bl * 4 + 0], p1 = p[bl * 4 + 1], p2 = p[bl * 4 + 2], p3 = p[bl * 4 + 3];
  float sg = sigmf(crl[h]) * resg[bl * 4 + h];
  float c0 = p0 + sg;
  float4 ov;
  ov.x = c0 * lsv.x + p1 * llv.x + p2 * ddv.x + p3 * vdv.x;
  ov.y = c0 * lsv.y + p1 * llv.y + p2 * ddv.y + p3 * vdv.y;
  ov.z = c0 * lsv.z + p1 * llv.z + p2 * ddv.z + p3 * vdv.z;
  ov.w = c0 * lsv.w + p1 * llv.w + p2 * ddv.w + p3 * vdv.w;
  *reinterpret_cast<float4*>(&o[base]) = ov;
  float s = ov.x + ov.y + ov.z + ov.w;
  float q = ov.x * ov.x + ov.y * ov.y + ov.z * ov.z + ov.w * ov.w;
  float a = fabsf(ov.x) + fabsf(ov.y) + fabsf(ov.z) + fabsf(ov.w);
  float sv = vdv.x + vdv.y + vdv.z + vdv.w;
  float qv = vdv.x * vdv.x + vdv.y * vdv.y + vdv.z * vdv.z + vdv.w * vdv.w;
  float av = fabsf(vdv.x) + fabsf(vdv.y) + fabsf(vdv.z) + fabsf(vdv.w);
#pragma unroll
  for (int st = 32; st > 0; st >>= 1) {
    s += __shfl_xor(s, st); q += __shfl_xor(q, st); a += __shfl_xor(a, st);
    sv += __shfl_xor(sv, st); qv += __shfl_xor(qv, st); av += __shfl_xor(av, st);
  }
  if (lane == 0) {
    float mo = s * (1.f / 256.f), mv = sv * (1.f / 256.f);
    part[h][0] = mo; part[h][1] = q * (1.f / 256.f) - mo * mo;
    part[h][2] = a * (1.f / 256.f); part[h][3] = sqrtf(q);
    part[h][4] = mv; part[h][5] = qv * (1.f / 256.f) - mv * mv;
    part[h][6] = av * (1.f / 256.f); part[h][7] = sqrtf(qv);
  }
  __syncthreads();
  if (threadIdx.x < 8) {
    int t = threadIdx.x;
    og8[bl * 8 + t] = 0.25f * (part[0][t] + part[1][t] + part[2][t] + part[3][t]);
  }
}

// ---------------- og: gelu(g + bog1 + og8@Wtail) @ Wog2 + bog2 -> sigmoid (fused) ----------------
__global__ __launch_bounds__(256)
void og_gate_fused(const float* __restrict__ g, const float* __restrict__ og8,
                   const float* __restrict__ Wog1t, const float* __restrict__ bog1,
                   const float* __restrict__ Wog2, const float* __restrict__ bog2,
                   float* __restrict__ ogv) {
  __shared__ float red[4];
  long m = blockIdx.x;
  int tid = threadIdx.x;
  int c0 = tid * 2;
  float2 gv = *reinterpret_cast<const float2*>(&g[m * 512 + c0]);
  float st[8];
#pragma unroll
  for (int k = 0; k < 8; ++k) st[k] = og8[m * 8 + k];
  float a = 0.f;
  float gvv[2] = {gv.x, gv.y};
#pragma unroll
  for (int j = 0; j < 2; ++j) {
    int c = c0 + j;
    float s = gvv[j] + bog1[c];
#pragma unroll
    for (int k = 0; k < 8; ++k) s += st[k] * Wog1t[(long)k * 512 + c];
    a += geluf(s) * Wog2[c];
  }
#pragma unroll
  for (int stp = 32; stp > 0; stp >>= 1) a += __shfl_xor(a, stp);
  int w = tid >> 6;
  if ((tid & 63) == 0) red[w] = a;
  __syncthreads();
  if (tid == 0) ogv[m] = sigmf(red[0] + red[1] + red[2] + red[3] + bog2[0]);
}

// ---------------- wave-parallel scale+rmsnorm, writes bf16 directly ----------------
__global__ __launch_bounds__(256)
void scale_rmsnorm_bf16(const float* __restrict__ o, const float* __restrict__ og,
                        const float* __restrict__ nw, unsigned short* __restrict__ xb) {
  long row = (long)blockIdx.x * 4 + (threadIdx.x >> 6);
  long bl = row >> 2;
  int lane = threadIdx.x & 63;
  float g = og[bl];
  float4 v = *reinterpret_cast<const float4*>(&o[row * 256 + lane * 4]);
  v.x *= g; v.y *= g; v.z *= g; v.w *= g;
  float q = v.x * v.x + v.y * v.y + v.z * v.z + v.w * v.w;
#pragma unroll
  for (int st = 32; st > 0; st >>= 1) q += __shfl_xor(q, st);
  float scale = rsqrtf(q * (1.f / 256.f) + 1e-5f);
  float4 w4 = *reinterpret_cast<const float4*>(&nw[lane * 4]);
  ushort4 r;
  r.x = f2bf(v.x * scale * w4.x);
  r.y = f2bf(v.y * scale * w4.y);
  r.z = f2bf(v.z * scale * w4.z);
  r.w = f2bf(v.w * scale * w4.w);
  *reinterpret_cast<ushort4*>(&xb[row * 256 + lane * 4]) = r;
}

extern "C" void kernel_launch(void* const* d_in, const int* in_sizes, int n_in,
                              void* d_out, int out_size, void* d_ws, size_t ws_size,
                              hipStream_t stream) {
  const float* hs       = (const float*)d_in[0];
  const float* Wq       = (const float*)d_in[1];
  const float* Wk       = (const float*)d_in[2];
  const float* Wv       = (const float*)d_in[3];
  const float* Wb       = (const float*)d_in[4];
  const float* wq_conv  = (const float*)d_in[5];
  const float* wk_conv  = (const float*)d_in[6];
  const float* wv_conv  = (const float*)d_in[7];
  const float* fir_long = (const float*)d_in[8];
  const float* fir_short= (const float*)d_in[9];
  const float* Wg1      = (const float*)d_in[10];
  const float* bg1      = (const float*)d_in[11];
  const float* Wg2      = (const float*)d_in[12];
  const float* bg2      = (const float*)d_in[13];
  const float* logit_temp     = (const float*)d_in[14];
  const float* conv_res_logit = (const float*)d_in[15];
  const float* Wres     = (const float*)d_in[16];
  const float* bres     = (const float*)d_in[17];
  const float* Wog1     = (const float*)d_in[18];
  const float* bog1     = (const float*)d_in[19];
  const float* Wog2     = (const float*)d_in[20];
  const float* bog2     = (const float*)d_in[21];
  const float* norm_w   = (const float*)d_in[22];
  const float* Wo       = (const float*)d_in[23];
  float* out = (float*)d_out;
  float* ws = (float*)d_ws;

  float* b0 = ws;             // qlin -> kn -> gate_hidden -> o_mix
  float* b1 = ws + 1L * BLD;  // klin -> v_in (v_direct)
  float* b2 = ws + 2L * BLD;  // vlin -> u -> delta_out -> og_hidden
  float* b3 = ws + 3L * BLD;  // qn -> local_long
  float* b4 = ws + 4L * BLD;  // w_bf (bf16, first half) -> local_short
  float* sm = ws + 5L * BLD;
  float* beta    = sm;
  float* resg    = beta + BL * H_;
  float* stats16 = resg + BL * H_;
  float* og8     = stats16 + BL * 16;
  float* logits  = og8 + BL * 8;
  float* pbuf    = logits + BL * 4;
  float* ogv     = pbuf + BL * 4;
  unsigned short* q_bfg  = (unsigned short*)(ogv + BL);   // BLD bf16
  unsigned short* kT_bfg = q_bfg + (long)BLD;             // BLD bf16
  unsigned short* at_bfg = kT_bfg + (long)BLD;            // 1M bf16
  unsigned short* hsb  = at_bfg + 1024L * 1024;           // BLD bf16
  unsigned short* wtq  = hsb + (long)BLD;
  unsigned short* wtk  = wtq + 1024L * 1024;
  unsigned short* wtv  = wtk + 1024L * 1024;
  unsigned short* wtg1 = wtv + 1024L * 1024;
  unsigned short* wto  = wtg1 + 1024L * 1024;
  unsigned short* wtog1= wto + 1024L * 1024;
  unsigned short* w_bfg = (unsigned short*)b4;            // bf16 w inside b4
  unsigned short* xb    = q_bfg;                          // reuse (q_bf dead after scan)

  size_t needed = (5L * BLD + BL * 41) * 4
                + (3L * BLD + 1024L * 1024 + 5L * 1024 * 1024 + 512L * 1024) * 2;
  if (ws_size < needed) return;

  dim3 blk(256);
  // 0. preconvert
  wconv_t<<<dim3(32, 32), blk, 0, stream>>>(Wq, wtq, 1024);
  wconv_t<<<dim3(32, 32), blk, 0, stream>>>(Wk, wtk, 1024);
  wconv_t<<<dim3(32, 32), blk, 0, stream>>>(Wv, wtv, 1024);
  wconv_t<<<dim3(32, 32), blk, 0, stream>>>(Wg1, wtg1, 1024);
  wconv_t<<<dim3(32, 32), blk, 0, stream>>>(Wo, wto, 1024);
  wconv_t<<<dim3(16, 32), blk, 0, stream>>>(Wog1, wtog1, 512);
  cvt_bf16<<<BLD / 1024, blk, 0, stream>>>(hs, hsb, BLD);
  // 1. projections
  gemm_bf16<<<dim3(8, 64), blk, 0, stream>>>(hsb, wtq, b0, 1024);
  gemm_bf16<<<dim3(8, 64), blk, 0, stream>>>(hsb, wtk, b1, 1024);
  gemm_bf16<<<dim3(8, 64), blk, 0, stream>>>(hsb, wtv, b2, 1024);
  // 2. conv + silu (sliding-window tiled)
  dwconv_tiled<4><<<1024, blk, 0, stream>>>(b0, wq_conv, b3, 1);
  dwconv_tiled<4><<<1024, blk, 0, stream>>>(b1, wk_conv, b0, 1);
  dwconv_tiled<4><<<1024, blk, 0, stream>>>(b2, wv_conv, b1, 1);
  // 3. beta + res gate (fused wave GEMV)
  beta_res_gemv<<<BL, blk, 0, stream>>>(hs, Wb, Wres, bres, beta, resg);
  // 4. l2norm (wave-parallel)
  l2norm_wave<<<BL * H_ / 4, blk, 0, stream>>>(b3);
  l2norm_wave<<<BL * H_ / 4, blk, 0, stream>>>(b0);
  // 5-6. delta rule (u->b2; bf16 operands; scan writes delta_out in place over u)
  chunk_uw<<<B_ * H_ * NCH, blk, 0, stream>>>(b3, b0, b1, beta, b2, q_bfg, w_bfg, kT_bfg, at_bfg);
  delta_scan<<<128, dim3(64), 0, stream>>>(q_bfg, w_bfg, kT_bfg, at_bfg, b2, b2);
  // 7. local convs
  dwconv_tiled<64><<<1024, blk, 0, stream>>>(b1, fir_long, b3, 0);
  dwconv_tiled<5><<<1024, blk, 0, stream>>>(b1, fir_short, b4, 0);
  // 8. stats16 fused (ls=b4, ll=b3, dd=b2, vd=b1)
  head_stats4<<<BL, blk, 0, stream>>>(b4, b3, b2, b1, stats16);
  // 9. gate hidden + gate tail + logits + softmax (fused)
  gemm_bf16<<<dim3(8, 64), blk, 0, stream>>>(hsb, wtg1, b0, 1024);
  gate_fused<<<BL, blk, 0, stream>>>(b0, stats16, Wg1 + 1024L * 1024, bg1, Wg2, bg2, logit_temp, pbuf);
  // 10. combine + og stats (fused) -> b0, og8
  combine_ogstats<<<BL, blk, 0, stream>>>(b4, b3, b2, b1, pbuf, resg, conv_res_logit, b0, og8);
  // 11. output gate: gemm + fused tail/gemv/sigmoid
  gemm_bf16<<<dim3(4, 64), blk, 0, stream>>>(hsb, wtog1, b2, 512);
  og_gate_fused<<<BL, blk, 0, stream>>>(b2, og8, Wog1 + 1024L * 512, bog1, Wog2, bog2, ogv);
  // 12. scale + rmsnorm -> bf16 directly
  scale_rmsnorm_bf16<<<BL * H_ / 4, blk, 0, stream>>>(b0, ogv, norm_w, xb);
  // 13. final projection
  gemm_bf16<<<dim3(8, 64), blk, 0, stream>>>(xb, wto, out, 1024);
}

// Round 15
// 934.332 us; speedup vs baseline: 2.9498x; 1.0138x over previous
//
#include <hip/hip_runtime.h>
#include <math.h>

#define B_ 2
#define L_ 4096
#define D_ 1024
#define H_ 4
#define DH 256
#define CHUNKSZ 32
#define NCH (L_/CHUNKSZ)      // 128
#define BL (B_*L_)            // 8192
#define BLD (B_*L_*D_)        // 8388608

typedef __attribute__((ext_vector_type(8))) short bf16x8;
typedef __attribute__((ext_vector_type(4))) float f32x4;

__device__ __forceinline__ float sigmf(float x) { return 1.f / (1.f + expf(-x)); }
__device__ __forceinline__ float geluf(float x) { return 0.5f * x * (1.f + erff(x * 0.70710678118654752f)); }
__device__ __forceinline__ unsigned short f2bf(float f) {
  unsigned int u = __float_as_uint(f);
  unsigned int r = (u + 0x7FFFu + ((u >> 16) & 1u)) >> 16;
  return (unsigned short)r;
}
__device__ __forceinline__ unsigned int pk2bf(float a, float b) {
  return ((unsigned int)f2bf(b) << 16) | (unsigned int)f2bf(a);
}

// ---------------- f32 -> bf16 elementwise (n multiple of 4) ----------------
__global__ __launch_bounds__(256)
void cvt_bf16(const float* __restrict__ x, unsigned short* __restrict__ y, long n) {
  long i = ((long)blockIdx.x * 256 + threadIdx.x) * 4;
  if (i >= n) return;
  float4 v = *reinterpret_cast<const float4*>(&x[i]);
  ushort4 o;
  o.x = f2bf(v.x); o.y = f2bf(v.y); o.z = f2bf(v.z); o.w = f2bf(v.w);
  *reinterpret_cast<ushort4*>(&y[i]) = o;
}

// ---------------- W[k][n] f32 -> Wt[n][k] bf16 (32x32 tiles) ----------------
__global__ __launch_bounds__(256)
void wconv_t(const float* __restrict__ W, unsigned short* __restrict__ Wt, int N) {
  __shared__ float tile[32][33];
  int kb = blockIdx.y * 32, nb = blockIdx.x * 32;
  int tx = threadIdx.x & 31, ty = threadIdx.x >> 5;
  for (int i = 0; i < 32; i += 8)
    tile[ty + i][tx] = W[(long)(kb + ty + i) * N + nb + tx];
  __syncthreads();
  for (int i = 0; i < 32; i += 8)
    Wt[(long)(nb + ty + i) * 1024 + kb + tx] = f2bf(tile[tx][ty + i]);
}

// ---------------- bf16 MFMA GEMM with XCD-aware tile swizzle ----------------
// grid = 1D (M/128)*(N/128); each XCD gets contiguous 8-bm x all-bn rectangle so its
// A-panel (2MB) + B (2MB) fit the 4MB per-XCD L2.
__global__ __launch_bounds__(256)
void gemm_bf16(const unsigned short* __restrict__ A, const unsigned short* __restrict__ Bt,
               float* __restrict__ C, int N) {
  __shared__ unsigned short Al[128 * 32];
  __shared__ unsigned short Bl[128 * 32];
  const int K = 1024;
  int nBn = N >> 7;
  int wgid = blockIdx.x;
  int xcd = wgid & 7;
  int local = wgid >> 3;
  int bm = (xcd * 8 + local / nBn) * 128;
  int bn = (local % nBn) * 128;
  int tid = threadIdx.x;
  int lane = tid & 63, wid = tid >> 6;
  int wr = wid >> 1, wc = wid & 1;
  int l15 = lane & 15, l4 = lane >> 4;
  f32x4 acc[4][4];
#pragma unroll
  for (int i = 0; i < 4; ++i)
#pragma unroll
    for (int j = 0; j < 4; ++j) { acc[i][j].x = 0.f; acc[i][j].y = 0.f; acc[i][j].z = 0.f; acc[i][j].w = 0.f; }
  for (int k0 = 0; k0 < K; k0 += 32) {
    __syncthreads();
#pragma unroll
    for (int i = 0; i < 2; ++i) {
      int idx = tid + i * 256;
      int r = idx >> 2, sl = idx & 3;
      int src = sl ^ ((r >> 1) & 3);
      __builtin_amdgcn_global_load_lds(
          (const __attribute__((address_space(1))) unsigned int*)&A[(long)(bm + r) * K + k0 + src * 8],
          (__attribute__((address_space(3))) unsigned int*)&Al[idx * 8], 16, 0, 0);
      __builtin_amdgcn_global_load_lds(
          (const __attribute__((address_space(1))) unsigned int*)&Bt[(long)(bn + r) * K + k0 + src * 8],
          (__attribute__((address_space(3))) unsigned int*)&Bl[idx * 8], 16, 0, 0);
    }
    __syncthreads();
    bf16x8 af[4], bfr[4];
#pragma unroll
    for (int fi = 0; fi < 4; ++fi) {
      int r = wr * 64 + fi * 16 + l15;
      af[fi] = *reinterpret_cast<const bf16x8*>(&Al[r * 32 + (l4 ^ ((r >> 1) & 3)) * 8]);
    }
#pragma unroll
    for (int fj = 0; fj < 4; ++fj) {
      int r = wc * 64 + fj * 16 + l15;
      bfr[fj] = *reinterpret_cast<const bf16x8*>(&Bl[r * 32 + (l4 ^ ((r >> 1) & 3)) * 8]);
    }
#pragma unroll
    for (int fi = 0; fi < 4; ++fi)
#pragma unroll
      for (int fj = 0; fj < 4; ++fj)
        acc[fi][fj] = __builtin_amdgcn_mfma_f32_16x16x32_bf16(af[fi], bfr[fj], acc[fi][fj], 0, 0, 0);
  }
#pragma unroll
  for (int fi = 0; fi < 4; ++fi) {
    int rb = bm + wr * 64 + fi * 16 + l4 * 4;
#pragma unroll
    for (int fj = 0; fj < 4; ++fj) {
      int cb = bn + wc * 64 + fj * 16 + l15;
#pragma unroll
      for (int j = 0; j < 4; ++j)
        C[(long)(rb + j) * N + cb] = acc[fi][fj][j];
    }
  }
}

// ---------------- tiled depthwise causal conv, sliding-window ----------------
#define CTL 128
template<int K>
__global__ __launch_bounds__(256)
void dwconv_tiled(const float* __restrict__ x, const float* __restrict__ w,
                  float* __restrict__ y, int do_silu) {
  __shared__ float tile[(CTL + K - 1) * 64];
  int bid = blockIdx.x;
  int ct = bid & 15;
  int lt = (bid >> 4) & 31;
  int b  = bid >> 9;
  int c0 = ct * 64;
  int l0 = lt * CTL;
  int tid = threadIdx.x;
  const int rows = CTL + K - 1;
  for (int i = tid; i < rows * 16; i += 256) {
    int rr = i >> 4, c4 = i & 15;
    int l = l0 - (K - 1) + rr;
    float4 v = make_float4(0.f, 0.f, 0.f, 0.f);
    if (l >= 0) v = *reinterpret_cast<const float4*>(&x[((long)b * L_ + l) * D_ + c0 + c4 * 4]);
    *reinterpret_cast<float4*>(&tile[rr * 64 + c4 * 4]) = v;
  }
  __syncthreads();
  int c = tid & 63;
  int wv = tid >> 6;
  float wreg[K];
#pragma unroll
  for (int j = 0; j < K; ++j) wreg[j] = w[(long)(c0 + c) * K + j];
#pragma unroll
  for (int g = 0; g < 4; ++g) {
    int lo_base = g * 32 + wv * 8;
    float win[8];
#pragma unroll
    for (int r = 0; r < 8; ++r) win[r] = tile[(lo_base + r) * 64 + c];
    float acc[8] = {0.f, 0.f, 0.f, 0.f, 0.f, 0.f, 0.f, 0.f};
#pragma unroll
    for (int j = 0; j < K; ++j) {
#pragma unroll
      for (int r = 0; r < 8; ++r) acc[r] = fmaf(wreg[j], win[r], acc[r]);
      if (j < K - 1) {
#pragma unroll
        for (int r = 0; r < 7; ++r) win[r] = win[r + 1];
        win[7] = tile[(lo_base + j + 8) * 64 + c];
      }
    }
#pragma unroll
    for (int r = 0; r < 8; ++r) {
      float v = acc[r];
      if (do_silu) v = v * sigmf(v);
      y[((long)b * L_ + l0 + lo_base + r) * D_ + c0 + c] = v;
    }
  }
}

// ---------------- wave-parallel l2norm ----------------
__global__ __launch_bounds__(256)
void l2norm_wave(float* __restrict__ x) {
  long row = (long)blockIdx.x * 4 + (threadIdx.x >> 6);
  int lane = threadIdx.x & 63;
  float4 v = *reinterpret_cast<const float4*>(&x[row * 256 + lane * 4]);
  float q = v.x * v.x + v.y * v.y + v.z * v.z + v.w * v.w;
#pragma unroll
  for (int st = 32; st > 0; st >>= 1) q += __shfl_xor(q, st);
  float inv = rsqrtf(q + 1e-6f);
  v.x *= inv; v.y *= inv; v.z *= inv; v.w *= inv;
  *reinterpret_cast<float4*>(&x[row * 256 + lane * 4]) = v;
}

// ---------------- fused beta/resg GEMV ----------------
__global__ __launch_bounds__(256)
void beta_res_gemv(const float* __restrict__ hs, const float* __restrict__ Wb,
                   const float* __restrict__ Wres, const float* __restrict__ bres,
                   float* __restrict__ beta, float* __restrict__ resg) {
  long m = blockIdx.x;
  int n = threadIdx.x >> 6, lane = threadIdx.x & 63;
  float ab = 0.f, ar = 0.f;
  for (int k0 = lane * 4; k0 < 1024; k0 += 256) {
    float4 x = *reinterpret_cast<const float4*>(&hs[m * 1024 + k0]);
    ab += x.x * Wb[(k0 + 0) * 4 + n] + x.y * Wb[(k0 + 1) * 4 + n]
        + x.z * Wb[(k0 + 2) * 4 + n] + x.w * Wb[(k0 + 3) * 4 + n];
    ar += x.x * Wres[(k0 + 0) * 4 + n] + x.y * Wres[(k0 + 1) * 4 + n]
        + x.z * Wres[(k0 + 2) * 4 + n] + x.w * Wres[(k0 + 3) * 4 + n];
  }
#pragma unroll
  for (int st = 32; st > 0; st >>= 1) { ab += __shfl_xor(ab, st); ar += __shfl_xor(ar, st); }
  if (lane == 0) {
    beta[m * 4 + n] = sigmf(ab);
    resg[m * 4 + n] = sigmf(ar + bres[n]);
  }
}

// ---------------- per-chunk (round-13 f32 version): inv, u, bf16 scan operands ----------------
__global__ __launch_bounds__(256)
void chunk_uw(const float* __restrict__ qn, const float* __restrict__ kn,
              const float* __restrict__ v, const float* __restrict__ beta,
              float* __restrict__ u,
              unsigned short* __restrict__ q_bf, unsigned short* __restrict__ w_bf,
              unsigned short* __restrict__ kT_bf, unsigned short* __restrict__ at_bf) {
  __shared__ float skT[256][33];
  __shared__ float sinv[32][33];
  __shared__ float sbeta[32];
  int blk = blockIdx.x;
  int ci = blk % NCH;
  int bh = blk / NCH;
  int h = bh % H_;
  int b = bh / H_;
  long base = ((long)b * L_ + (long)ci * CHUNKSZ) * D_ + h * DH;
  long brow = (long)b * L_ + (long)ci * CHUNKSZ;
  long obase = (long)blk * 8192;
  int tid = threadIdx.x;
  for (int i = tid; i < 32 * 256; i += 256) {
    int r = i >> 8, c = i & 255;
    skT[c][r] = kn[base + (long)r * D_ + c];
  }
  if (tid < 32) sbeta[tid] = beta[(brow + tid) * H_ + h];
  __syncthreads();
  for (int i = tid; i < 8192; i += 256)
    kT_bf[obase + i] = f2bf(skT[i >> 5][i & 31]);
  for (int i = tid; i < 8192; i += 256)
    q_bf[obase + i] = f2bf(qn[base + (long)(i >> 8) * D_ + (i & 255)]);
  int j = tid & 31, i0 = tid >> 5;
  for (int r = 0; r < 4; ++r) {
    int i = i0 + (r << 3);
    float acc = 0.f;
    for (int d = 0; d < 256; ++d) acc += skT[d][i] * skT[d][j];
    sinv[i][j] = (i > j) ? -acc * sbeta[i] : 0.f;
  }
  __syncthreads();
  for (int i = 1; i < 32; ++i) {
    float val = 0.f;
    if (tid < 32) {
      for (int t = 0; t < i; ++t) val += sinv[i][t] * sinv[t][tid];
    }
    __syncthreads();
    if (tid < 32) sinv[i][tid] += val;
    __syncthreads();
  }
  if (tid < 32) sinv[tid][tid] += 1.f;
  long abase = (long)blk * 1024;
  for (int r = 0; r < 4; ++r) {
    int i = i0 + (r << 3);
    const float* qrow = qn + base + (long)i * D_;
    float acc = 0.f;
    for (int d = 0; d < 256; ++d) acc += qrow[d] * skT[d][j];
    at_bf[abase + i * 32 + j] = f2bf((i >= j) ? acc : 0.f);
  }
  __syncthreads();
  int c = tid;
  float vt[32], kt[32];
#pragma unroll
  for (int t = 0; t < 32; ++t) {
    vt[t] = v[base + t * D_ + c] * sbeta[t];
    kt[t] = skT[c][t] * sbeta[t];
  }
#pragma unroll
  for (int i2 = 0; i2 < 32; ++i2) {
    float au = 0.f, aw = 0.f;
#pragma unroll
    for (int t = 0; t <= i2; ++t) {
      float f = sinv[i2][t];
      au += f * vt[t];
      aw += f * kt[t];
    }
    u[base + i2 * D_ + c] = au;
    w_bf[obase + i2 * 256 + c] = f2bf(aw);
  }
}

// ---------------- MFMA scan (round-11 version): 128 blocks x 1 wave, barrier-free ----------------
__global__ __launch_bounds__(64, 1)
void delta_scan(const unsigned short* __restrict__ qb, const unsigned short* __restrict__ wbf,
                const unsigned short* __restrict__ ktb, const unsigned short* __restrict__ atb,
                const float* u, float* out) {
  __shared__ unsigned short sB[16 * 264];
  __shared__ unsigned short su2[16 * 40];
  int blk = blockIdx.x;
  int bh = blk & 7, cg = blk >> 3;
  int h = bh & 3, b = bh >> 2;
  int lane = threadIdx.x;
  int l15 = lane & 15, l4 = lane >> 4;
  int colw = cg * 16;

  f32x4 zero4; zero4.x = 0.f; zero4.y = 0.f; zero4.z = 0.f; zero4.w = 0.f;
  f32x4 acc[16];
#pragma unroll
  for (int t = 0; t < 16; ++t) acc[t] = zero4;

  uint4 wf[2][8];
  float ru[2][4];
  uint4 qf[2][8];
  uint4 kfa[8], kfb[8];
  uint4 af[2];

#define LOAD_W(CI) do {                                                          \
    long o8_ = ((long)bh * NCH + (CI)) * 8192;                                   \
    _Pragma("unroll")                                                            \
    for (int m_ = 0; m_ < 2; ++m_)                                               \
      _Pragma("unroll")                                                          \
      for (int kc_ = 0; kc_ < 8; ++kc_)                                          \
        wf[m_][kc_] = *reinterpret_cast<const uint4*>(                           \
            &wbf[o8_ + (16 * m_ + l15) * 256 + kc_ * 32 + l4 * 8]);              \
  } while (0)

#define LOAD_U(CI) do {                                                          \
    long ub_ = ((long)b * L_ + (long)(CI) * CHUNKSZ) * D_ + h * DH + colw;       \
    _Pragma("unroll")                                                            \
    for (int m_ = 0; m_ < 2; ++m_)                                               \
      _Pragma("unroll")                                                          \
      for (int r_ = 0; r_ < 4; ++r_)                                             \
        ru[m_][r_] = u[ub_ + (long)(16 * m_ + 4 * l4 + r_) * D_ + l15];          \
  } while (0)

#define LOAD_Q(CI) do {                                                          \
    long o8_ = ((long)bh * NCH + (CI)) * 8192;                                   \
    _Pragma("unroll")                                                            \
    for (int m_ = 0; m_ < 2; ++m_)                                               \
      _Pragma("unroll")                                                          \
      for (int kc_ = 0; kc_ < 8; ++kc_)                                          \
        qf[m_][kc_] = *reinterpret_cast<const uint4*>(                           \
            &qb[o8_ + (16 * m_ + l15) * 256 + kc_ * 32 + l4 * 8]);               \
  } while (0)

#define LOAD_KA(CI) do {                                                         \
    long o8_ = ((long)bh * NCH + (CI)) * 8192;                                   \
    _Pragma("unroll")                                                            \
    for (int dt_ = 0; dt_ < 8; ++dt_)                                            \
      kfa[dt_] = *reinterpret_cast<const uint4*>(                                \
          &ktb[o8_ + (16 * dt_ + l15) * 32 + l4 * 8]);                           \
  } while (0)

#define LOAD_KB(CI) do {                                                         \
    long o8_ = ((long)bh * NCH + (CI)) * 8192;                                   \
    _Pragma("unroll")                                                            \
    for (int dt_ = 0; dt_ < 8; ++dt_)                                            \
      kfb[dt_] = *reinterpret_cast<const uint4*>(                                \
          &ktb[o8_ + (16 * (dt_ + 8) + l15) * 32 + l4 * 8]);                     \
  } while (0)

#define LOAD_A(CI) do {                                                          \
    long oa_ = ((long)bh * NCH + (CI)) * 1024;                                   \
    _Pragma("unroll")                                                            \
    for (int m_ = 0; m_ < 2; ++m_)                                               \
      af[m_] = *reinterpret_cast<const uint4*>(                                  \
          &atb[oa_ + (16 * m_ + l15) * 32 + l4 * 8]);                            \
  } while (0)

#define SCAN_BODY(CI, PF) do {                                                   \
    long ub = ((long)b * L_ + (long)(CI) * CHUNKSZ) * D_ + h * DH + colw;        \
    _Pragma("unroll")                                                            \
    for (int dt = 0; dt < 16; ++dt) {                                            \
      uint2 pv;                                                                  \
      pv.x = pk2bf(acc[dt].x, acc[dt].y);                                        \
      pv.y = pk2bf(acc[dt].z, acc[dt].w);                                        \
      *reinterpret_cast<uint2*>(&sB[l15 * 264 + dt * 16 + l4 * 4]) = pv;         \
    }                                                                            \
    bf16x8 sf[8];                                                                \
    _Pragma("unroll")                                                            \
    for (int kc = 0; kc < 8; ++kc)                                               \
      sf[kc] = *reinterpret_cast<const bf16x8*>(&sB[l15 * 264 + kc * 32 + l4 * 8]); \
    f32x4 wa[2][2];                                                              \
    wa[0][0] = zero4; wa[0][1] = zero4; wa[1][0] = zero4; wa[1][1] = zero4;      \
    _Pragma("unroll")                                                            \
    for (int kc = 0; kc < 8; ++kc) {                                             \
      _Pragma("unroll")                                                          \
      for (int m = 0; m < 2; ++m)                                                \
        wa[m][kc & 1] = __builtin_amdgcn_mfma_f32_16x16x32_bf16(                 \
            *reinterpret_cast<bf16x8*>(&wf[m][kc]), sf[kc], wa[m][kc & 1], 0, 0, 0); \
    }                                                                            \
    if (PF) LOAD_W((CI) + 1);                                                    \
    _Pragma("unroll")                                                            \
    for (int m = 0; m < 2; ++m) {                                                \
      f32x4 wsum = wa[m][0] + wa[m][1];                                          \
      uint2 pv;                                                                  \
      pv.x = pk2bf(ru[m][0] - wsum.x, ru[m][1] - wsum.y);                        \
      pv.y = pk2bf(ru[m][2] - wsum.z, ru[m][3] - wsum.w);                        \
      *reinterpret_cast<uint2*>(&su2[l15 * 40 + m * 16 + l4 * 4]) = pv;          \
    }                                                                            \
    if (PF) LOAD_U((CI) + 1);                                                    \
    bf16x8 u2f = *reinterpret_cast<const bf16x8*>(&su2[l15 * 40 + l4 * 8]);      \
    _Pragma("unroll")                                                            \
    for (int dt = 0; dt < 8; ++dt)                                               \
      acc[dt] = __builtin_amdgcn_mfma_f32_16x16x32_bf16(                         \
          *reinterpret_cast<bf16x8*>(&kfa[dt]), u2f, acc[dt], 0, 0, 0);          \
    if (PF) LOAD_KA((CI) + 1);                                                   \
    _Pragma("unroll")                                                            \
    for (int dt = 0; dt < 8; ++dt)                                               \
      acc[dt + 8] = __builtin_amdgcn_mfma_f32_16x16x32_bf16(                     \
          *reinterpret_cast<bf16x8*>(&kfb[dt]), u2f, acc[dt + 8], 0, 0, 0);      \
    if (PF) LOAD_KB((CI) + 1);                                                   \
    f32x4 qa[2][2];                                                              \
    qa[0][0] = zero4; qa[0][1] = zero4; qa[1][0] = zero4; qa[1][1] = zero4;      \
    _Pragma("unroll")                                                            \
    for (int kc = 0; kc < 8; ++kc) {                                             \
      _Pragma("unroll")                                                          \
      for (int m = 0; m < 2; ++m)                                                \
        qa[m][kc & 1] = __builtin_amdgcn_mfma_f32_16x16x32_bf16(                 \
            *reinterpret_cast<bf16x8*>(&qf[m][kc]), sf[kc], qa[m][kc & 1], 0, 0, 0); \
    }                                                                            \
    if (PF) LOAD_Q((CI) + 1);                                                    \
    _Pragma("unroll")                                                            \
    for (int m = 0; m < 2; ++m) {                                                \
      f32x4 qacc = qa[m][0] + qa[m][1];                                          \
      f32x4 dv = __builtin_amdgcn_mfma_f32_16x16x32_bf16(                        \
          *reinterpret_cast<bf16x8*>(&af[m]), u2f, qacc, 0, 0, 0);               \
      _Pragma("unroll")                                                          \
      for (int r = 0; r < 4; ++r)                                                \
        out[ub + (long)(16 * m + 4 * l4 + r) * D_ + l15] = dv[r];                \
    }                                                                            \
    if (PF) LOAD_A((CI) + 1);                                                    \
  } while (0)

  LOAD_W(0); LOAD_U(0); LOAD_Q(0); LOAD_KA(0); LOAD_KB(0); LOAD_A(0);

  for (int ci = 0; ci < NCH - 1; ++ci) {
    SCAN_BODY(ci, 1);
  }
  SCAN_BODY(NCH - 1, 0);

#undef LOAD_W
#undef LOAD_U
#undef LOAD_Q
#undef LOAD_KA
#undef LOAD_KB
#undef LOAD_A
#undef SCAN_BODY
}

// ---------------- fused head stats x4 tensors ----------------
__global__ __launch_bounds__(256)
void head_stats4(const float* __restrict__ t0, const float* __restrict__ t1,
                 const float* __restrict__ t2, const float* __restrict__ t3,
                 float* __restrict__ outp) {
  long bl = blockIdx.x;
  int w = threadIdx.x >> 6, lane = threadIdx.x & 63;
  const float* x = (w == 0) ? t0 : (w == 1) ? t1 : (w == 2) ? t2 : t3;
  float m = 0.f, vv = 0.f, am = 0.f, l2 = 0.f;
#pragma unroll
  for (int h = 0; h < 4; ++h) {
    float4 v = *reinterpret_cast<const float4*>(&x[bl * 1024 + h * 256 + lane * 4]);
    float s = v.x + v.y + v.z + v.w;
    float q = v.x * v.x + v.y * v.y + v.z * v.z + v.w * v.w;
    float a = fabsf(v.x) + fabsf(v.y) + fabsf(v.z) + fabsf(v.w);
#pragma unroll
    for (int st = 32; st > 0; st >>= 1) {
      s += __shfl_xor(s, st); q += __shfl_xor(q, st); a += __shfl_xor(a, st);
    }
    float mean = s * (1.f / 256.f);
    m += mean;
    vv += q * (1.f / 256.f) - mean * mean;
    am += a * (1.f / 256.f);
    l2 += sqrtf(q);
  }
  if (lane == 0) {
    float* o = outp + bl * 16 + w * 4;
    o[0] = m * 0.25f; o[1] = vv * 0.25f; o[2] = am * 0.25f; o[3] = l2 * 0.25f;
  }
}

// ---------------- gate fused ----------------
__global__ __launch_bounds__(256)
void gate_fused(const float* __restrict__ g, const float* __restrict__ stats,
                const float* __restrict__ Wg1t, const float* __restrict__ bg1,
                const float* __restrict__ Wg2, const float* __restrict__ bg2,
                const float* __restrict__ temp_in, float* __restrict__ p) {
  __shared__ float red[4][4];
  long m = blockIdx.x;
  int tid = threadIdx.x;
  int c0 = tid * 4;
  float4 gv = *reinterpret_cast<const float4*>(&g[m * 1024 + c0]);
  float st[16];
#pragma unroll
  for (int k = 0; k < 16; ++k) st[k] = stats[m * 16 + k];
  float la[4] = {0.f, 0.f, 0.f, 0.f};
  float gvv[4] = {gv.x, gv.y, gv.z, gv.w};
#pragma unroll
  for (int j = 0; j < 4; ++j) {
    int c = c0 + j;
    float s = gvv[j] + bg1[c];
#pragma unroll
    for (int k = 0; k < 16; ++k) s += st[k] * Wg1t[(long)k * 1024 + c];
    float ge = geluf(s);
#pragma unroll
    for (int n = 0; n < 4; ++n) la[n] += ge * Wg2[c * 4 + n];
  }
#pragma unroll
  for (int stp = 32; stp > 0; stp >>= 1)
#pragma unroll
    for (int n = 0; n < 4; ++n) la[n] += __shfl_xor(la[n], stp);
  int w = tid >> 6;
  if ((tid & 63) == 0) {
#pragma unroll
    for (int n = 0; n < 4; ++n) red[w][n] = la[n];
  }
  __syncthreads();
  if (tid == 0) {
    float temp = log1pf(expf(temp_in[0]));
    float l[4];
#pragma unroll
    for (int n = 0; n < 4; ++n)
      l[n] = (red[0][n] + red[1][n] + red[2][n] + red[3][n] + bg2[n]) / temp;
    float mx = fmaxf(fmaxf(l[0], l[1]), fmaxf(l[2], l[3]));
    float e[4], s = 0.f;
#pragma unroll
    for (int n = 0; n < 4; ++n) { e[n] = expf(l[n] - mx); s += e[n]; }
    float s2 = 0.f;
#pragma unroll
    for (int n = 0; n < 4; ++n) { e[n] = fmaxf(e[n] / s, 0.02f); s2 += e[n]; }
#pragma unroll
    for (int n = 0; n < 4; ++n) p[m * 4 + n] = e[n] / s2;
  }
}

// ---------------- combine + og stats fused ----------------
__global__ __launch_bounds__(256)
void combine_ogstats(const float* __restrict__ ls, const float* __restrict__ ll,
                     const float* __restrict__ dd, const float* __restrict__ vd,
                     const float* __restrict__ p, const float* __restrict__ resg,
                     const float* __restrict__ crl, float* __restrict__ o,
                     float* __restrict__ og8) {
  __shared__ float part[4][8];
  long bl = blockIdx.x;
  int h = threadIdx.x >> 6, lane = threadIdx.x & 63;
  long base = bl * 1024 + h * 256 + lane * 4;
  float4 lsv = *reinterpret_cast<const float4*>(&ls[base]);
  float4 llv = *reinterpret_cast<const float4*>(&ll[base]);
  float4 ddv = *reinterpret_cast<const float4*>(&dd[base]);
  float4 vdv = *reinterpret_cast<const float4*>(&vd[base]);
  float p0 = p[bl * 4 + 0], p1 = p[bl * 4 + 1], p2 = p[bl * 4 + 2], p3 = p[bl * 4 + 3];
  float sg = sigmf(crl[h]) * resg[bl * 4 + h];
  float c0 = p0 + sg;
  float4 ov;
  ov.x = c0 * lsv.x + p1 * llv.x + p2 * ddv.x + p3 * vdv.x;
  ov.y = c0 * lsv.y + p1 * llv.y + p2 * ddv.y + p3 * vdv.y;
  ov.z = c0 * lsv.z + p1 * llv.z + p2 * ddv.z + p3 * vdv.z;
  ov.w = c0 * lsv.w + p1 * llv.w + p2 * ddv.w + p3 * vdv.w;
  *reinterpret_cast<float4*>(&o[base]) = ov;
  float s = ov.x + ov.y + ov.z + ov.w;
  float q = ov.x * ov.x + ov.y * ov.y + ov.z * ov.z + ov.w * ov.w;
  float a = fabsf(ov.x) + fabsf(ov.y) + fabsf(ov.z) + fabsf(ov.w);
  float sv = vdv.x + vdv.y + vdv.z + vdv.w;
  float qv = vdv.x * vdv.x + vdv.y * vdv.y + vdv.z * vdv.z + vdv.w * vdv.w;
  float av = fabsf(vdv.x) + fabsf(vdv.y) + fabsf(vdv.z) + fabsf(vdv.w);
#pragma unroll
  for (int st = 32; st > 0; st >>= 1) {
    s += __shfl_xor(s, st); q += __shfl_xor(q, st); a += __shfl_xor(a, st);
    sv += __shfl_xor(sv, st); qv += __shfl_xor(qv, st); av += __shfl_xor(av, st);
  }
  if (lane == 0) {
    float mo = s * (1.f / 256.f), mv = sv * (1.f / 256.f);
    part[h][0] = mo; part[h][1] = q * (1.f / 256.f) - mo * mo;
    part[h][2] = a * (1.f / 256.f); part[h][3] = sqrtf(q);
    part[h][4] = mv; part[h][5] = qv * (1.f / 256.f) - mv * mv;
    part[h][6] = av * (1.f / 256.f); part[h][7] = sqrtf(qv);
  }
  __syncthreads();
  if (threadIdx.x < 8) {
    int t = threadIdx.x;
    og8[bl * 8 + t] = 0.25f * (part[0][t] + part[1][t] + part[2][t] + part[3][t]);
  }
}

// ---------------- og gate fused ----------------
__global__ __launch_bounds__(256)
void og_gate_fused(const float* __restrict__ g, const float* __restrict__ og8,
                   const float* __restrict__ Wog1t, const float* __restrict__ bog1,
                   const float* __restrict__ Wog2, const float* __restrict__ bog2,
                   float* __restrict__ ogv) {
  __shared__ float red[4];
  long m = blockIdx.x;
  int tid = threadIdx.x;
  int c0 = tid * 2;
  float2 gv = *reinterpret_cast<const float2*>(&g[m * 512 + c0]);
  float st[8];
#pragma unroll
  for (int k = 0; k < 8; ++k) st[k] = og8[m * 8 + k];
  float a = 0.f;
  float gvv[2] = {gv.x, gv.y};
#pragma unroll
  for (int j = 0; j < 2; ++j) {
    int c = c0 + j;
    float s = gvv[j] + bog1[c];
#pragma unroll
    for (int k = 0; k < 8; ++k) s += st[k] * Wog1t[(long)k * 512 + c];
    a += geluf(s) * Wog2[c];
  }
#pragma unroll
  for (int stp = 32; stp > 0; stp >>= 1) a += __shfl_xor(a, stp);
  int w = tid >> 6;
  if ((tid & 63) == 0) red[w] = a;
  __syncthreads();
  if (tid == 0) ogv[m] = sigmf(red[0] + red[1] + red[2] + red[3] + bog2[0]);
}

// ---------------- wave-parallel scale+rmsnorm -> bf16 ----------------
__global__ __launch_bounds__(256)
void scale_rmsnorm_bf16(const float* __restrict__ o, const float* __restrict__ og,
                        const float* __restrict__ nw, unsigned short* __restrict__ xb) {
  long row = (long)blockIdx.x * 4 + (threadIdx.x >> 6);
  long bl = row >> 2;
  int lane = threadIdx.x & 63;
  float g = og[bl];
  float4 v = *reinterpret_cast<const float4*>(&o[row * 256 + lane * 4]);
  v.x *= g; v.y *= g; v.z *= g; v.w *= g;
  float q = v.x * v.x + v.y * v.y + v.z * v.z + v.w * v.w;
#pragma unroll
  for (int st = 32; st > 0; st >>= 1) q += __shfl_xor(q, st);
  float scale = rsqrtf(q * (1.f / 256.f) + 1e-5f);
  float4 w4 = *reinterpret_cast<const float4*>(&nw[lane * 4]);
  ushort4 r;
  r.x = f2bf(v.x * scale * w4.x);
  r.y = f2bf(v.y * scale * w4.y);
  r.z = f2bf(v.z * scale * w4.z);
  r.w = f2bf(v.w * scale * w4.w);
  *reinterpret_cast<ushort4*>(&xb[row * 256 + lane * 4]) = r;
}

extern "C" void kernel_launch(void* const* d_in, const int* in_sizes, int n_in,
                              void* d_out, int out_size, void* d_ws, size_t ws_size,
                              hipStream_t stream) {
  const float* hs       = (const float*)d_in[0];
  const float* Wq       = (const float*)d_in[1];
  const float* Wk       = (const float*)d_in[2];
  const float* Wv       = (const float*)d_in[3];
  const float* Wb       = (const float*)d_in[4];
  const float* wq_conv  = (const float*)d_in[5];
  const float* wk_conv  = (const float*)d_in[6];
  const float* wv_conv  = (const float*)d_in[7];
  const float* fir_long = (const float*)d_in[8];
  const float* fir_short= (const float*)d_in[9];
  const float* Wg1      = (const float*)d_in[10];
  const float* bg1      = (const float*)d_in[11];
  const float* Wg2      = (const float*)d_in[12];
  const float* bg2      = (const float*)d_in[13];
  const float* logit_temp     = (const float*)d_in[14];
  const float* conv_res_logit = (const float*)d_in[15];
  const float* Wres     = (const float*)d_in[16];
  const float* bres     = (const float*)d_in[17];
  const float* Wog1     = (const float*)d_in[18];
  const float* bog1     = (const float*)d_in[19];
  const float* Wog2     = (const float*)d_in[20];
  const float* bog2     = (const float*)d_in[21];
  const float* norm_w   = (const float*)d_in[22];
  const float* Wo       = (const float*)d_in[23];
  float* out = (float*)d_out;
  float* ws = (float*)d_ws;

  float* b0 = ws;
  float* b1 = ws + 1L * BLD;
  float* b2 = ws + 2L * BLD;
  float* b3 = ws + 3L * BLD;
  float* b4 = ws + 4L * BLD;
  float* sm = ws + 5L * BLD;
  float* beta    = sm;
  float* resg    = beta + BL * H_;
  float* stats16 = resg + BL * H_;
  float* og8     = stats16 + BL * 16;
  float* logits  = og8 + BL * 8;
  float* pbuf    = logits + BL * 4;
  float* ogv     = pbuf + BL * 4;
  unsigned short* q_bfg  = (unsigned short*)(ogv + BL);
  unsigned short* kT_bfg = q_bfg + (long)BLD;
  unsigned short* at_bfg = kT_bfg + (long)BLD;
  unsigned short* hsb  = at_bfg + 1024L * 1024;
  unsigned short* wtq  = hsb + (long)BLD;
  unsigned short* wtk  = wtq + 1024L * 1024;
  unsigned short* wtv  = wtk + 1024L * 1024;
  unsigned short* wtg1 = wtv + 1024L * 1024;
  unsigned short* wto  = wtg1 + 1024L * 1024;
  unsigned short* wtog1= wto + 1024L * 1024;
  unsigned short* w_bfg = (unsigned short*)b4;
  unsigned short* xb    = q_bfg;

  size_t needed = (5L * BLD + BL * 41) * 4
                + (3L * BLD + 1024L * 1024 + 5L * 1024 * 1024 + 512L * 1024) * 2;
  if (ws_size < needed) return;

  dim3 blk(256);
  // 0. preconvert
  wconv_t<<<dim3(32, 32), blk, 0, stream>>>(Wq, wtq, 1024);
  wconv_t<<<dim3(32, 32), blk, 0, stream>>>(Wk, wtk, 1024);
  wconv_t<<<dim3(32, 32), blk, 0, stream>>>(Wv, wtv, 1024);
  wconv_t<<<dim3(32, 32), blk, 0, stream>>>(Wg1, wtg1, 1024);
  wconv_t<<<dim3(32, 32), blk, 0, stream>>>(Wo, wto, 1024);
  wconv_t<<<dim3(16, 32), blk, 0, stream>>>(Wog1, wtog1, 512);
  cvt_bf16<<<BLD / 1024, blk, 0, stream>>>(hs, hsb, BLD);
  // 1. projections (XCD-swizzled 1D grid)
  gemm_bf16<<<512, blk, 0, stream>>>(hsb, wtq, b0, 1024);
  gemm_bf16<<<512, blk, 0, stream>>>(hsb, wtk, b1, 1024);
  gemm_bf16<<<512, blk, 0, stream>>>(hsb, wtv, b2, 1024);
  // 2. conv + silu
  dwconv_tiled<4><<<1024, blk, 0, stream>>>(b0, wq_conv, b3, 1);
  dwconv_tiled<4><<<1024, blk, 0, stream>>>(b1, wk_conv, b0, 1);
  dwconv_tiled<4><<<1024, blk, 0, stream>>>(b2, wv_conv, b1, 1);
  // 3. beta + res gate
  beta_res_gemv<<<BL, blk, 0, stream>>>(hs, Wb, Wres, bres, beta, resg);
  // 4. l2norm
  l2norm_wave<<<BL * H_ / 4, blk, 0, stream>>>(b3);
  l2norm_wave<<<BL * H_ / 4, blk, 0, stream>>>(b0);
  // 5-6. delta rule
  chunk_uw<<<B_ * H_ * NCH, blk, 0, stream>>>(b3, b0, b1, beta, b2, q_bfg, w_bfg, kT_bfg, at_bfg);
  delta_scan<<<128, dim3(64), 0, stream>>>(q_bfg, w_bfg, kT_bfg, at_bfg, b2, b2);
  // 7. local convs
  dwconv_tiled<64><<<1024, blk, 0, stream>>>(b1, fir_long, b3, 0);
  dwconv_tiled<5><<<1024, blk, 0, stream>>>(b1, fir_short, b4, 0);
  // 8. stats16 fused
  head_stats4<<<BL, blk, 0, stream>>>(b4, b3, b2, b1, stats16);
  // 9. gate hidden + fused tail/logits/softmax
  gemm_bf16<<<512, blk, 0, stream>>>(hsb, wtg1, b0, 1024);
  gate_fused<<<BL, blk, 0, stream>>>(b0, stats16, Wg1 + 1024L * 1024, bg1, Wg2, bg2, logit_temp, pbuf);
  // 10. combine + og stats
  combine_ogstats<<<BL, blk, 0, stream>>>(b4, b3, b2, b1, pbuf, resg, conv_res_logit, b0, og8);
  // 11. output gate
  gemm_bf16<<<256, blk, 0, stream>>>(hsb, wtog1, b2, 512);
  og_gate_fused<<<BL, blk, 0, stream>>>(b2, og8, Wog1 + 1024L * 512, bog1, Wog2, bog2, ogv);
  // 12. scale + rmsnorm -> bf16
  scale_rmsnorm_bf16<<<BL * H_ / 4, blk, 0, stream>>>(b0, ogv, norm_w, xb);
  // 13. final projection
  gemm_bf16<<<512, blk, 0, stream>>>(xb, wto, out, 1024);
}

// Round 16
// 933.802 us; speedup vs baseline: 2.9514x; 1.0006x over previous
//
#include <hip/hip_runtime.h>
#include <math.h>

#define B_ 2
#define L_ 4096
#define D_ 1024
#define H_ 4
#define DH 256
#define CHUNKSZ 32
#define NCH (L_/CHUNKSZ)      // 128
#define BL (B_*L_)            // 8192
#define BLD (B_*L_*D_)        // 8388608

typedef __attribute__((ext_vector_type(8))) short bf16x8;
typedef __attribute__((ext_vector_type(4))) float f32x4;

__device__ __forceinline__ float sigmf(float x) { return 1.f / (1.f + expf(-x)); }
__device__ __forceinline__ float geluf(float x) { return 0.5f * x * (1.f + erff(x * 0.70710678118654752f)); }
__device__ __forceinline__ unsigned short f2bf(float f) {
  unsigned int u = __float_as_uint(f);
  unsigned int r = (u + 0x7FFFu + ((u >> 16) & 1u)) >> 16;
  return (unsigned short)r;
}
__device__ __forceinline__ unsigned int pk2bf(float a, float b) {
  return ((unsigned int)f2bf(b) << 16) | (unsigned int)f2bf(a);
}

// ---------------- f32 -> bf16 elementwise (n multiple of 4) ----------------
__global__ __launch_bounds__(256)
void cvt_bf16(const float* __restrict__ x, unsigned short* __restrict__ y, long n) {
  long i = ((long)blockIdx.x * 256 + threadIdx.x) * 4;
  if (i >= n) return;
  float4 v = *reinterpret_cast<const float4*>(&x[i]);
  ushort4 o;
  o.x = f2bf(v.x); o.y = f2bf(v.y); o.z = f2bf(v.z); o.w = f2bf(v.w);
  *reinterpret_cast<ushort4*>(&y[i]) = o;
}

// ---------------- W[k][n] f32 -> Wt[n][k] bf16 (32x32 tiles) ----------------
__global__ __launch_bounds__(256)
void wconv_t(const float* __restrict__ W, unsigned short* __restrict__ Wt, int N) {
  __shared__ float tile[32][33];
  int kb = blockIdx.y * 32, nb = blockIdx.x * 32;
  int tx = threadIdx.x & 31, ty = threadIdx.x >> 5;
  for (int i = 0; i < 32; i += 8)
    tile[ty + i][tx] = W[(long)(kb + ty + i) * N + nb + tx];
  __syncthreads();
  for (int i = 0; i < 32; i += 8)
    Wt[(long)(nb + ty + i) * 1024 + kb + tx] = f2bf(tile[tx][ty + i]);
}

// ---------------- bf16 MFMA GEMM with XCD-aware tile swizzle ----------------
__global__ __launch_bounds__(256)
void gemm_bf16(const unsigned short* __restrict__ A, const unsigned short* __restrict__ Bt,
               float* __restrict__ C, int N) {
  __shared__ unsigned short Al[128 * 32];
  __shared__ unsigned short Bl[128 * 32];
  const int K = 1024;
  int nBn = N >> 7;
  int wgid = blockIdx.x;
  int xcd = wgid & 7;
  int local = wgid >> 3;
  int bm = (xcd * 8 + local / nBn) * 128;
  int bn = (local % nBn) * 128;
  int tid = threadIdx.x;
  int lane = tid & 63, wid = tid >> 6;
  int wr = wid >> 1, wc = wid & 1;
  int l15 = lane & 15, l4 = lane >> 4;
  f32x4 acc[4][4];
#pragma unroll
  for (int i = 0; i < 4; ++i)
#pragma unroll
    for (int j = 0; j < 4; ++j) { acc[i][j].x = 0.f; acc[i][j].y = 0.f; acc[i][j].z = 0.f; acc[i][j].w = 0.f; }
  for (int k0 = 0; k0 < K; k0 += 32) {
    __syncthreads();
#pragma unroll
    for (int i = 0; i < 2; ++i) {
      int idx = tid + i * 256;
      int r = idx >> 2, sl = idx & 3;
      int src = sl ^ ((r >> 1) & 3);
      __builtin_amdgcn_global_load_lds(
          (const __attribute__((address_space(1))) unsigned int*)&A[(long)(bm + r) * K + k0 + src * 8],
          (__attribute__((address_space(3))) unsigned int*)&Al[idx * 8], 16, 0, 0);
      __builtin_amdgcn_global_load_lds(
          (const __attribute__((address_space(1))) unsigned int*)&Bt[(long)(bn + r) * K + k0 + src * 8],
          (__attribute__((address_space(3))) unsigned int*)&Bl[idx * 8], 16, 0, 0);
    }
    __syncthreads();
    bf16x8 af[4], bfr[4];
#pragma unroll
    for (int fi = 0; fi < 4; ++fi) {
      int r = wr * 64 + fi * 16 + l15;
      af[fi] = *reinterpret_cast<const bf16x8*>(&Al[r * 32 + (l4 ^ ((r >> 1) & 3)) * 8]);
    }
#pragma unroll
    for (int fj = 0; fj < 4; ++fj) {
      int r = wc * 64 + fj * 16 + l15;
      bfr[fj] = *reinterpret_cast<const bf16x8*>(&Bl[r * 32 + (l4 ^ ((r >> 1) & 3)) * 8]);
    }
#pragma unroll
    for (int fi = 0; fi < 4; ++fi)
#pragma unroll
      for (int fj = 0; fj < 4; ++fj)
        acc[fi][fj] = __builtin_amdgcn_mfma_f32_16x16x32_bf16(af[fi], bfr[fj], acc[fi][fj], 0, 0, 0);
  }
#pragma unroll
  for (int fi = 0; fi < 4; ++fi) {
    int rb = bm + wr * 64 + fi * 16 + l4 * 4;
#pragma unroll
    for (int fj = 0; fj < 4; ++fj) {
      int cb = bn + wc * 64 + fj * 16 + l15;
#pragma unroll
      for (int j = 0; j < 4; ++j)
        C[(long)(rb + j) * N + cb] = acc[fi][fj][j];
    }
  }
}

// ---------------- tiled depthwise causal conv, sliding-window ----------------
#define CTL 128
template<int K>
__global__ __launch_bounds__(256)
void dwconv_tiled(const float* __restrict__ x, const float* __restrict__ w,
                  float* __restrict__ y, int do_silu) {
  __shared__ float tile[(CTL + K - 1) * 64];
  int bid = blockIdx.x;
  int ct = bid & 15;
  int lt = (bid >> 4) & 31;
  int b  = bid >> 9;
  int c0 = ct * 64;
  int l0 = lt * CTL;
  int tid = threadIdx.x;
  const int rows = CTL + K - 1;
  for (int i = tid; i < rows * 16; i += 256) {
    int rr = i >> 4, c4 = i & 15;
    int l = l0 - (K - 1) + rr;
    float4 v = make_float4(0.f, 0.f, 0.f, 0.f);
    if (l >= 0) v = *reinterpret_cast<const float4*>(&x[((long)b * L_ + l) * D_ + c0 + c4 * 4]);
    *reinterpret_cast<float4*>(&tile[rr * 64 + c4 * 4]) = v;
  }
  __syncthreads();
  int c = tid & 63;
  int wv = tid >> 6;
  float wreg[K];
#pragma unroll
  for (int j = 0; j < K; ++j) wreg[j] = w[(long)(c0 + c) * K + j];
#pragma unroll
  for (int g = 0; g < 4; ++g) {
    int lo_base = g * 32 + wv * 8;
    float win[8];
#pragma unroll
    for (int r = 0; r < 8; ++r) win[r] = tile[(lo_base + r) * 64 + c];
    float acc[8] = {0.f, 0.f, 0.f, 0.f, 0.f, 0.f, 0.f, 0.f};
#pragma unroll
    for (int j = 0; j < K; ++j) {
#pragma unroll
      for (int r = 0; r < 8; ++r) acc[r] = fmaf(wreg[j], win[r], acc[r]);
      if (j < K - 1) {
#pragma unroll
        for (int r = 0; r < 7; ++r) win[r] = win[r + 1];
        win[7] = tile[(lo_base + j + 8) * 64 + c];
      }
    }
#pragma unroll
    for (int r = 0; r < 8; ++r) {
      float v = acc[r];
      if (do_silu) v = v * sigmf(v);
      y[((long)b * L_ + l0 + lo_base + r) * D_ + c0 + c] = v;
    }
  }
}

// ---------------- wave-parallel l2norm ----------------
__global__ __launch_bounds__(256)
void l2norm_wave(float* __restrict__ x) {
  long row = (long)blockIdx.x * 4 + (threadIdx.x >> 6);
  int lane = threadIdx.x & 63;
  float4 v = *reinterpret_cast<const float4*>(&x[row * 256 + lane * 4]);
  float q = v.x * v.x + v.y * v.y + v.z * v.z + v.w * v.w;
#pragma unroll
  for (int st = 32; st > 0; st >>= 1) q += __shfl_xor(q, st);
  float inv = rsqrtf(q + 1e-6f);
  v.x *= inv; v.y *= inv; v.z *= inv; v.w *= inv;
  *reinterpret_cast<float4*>(&x[row * 256 + lane * 4]) = v;
}

// ---------------- fused beta/resg GEMV ----------------
__global__ __launch_bounds__(256)
void beta_res_gemv(const float* __restrict__ hs, const float* __restrict__ Wb,
                   const float* __restrict__ Wres, const float* __restrict__ bres,
                   float* __restrict__ beta, float* __restrict__ resg) {
  long m = blockIdx.x;
  int n = threadIdx.x >> 6, lane = threadIdx.x & 63;
  float ab = 0.f, ar = 0.f;
  for (int k0 = lane * 4; k0 < 1024; k0 += 256) {
    float4 x = *reinterpret_cast<const float4*>(&hs[m * 1024 + k0]);
    ab += x.x * Wb[(k0 + 0) * 4 + n] + x.y * Wb[(k0 + 1) * 4 + n]
        + x.z * Wb[(k0 + 2) * 4 + n] + x.w * Wb[(k0 + 3) * 4 + n];
    ar += x.x * Wres[(k0 + 0) * 4 + n] + x.y * Wres[(k0 + 1) * 4 + n]
        + x.z * Wres[(k0 + 2) * 4 + n] + x.w * Wres[(k0 + 3) * 4 + n];
  }
#pragma unroll
  for (int st = 32; st > 0; st >>= 1) { ab += __shfl_xor(ab, st); ar += __shfl_xor(ar, st); }
  if (lane == 0) {
    beta[m * 4 + n] = sigmf(ab);
    resg[m * 4 + n] = sigmf(ar + bres[n]);
  }
}

// ---------------- per-chunk: inv, u, bf16 scan operands ----------------
__global__ __launch_bounds__(256)
void chunk_uw(const float* __restrict__ qn, const float* __restrict__ kn,
              const float* __restrict__ v, const float* __restrict__ beta,
              float* __restrict__ u,
              unsigned short* __restrict__ q_bf, unsigned short* __restrict__ w_bf,
              unsigned short* __restrict__ kT_bf, unsigned short* __restrict__ at_bf) {
  __shared__ float skT[256][33];
  __shared__ float sinv[32][33];
  __shared__ float sbeta[32];
  int blk = blockIdx.x;
  int ci = blk % NCH;
  int bh = blk / NCH;
  int h = bh % H_;
  int b = bh / H_;
  long base = ((long)b * L_ + (long)ci * CHUNKSZ) * D_ + h * DH;
  long brow = (long)b * L_ + (long)ci * CHUNKSZ;
  long obase = (long)blk * 8192;
  int tid = threadIdx.x;
  for (int i = tid; i < 32 * 256; i += 256) {
    int r = i >> 8, c = i & 255;
    skT[c][r] = kn[base + (long)r * D_ + c];
  }
  if (tid < 32) sbeta[tid] = beta[(brow + tid) * H_ + h];
  __syncthreads();
  for (int i = tid; i < 8192; i += 256)
    kT_bf[obase + i] = f2bf(skT[i >> 5][i & 31]);
  for (int i = tid; i < 8192; i += 256)
    q_bf[obase + i] = f2bf(qn[base + (long)(i >> 8) * D_ + (i & 255)]);
  int j = tid & 31, i0 = tid >> 5;
  for (int r = 0; r < 4; ++r) {
    int i = i0 + (r << 3);
    float acc = 0.f;
    for (int d = 0; d < 256; ++d) acc += skT[d][i] * skT[d][j];
    sinv[i][j] = (i > j) ? -acc * sbeta[i] : 0.f;
  }
  __syncthreads();
  for (int i = 1; i < 32; ++i) {
    float val = 0.f;
    if (tid < 32) {
      for (int t = 0; t < i; ++t) val += sinv[i][t] * sinv[t][tid];
    }
    __syncthreads();
    if (tid < 32) sinv[i][tid] += val;
    __syncthreads();
  }
  if (tid < 32) sinv[tid][tid] += 1.f;
  long abase = (long)blk * 1024;
  for (int r = 0; r < 4; ++r) {
    int i = i0 + (r << 3);
    const float* qrow = qn + base + (long)i * D_;
    float acc = 0.f;
    for (int d = 0; d < 256; ++d) acc += qrow[d] * skT[d][j];
    at_bf[abase + i * 32 + j] = f2bf((i >= j) ? acc : 0.f);
  }
  __syncthreads();
  int c = tid;
  float vt[32], kt[32];
#pragma unroll
  for (int t = 0; t < 32; ++t) {
    vt[t] = v[base + t * D_ + c] * sbeta[t];
    kt[t] = skT[c][t] * sbeta[t];
  }
#pragma unroll
  for (int i2 = 0; i2 < 32; ++i2) {
    float au = 0.f, aw = 0.f;
#pragma unroll
    for (int t = 0; t <= i2; ++t) {
      float f = sinv[i2][t];
      au += f * vt[t];
      aw += f * kt[t];
    }
    u[base + i2 * D_ + c] = au;
    w_bf[obase + i2 * 256 + c] = f2bf(aw);
  }
}

// ---------------- MFMA scan: 128 blocks x 1 wave, barrier-free ----------------
// u/out point into the SAME buffer (in-place) but every address is touched exactly once
// by each pointer class and u[rows of chunk ci] are consumed (feeding out's value through
// registers) strictly before out[ci] stores them -> __restrict__ on BOTH is access-disjoint
// and removes the legalizer's per-chunk vmcnt(0) drain between out stores and u loads.
__global__ __launch_bounds__(64, 1)
void delta_scan(const unsigned short* __restrict__ qb, const unsigned short* __restrict__ wbf,
                const unsigned short* __restrict__ ktb, const unsigned short* __restrict__ atb,
                const float* __restrict__ u, float* __restrict__ out) {
  __shared__ unsigned short sB[16 * 264];
  __shared__ unsigned short su2[16 * 40];
  int blk = blockIdx.x;
  int bh = blk & 7, cg = blk >> 3;
  int h = bh & 3, b = bh >> 2;
  int lane = threadIdx.x;
  int l15 = lane & 15, l4 = lane >> 4;
  int colw = cg * 16;

  f32x4 zero4; zero4.x = 0.f; zero4.y = 0.f; zero4.z = 0.f; zero4.w = 0.f;
  f32x4 acc[16];
#pragma unroll
  for (int t = 0; t < 16; ++t) acc[t] = zero4;

  uint4 wf[2][8];
  float ru[2][4];
  uint4 qf[2][8];
  uint4 kfa[8], kfb[8];
  uint4 af[2];

#define LOAD_W(CI) do {                                                          \
    long o8_ = ((long)bh * NCH + (CI)) * 8192;                                   \
    _Pragma("unroll")                                                            \
    for (int m_ = 0; m_ < 2; ++m_)                                               \
      _Pragma("unroll")                                                          \
      for (int kc_ = 0; kc_ < 8; ++kc_)                                          \
        wf[m_][kc_] = *reinterpret_cast<const uint4*>(                           \
            &wbf[o8_ + (16 * m_ + l15) * 256 + kc_ * 32 + l4 * 8]);              \
  } while (0)

#define LOAD_U(CI) do {                                                          \
    long ub_ = ((long)b * L_ + (long)(CI) * CHUNKSZ) * D_ + h * DH + colw;       \
    _Pragma("unroll")                                                            \
    for (int m_ = 0; m_ < 2; ++m_)                                               \
      _Pragma("unroll")                                                          \
      for (int r_ = 0; r_ < 4; ++r_)                                             \
        ru[m_][r_] = u[ub_ + (long)(16 * m_ + 4 * l4 + r_) * D_ + l15];          \
  } while (0)

#define LOAD_Q(CI) do {                                                          \
    long o8_ = ((long)bh * NCH + (CI)) * 8192;                                   \
    _Pragma("unroll")                                                            \
    for (int m_ = 0; m_ < 2; ++m_)                                               \
      _Pragma("unroll")                                                          \
      for (int kc_ = 0; kc_ < 8; ++kc_)                                          \
        qf[m_][kc_] = *reinterpret_cast<const uint4*>(                           \
            &qb[o8_ + (16 * m_ + l15) * 256 + kc_ * 32 + l4 * 8]);               \
  } while (0)

#define LOAD_KA(CI) do {                                                         \
    long o8_ = ((long)bh * NCH + (CI)) * 8192;                                   \
    _Pragma("unroll")                                                            \
    for (int dt_ = 0; dt_ < 8; ++dt_)                                            \
      kfa[dt_] = *reinterpret_cast<const uint4*>(                                \
          &ktb[o8_ + (16 * dt_ + l15) * 32 + l4 * 8]);                           \
  } while (0)

#define LOAD_KB(CI) do {                                                         \
    long o8_ = ((long)bh * NCH + (CI)) * 8192;                                   \
    _Pragma("unroll")                                                            \
    for (int dt_ = 0; dt_ < 8; ++dt_)                                            \
      kfb[dt_] = *reinterpret_cast<const uint4*>(                                \
          &ktb[o8_ + (16 * (dt_ + 8) + l15) * 32 + l4 * 8]);                     \
  } while (0)

#define LOAD_A(CI) do {                                                          \
    long oa_ = ((long)bh * NCH + (CI)) * 1024;                                   \
    _Pragma("unroll")                                                            \
    for (int m_ = 0; m_ < 2; ++m_)                                               \
      af[m_] = *reinterpret_cast<const uint4*>(                                  \
          &atb[oa_ + (16 * m_ + l15) * 32 + l4 * 8]);                            \
  } while (0)

#define SCAN_BODY(CI, PF) do {                                                   \
    long ub = ((long)b * L_ + (long)(CI) * CHUNKSZ) * D_ + h * DH + colw;        \
    _Pragma("unroll")                                                            \
    for (int dt = 0; dt < 16; ++dt) {                                            \
      uint2 pv;                                                                  \
      pv.x = pk2bf(acc[dt].x, acc[dt].y);                                        \
      pv.y = pk2bf(acc[dt].z, acc[dt].w);                                        \
      *reinterpret_cast<uint2*>(&sB[l15 * 264 + dt * 16 + l4 * 4]) = pv;         \
    }                                                                            \
    bf16x8 sf[8];                                                                \
    _Pragma("unroll")                                                            \
    for (int kc = 0; kc < 8; ++kc)                                               \
      sf[kc] = *reinterpret_cast<const bf16x8*>(&sB[l15 * 264 + kc * 32 + l4 * 8]); \
    f32x4 wa[2][2];                                                              \
    wa[0][0] = zero4; wa[0][1] = zero4; wa[1][0] = zero4; wa[1][1] = zero4;      \
    _Pragma("unroll")                                                            \
    for (int kc = 0; kc < 8; ++kc) {                                             \
      _Pragma("unroll")                                                          \
      for (int m = 0; m < 2; ++m)                                                \
        wa[m][kc & 1] = __builtin_amdgcn_mfma_f32_16x16x32_bf16(                 \
            *reinterpret_cast<bf16x8*>(&wf[m][kc]), sf[kc], wa[m][kc & 1], 0, 0, 0); \
    }                                                                            \
    if (PF) LOAD_W((CI) + 1);                                                    \
    _Pragma("unroll")                                                            \
    for (int m = 0; m < 2; ++m) {                                                \
      f32x4 wsum = wa[m][0] + wa[m][1];                                          \
      uint2 pv;                                                                  \
      pv.x = pk2bf(ru[m][0] - wsum.x, ru[m][1] - wsum.y);                        \
      pv.y = pk2bf(ru[m][2] - wsum.z, ru[m][3] - wsum.w);                        \
      *reinterpret_cast<uint2*>(&su2[l15 * 40 + m * 16 + l4 * 4]) = pv;          \
    }                                                                            \
    if (PF) LOAD_U((CI) + 1);                                                    \
    bf16x8 u2f = *reinterpret_cast<const bf16x8*>(&su2[l15 * 40 + l4 * 8]);      \
    _Pragma("unroll")                                                            \
    for (int dt = 0; dt < 8; ++dt)                                               \
      acc[dt] = __builtin_amdgcn_mfma_f32_16x16x32_bf16(                         \
          *reinterpret_cast<bf16x8*>(&kfa[dt]), u2f, acc[dt], 0, 0, 0);          \
    if (PF) LOAD_KA((CI) + 1);                                                   \
    _Pragma("unroll")                                                            \
    for (int dt = 0; dt < 8; ++dt)                                               \
      acc[dt + 8] = __builtin_amdgcn_mfma_f32_16x16x32_bf16(                     \
          *reinterpret_cast<bf16x8*>(&kfb[dt]), u2f, acc[dt + 8], 0, 0, 0);      \
    if (PF) LOAD_KB((CI) + 1);                                                   \
    f32x4 qa[2][2];                                                              \
    qa[0][0] = zero4; qa[0][1] = zero4; qa[1][0] = zero4; qa[1][1] = zero4;      \
    _Pragma("unroll")                                                            \
    for (int kc = 0; kc < 8; ++kc) {                                             \
      _Pragma("unroll")                                                          \
      for (int m = 0; m < 2; ++m)                                                \
        qa[m][kc & 1] = __builtin_amdgcn_mfma_f32_16x16x32_bf16(                 \
            *reinterpret_cast<bf16x8*>(&qf[m][kc]), sf[kc], qa[m][kc & 1], 0, 0, 0); \
    }                                                                            \
    if (PF) LOAD_Q((CI) + 1);                                                    \
    _Pragma("unroll")                                                            \
    for (int m = 0; m < 2; ++m) {                                                \
      f32x4 qacc = qa[m][0] + qa[m][1];                                          \
      f32x4 dv = __builtin_amdgcn_mfma_f32_16x16x32_bf16(                        \
          *reinterpret_cast<bf16x8*>(&af[m]), u2f, qacc, 0, 0, 0);               \
      _Pragma("unroll")                                                          \
      for (int r = 0; r < 4; ++r)                                                \
        out[ub + (long)(16 * m + 4 * l4 + r) * D_ + l15] = dv[r];                \
    }                                                                            \
    if (PF) LOAD_A((CI) + 1);                                                    \
  } while (0)

  LOAD_W(0); LOAD_U(0); LOAD_Q(0); LOAD_KA(0); LOAD_KB(0); LOAD_A(0);

  for (int ci = 0; ci < NCH - 1; ++ci) {
    SCAN_BODY(ci, 1);
  }
  SCAN_BODY(NCH - 1, 0);

#undef LOAD_W
#undef LOAD_U
#undef LOAD_Q
#undef LOAD_KA
#undef LOAD_KB
#undef LOAD_A
#undef SCAN_BODY
}

// ---------------- fused head stats x4 tensors ----------------
__global__ __launch_bounds__(256)
void head_stats4(const float* __restrict__ t0, const float* __restrict__ t1,
                 const float* __restrict__ t2, const float* __restrict__ t3,
                 float* __restrict__ outp) {
  long bl = blockIdx.x;
  int w = threadIdx.x >> 6, lane = threadIdx.x & 63;
  const float* x = (w == 0) ? t0 : (w == 1) ? t1 : (w == 2) ? t2 : t3;
  float m = 0.f, vv = 0.f, am = 0.f, l2 = 0.f;
#pragma unroll
  for (int h = 0; h < 4; ++h) {
    float4 v = *reinterpret_cast<const float4*>(&x[bl * 1024 + h * 256 + lane * 4]);
    float s = v.x + v.y + v.z + v.w;
    float q = v.x * v.x + v.y * v.y + v.z * v.z + v.w * v.w;
    float a = fabsf(v.x) + fabsf(v.y) + fabsf(v.z) + fabsf(v.w);
#pragma unroll
    for (int st = 32; st > 0; st >>= 1) {
      s += __shfl_xor(s, st); q += __shfl_xor(q, st); a += __shfl_xor(a, st);
    }
    float mean = s * (1.f / 256.f);
    m += mean;
    vv += q * (1.f / 256.f) - mean * mean;
    am += a * (1.f / 256.f);
    l2 += sqrtf(q);
  }
  if (lane == 0) {
    float* o = outp + bl * 16 + w * 4;
    o[0] = m * 0.25f; o[1] = vv * 0.25f; o[2] = am * 0.25f; o[3] = l2 * 0.25f;
  }
}

// ---------------- gate fused ----------------
__global__ __launch_bounds__(256)
void gate_fused(const float* __restrict__ g, const float* __restrict__ stats,
                const float* __restrict__ Wg1t, const float* __restrict__ bg1,
                const float* __restrict__ Wg2, const float* __restrict__ bg2,
                const float* __restrict__ temp_in, float* __restrict__ p) {
  __shared__ float red[4][4];
  long m = blockIdx.x;
  int tid = threadIdx.x;
  int c0 = tid * 4;
  float4 gv = *reinterpret_cast<const float4*>(&g[m * 1024 + c0]);
  float st[16];
#pragma unroll
  for (int k = 0; k < 16; ++k) st[k] = stats[m * 16 + k];
  float la[4] = {0.f, 0.f, 0.f, 0.f};
  float gvv[4] = {gv.x, gv.y, gv.z, gv.w};
#pragma unroll
  for (int j = 0; j < 4; ++j) {
    int c = c0 + j;
    float s = gvv[j] + bg1[c];
#pragma unroll
    for (int k = 0; k < 16; ++k) s += st[k] * Wg1t[(long)k * 1024 + c];
    float ge = geluf(s);
#pragma unroll
    for (int n = 0; n < 4; ++n) la[n] += ge * Wg2[c * 4 + n];
  }
#pragma unroll
  for (int stp = 32; stp > 0; stp >>= 1)
#pragma unroll
    for (int n = 0; n < 4; ++n) la[n] += __shfl_xor(la[n], stp);
  int w = tid >> 6;
  if ((tid & 63) == 0) {
#pragma unroll
    for (int n = 0; n < 4; ++n) red[w][n] = la[n];
  }
  __syncthreads();
  if (tid == 0) {
    float temp = log1pf(expf(temp_in[0]));
    float l[4];
#pragma unroll
    for (int n = 0; n < 4; ++n)
      l[n] = (red[0][n] + red[1][n] + red[2][n] + red[3][n] + bg2[n]) / temp;
    float mx = fmaxf(fmaxf(l[0], l[1]), fmaxf(l[2], l[3]));
    float e[4], s = 0.f;
#pragma unroll
    for (int n = 0; n < 4; ++n) { e[n] = expf(l[n] - mx); s += e[n]; }
    float s2 = 0.f;
#pragma unroll
    for (int n = 0; n < 4; ++n) { e[n] = fmaxf(e[n] / s, 0.02f); s2 += e[n]; }
#pragma unroll
    for (int n = 0; n < 4; ++n) p[m * 4 + n] = e[n] / s2;
  }
}

// ---------------- combine + og stats fused ----------------
__global__ __launch_bounds__(256)
void combine_ogstats(const float* __restrict__ ls, const float* __restrict__ ll,
                     const float* __restrict__ dd, const float* __restrict__ vd,
                     const float* __restrict__ p, const float* __restrict__ resg,
                     const float* __restrict__ crl, float* __restrict__ o,
                     float* __restrict__ og8) {
  __shared__ float part[4][8];
  long bl = blockIdx.x;
  int h = threadIdx.x >> 6, lane = threadIdx.x & 63;
  long base = bl * 1024 + h * 256 + lane * 4;
  float4 lsv = *reinterpret_cast<const float4*>(&ls[base]);
  float4 llv = *reinterpret_cast<const float4*>(&ll[base]);
  float4 ddv = *reinterpret_cast<const float4*>(&dd[base]);
  float4 vdv = *reinterpret_cast<const float4*>(&vd[base]);
  float p0 = p[bl * 4 + 0], p1 = p[bl * 4 + 1], p2 = p[bl * 4 + 2], p3 = p[bl * 4 + 3];
  float sg = sigmf(crl[h]) * resg[bl * 4 + h];
  float c0 = p0 + sg;
  float4 ov;
  ov.x = c0 * lsv.x + p1 * llv.x + p2 * ddv.x + p3 * vdv.x;
  ov.y = c0 * lsv.y + p1 * llv.y + p2 * ddv.y + p3 * vdv.y;
  ov.z = c0 * lsv.z + p1 * llv.z + p2 * ddv.z + p3 * vdv.z;
  ov.w = c0 * lsv.w + p1 * llv.w + p2 * ddv.w + p3 * vdv.w;
  *reinterpret_cast<float4*>(&o[base]) = ov;
  float s = ov.x + ov.y + ov.z + ov.w;
  float q = ov.x * ov.x + ov.y * ov.y + ov.z * ov.z + ov.w * ov.w;
  float a = fabsf(ov.x) + fabsf(ov.y) + fabsf(ov.z) + fabsf(ov.w);
  float sv = vdv.x + vdv.y + vdv.z + vdv.w;
  float qv = vdv.x * vdv.x + vdv.y * vdv.y + vdv.z * vdv.z + vdv.w * vdv.w;
  float av = fabsf(vdv.x) + fabsf(vdv.y) + fabsf(vdv.z) + fabsf(vdv.w);
#pragma unroll
  for (int st = 32; st > 0; st >>= 1) {
    s += __shfl_xor(s, st); q += __shfl_xor(q, st); a += __shfl_xor(a, st);
    sv += __shfl_xor(sv, st); qv += __shfl_xor(qv, st); av += __shfl_xor(av, st);
  }
  if (lane == 0) {
    float mo = s * (1.f / 256.f), mv = sv * (1.f / 256.f);
    part[h][0] = mo; part[h][1] = q * (1.f / 256.f) - mo * mo;
    part[h][2] = a * (1.f / 256.f); part[h][3] = sqrtf(q);
    part[h][4] = mv; part[h][5] = qv * (1.f / 256.f) - mv * mv;
    part[h][6] = av * (1.f / 256.f); part[h][7] = sqrtf(qv);
  }
  __syncthreads();
  if (threadIdx.x < 8) {
    int t = threadIdx.x;
    og8[bl * 8 + t] = 0.25f * (part[0][t] + part[1][t] + part[2][t] + part[3][t]);
  }
}

// ---------------- og gate fused ----------------
__global__ __launch_bounds__(256)
void og_gate_fused(const float* __restrict__ g, const float* __restrict__ og8,
                   const float* __restrict__ Wog1t, const float* __restrict__ bog1,
                   const float* __restrict__ Wog2, const float* __restrict__ bog2,
                   float* __restrict__ ogv) {
  __shared__ float red[4];
  long m = blockIdx.x;
  int tid = threadIdx.x;
  int c0 = tid * 2;
  float2 gv = *reinterpret_cast<const float2*>(&g[m * 512 + c0]);
  float st[8];
#pragma unroll
  for (int k = 0; k < 8; ++k) st[k] = og8[m * 8 + k];
  float a = 0.f;
  float gvv[2] = {gv.x, gv.y};
#pragma unroll
  for (int j = 0; j < 2; ++j) {
    int c = c0 + j;
    float s = gvv[j] + bog1[c];
#pragma unroll
    for (int k = 0; k < 8; ++k) s += st[k] * Wog1t[(long)k * 512 + c];
    a += geluf(s) * Wog2[c];
  }
#pragma unroll
  for (int stp = 32; stp > 0; stp >>= 1) a += __shfl_xor(a, stp);
  int w = tid >> 6;
  if ((tid & 63) == 0) red[w] = a;
  __syncthreads();
  if (tid == 0) ogv[m] = sigmf(red[0] + red[1] + red[2] + red[3] + bog2[0]);
}

// ---------------- wave-parallel scale+rmsnorm -> bf16 ----------------
__global__ __launch_bounds__(256)
void scale_rmsnorm_bf16(const float* __restrict__ o, const float* __restrict__ og,
                        const float* __restrict__ nw, unsigned short* __restrict__ xb) {
  long row = (long)blockIdx.x * 4 + (threadIdx.x >> 6);
  long bl = row >> 2;
  int lane = threadIdx.x & 63;
  float g = og[bl];
  float4 v = *reinterpret_cast<const float4*>(&o[row * 256 + lane * 4]);
  v.x *= g; v.y *= g; v.z *= g; v.w *= g;
  float q = v.x * v.x + v.y * v.y + v.z * v.z + v.w * v.w;
#pragma unroll
  for (int st = 32; st > 0; st >>= 1) q += __shfl_xor(q, st);
  float scale = rsqrtf(q * (1.f / 256.f) + 1e-5f);
  float4 w4 = *reinterpret_cast<const float4*>(&nw[lane * 4]);
  ushort4 r;
  r.x = f2bf(v.x * scale * w4.x);
  r.y = f2bf(v.y * scale * w4.y);
  r.z = f2bf(v.z * scale * w4.z);
  r.w = f2bf(v.w * scale * w4.w);
  *reinterpret_cast<ushort4*>(&xb[row * 256 + lane * 4]) = r;
}

extern "C" void kernel_launch(void* const* d_in, const int* in_sizes, int n_in,
                              void* d_out, int out_size, void* d_ws, size_t ws_size,
                              hipStream_t stream) {
  const float* hs       = (const float*)d_in[0];
  const float* Wq       = (const float*)d_in[1];
  const float* Wk       = (const float*)d_in[2];
  const float* Wv       = (const float*)d_in[3];
  const float* Wb       = (const float*)d_in[4];
  const float* wq_conv  = (const float*)d_in[5];
  const float* wk_conv  = (const float*)d_in[6];
  const float* wv_conv  = (const float*)d_in[7];
  const float* fir_long = (const float*)d_in[8];
  const float* fir_short= (const float*)d_in[9];
  const float* Wg1      = (const float*)d_in[10];
  const float* bg1      = (const float*)d_in[11];
  const float* Wg2      = (const float*)d_in[12];
  const float* bg2      = (const float*)d_in[13];
  const float* logit_temp     = (const float*)d_in[14];
  const float* conv_res_logit = (const float*)d_in[15];
  const float* Wres     = (const float*)d_in[16];
  const float* bres     = (const float*)d_in[17];
  const float* Wog1     = (const float*)d_in[18];
  const float* bog1     = (const float*)d_in[19];
  const float* Wog2     = (const float*)d_in[20];
  const float* bog2     = (const float*)d_in[21];
  const float* norm_w   = (const float*)d_in[22];
  const float* Wo       = (const float*)d_in[23];
  float* out = (float*)d_out;
  float* ws = (float*)d_ws;

  float* b0 = ws;
  float* b1 = ws + 1L * BLD;
  float* b2 = ws + 2L * BLD;
  float* b3 = ws + 3L * BLD;
  float* b4 = ws + 4L * BLD;
  float* sm = ws + 5L * BLD;
  float* beta    = sm;
  float* resg    = beta + BL * H_;
  float* stats16 = resg + BL * H_;
  float* og8     = stats16 + BL * 16;
  float* logits  = og8 + BL * 8;
  float* pbuf    = logits + BL * 4;
  float* ogv     = pbuf + BL * 4;
  unsigned short* q_bfg  = (unsigned short*)(ogv + BL);
  unsigned short* kT_bfg = q_bfg + (long)BLD;
  unsigned short* at_bfg = kT_bfg + (long)BLD;
  unsigned short* hsb  = at_bfg + 1024L * 1024;
  unsigned short* wtq  = hsb + (long)BLD;
  unsigned short* wtk  = wtq + 1024L * 1024;
  unsigned short* wtv  = wtk + 1024L * 1024;
  unsigned short* wtg1 = wtv + 1024L * 1024;
  unsigned short* wto  = wtg1 + 1024L * 1024;
  unsigned short* wtog1= wto + 1024L * 1024;
  unsigned short* w_bfg = (unsigned short*)b4;
  unsigned short* xb    = q_bfg;

  size_t needed = (5L * BLD + BL * 41) * 4
                + (3L * BLD + 1024L * 1024 + 5L * 1024 * 1024 + 512L * 1024) * 2;
  if (ws_size < needed) return;

  dim3 blk(256);
  // 0. preconvert
  wconv_t<<<dim3(32, 32), blk, 0, stream>>>(Wq, wtq, 1024);
  wconv_t<<<dim3(32, 32), blk, 0, stream>>>(Wk, wtk, 1024);
  wconv_t<<<dim3(32, 32), blk, 0, stream>>>(Wv, wtv, 1024);
  wconv_t<<<dim3(32, 32), blk, 0, stream>>>(Wg1, wtg1, 1024);
  wconv_t<<<dim3(32, 32), blk, 0, stream>>>(Wo, wto, 1024);
  wconv_t<<<dim3(16, 32), blk, 0, stream>>>(Wog1, wtog1, 512);
  cvt_bf16<<<BLD / 1024, blk, 0, stream>>>(hs, hsb, BLD);
  // 1. projections (XCD-swizzled 1D grid)
  gemm_bf16<<<512, blk, 0, stream>>>(hsb, wtq, b0, 1024);
  gemm_bf16<<<512, blk, 0, stream>>>(hsb, wtk, b1, 1024);
  gemm_bf16<<<512, blk, 0, stream>>>(hsb, wtv, b2, 1024);
  // 2. conv + silu
  dwconv_tiled<4><<<1024, blk, 0, stream>>>(b0, wq_conv, b3, 1);
  dwconv_tiled<4><<<1024, blk, 0, stream>>>(b1, wk_conv, b0, 1);
  dwconv_tiled<4><<<1024, blk, 0, stream>>>(b2, wv_conv, b1, 1);
  // 3. beta + res gate
  beta_res_gemv<<<BL, blk, 0, stream>>>(hs, Wb, Wres, bres, beta, resg);
  // 4. l2norm
  l2norm_wave<<<BL * H_ / 4, blk, 0, stream>>>(b3);
  l2norm_wave<<<BL * H_ / 4, blk, 0, stream>>>(b0);
  // 5-6. delta rule
  chunk_uw<<<B_ * H_ * NCH, blk, 0, stream>>>(b3, b0, b1, beta, b2, q_bfg, w_bfg, kT_bfg, at_bfg);
  delta_scan<<<128, dim3(64), 0, stream>>>(q_bfg, w_bfg, kT_bfg, at_bfg, b2, b2);
  // 7. local convs
  dwconv_tiled<64><<<1024, blk, 0, stream>>>(b1, fir_long, b3, 0);
  dwconv_tiled<5><<<1024, blk, 0, stream>>>(b1, fir_short, b4, 0);
  // 8. stats16 fused
  head_stats4<<<BL, blk, 0, stream>>>(b4, b3, b2, b1, stats16);
  // 9. gate hidden + fused tail/logits/softmax
  gemm_bf16<<<512, blk, 0, stream>>>(hsb, wtg1, b0, 1024);
  gate_fused<<<BL, blk, 0, stream>>>(b0, stats16, Wg1 + 1024L * 1024, bg1, Wg2, bg2, logit_temp, pbuf);
  // 10. combine + og stats
  combine_ogstats<<<BL, blk, 0, stream>>>(b4, b3, b2, b1, pbuf, resg, conv_res_logit, b0, og8);
  // 11. output gate
  gemm_bf16<<<256, blk, 0, stream>>>(hsb, wtog1, b2, 512);
  og_gate_fused<<<BL, blk, 0, stream>>>(b2, og8, Wog1 + 1024L * 512, bog1, Wog2, bog2, ogv);
  // 12. scale + rmsnorm -> bf16
  scale_rmsnorm_bf16<<<BL * H_ / 4, blk, 0, stream>>>(b0, ogv, norm_w, xb);
  // 13. final projection
  gemm_bf16<<<512, blk, 0, stream>>>(xb, wto, out, 1024);
}

// Round 17
// 806.608 us; speedup vs baseline: 3.4169x; 1.1577x over previous
//
#include <hip/hip_runtime.h>
#include <math.h>

#define B_ 2
#define L_ 4096
#define D_ 1024
#define H_ 4
#define DH 256
#define CHUNKSZ 32
#define NCH (L_/CHUNKSZ)      // 128
#define BL (B_*L_)            // 8192
#define BLD (B_*L_*D_)        // 8388608

typedef __attribute__((ext_vector_type(8))) short bf16x8;
typedef __attribute__((ext_vector_type(4))) float f32x4;

__device__ __forceinline__ float sigmf(float x) { return 1.f / (1.f + expf(-x)); }
__device__ __forceinline__ float geluf(float x) { return 0.5f * x * (1.f + erff(x * 0.70710678118654752f)); }
__device__ __forceinline__ unsigned short f2bf(float f) {
  unsigned int u = __float_as_uint(f);
  unsigned int r = (u + 0x7FFFu + ((u >> 16) & 1u)) >> 16;
  return (unsigned short)r;
}
__device__ __forceinline__ unsigned int pk2bf(float a, float b) {
  return ((unsigned int)f2bf(b) << 16) | (unsigned int)f2bf(a);
}

// ---------------- ALL weight transposes in one launch ----------------
// bids [0,5120): 5 full 1024x1024 weights (Wq,Wk,Wv,Wg1,Wo); [5120,5632): Wog1 (512 cols)
__global__ __launch_bounds__(256)
void wconv_all(const float* __restrict__ Wq, const float* __restrict__ Wk,
               const float* __restrict__ Wv, const float* __restrict__ Wg1,
               const float* __restrict__ Wog1, const float* __restrict__ Wo,
               unsigned short* __restrict__ wtq, unsigned short* __restrict__ wtk,
               unsigned short* __restrict__ wtv, unsigned short* __restrict__ wtg1,
               unsigned short* __restrict__ wtog1, unsigned short* __restrict__ wto) {
  __shared__ float tile[32][33];
  int bid = blockIdx.x;
  const float* W; unsigned short* Wt; int N; int rem;
  if (bid < 5120) {
    int widx = bid >> 10; rem = bid & 1023; N = 1024;
    switch (widx) {
      case 0: W = Wq; Wt = wtq; break;
      case 1: W = Wk; Wt = wtk; break;
      case 2: W = Wv; Wt = wtv; break;
      case 3: W = Wg1; Wt = wtg1; break;
      default: W = Wo; Wt = wto; break;
    }
  } else { rem = bid - 5120; N = 512; W = Wog1; Wt = wtog1; }
  int nT = N >> 5;
  int nb = (rem % nT) * 32, kb = (rem / nT) * 32;
  int tx = threadIdx.x & 31, ty = threadIdx.x >> 5;
  for (int i = 0; i < 32; i += 8)
    tile[ty + i][tx] = W[(long)(kb + ty + i) * N + nb + tx];
  __syncthreads();
  for (int i = 0; i < 32; i += 8)
    Wt[(long)(nb + ty + i) * 1024 + kb + tx] = f2bf(tile[tx][ty + i]);
}

// ---------------- fused: hs->bf16 + beta/resg GEMV (one hs pass) ----------------
__global__ __launch_bounds__(256)
void cvt_beta(const float* __restrict__ hs, unsigned short* __restrict__ hsb,
              const float* __restrict__ Wb, const float* __restrict__ Wres,
              const float* __restrict__ bres,
              float* __restrict__ beta, float* __restrict__ resg) {
  __shared__ float red[4][8];
  long m = blockIdx.x;
  int tid = threadIdx.x;
  int k0 = tid * 4;
  float4 x = *reinterpret_cast<const float4*>(&hs[m * 1024 + k0]);
  ushort4 o;
  o.x = f2bf(x.x); o.y = f2bf(x.y); o.z = f2bf(x.z); o.w = f2bf(x.w);
  *reinterpret_cast<ushort4*>(&hsb[m * 1024 + k0]) = o;
  float xr[4] = {x.x, x.y, x.z, x.w};
  float ab[4] = {0.f, 0.f, 0.f, 0.f}, ar[4] = {0.f, 0.f, 0.f, 0.f};
#pragma unroll
  for (int j = 0; j < 4; ++j) {
    float4 wb = *reinterpret_cast<const float4*>(&Wb[(long)(k0 + j) * 4]);
    float4 wr = *reinterpret_cast<const float4*>(&Wres[(long)(k0 + j) * 4]);
    ab[0] = fmaf(xr[j], wb.x, ab[0]); ab[1] = fmaf(xr[j], wb.y, ab[1]);
    ab[2] = fmaf(xr[j], wb.z, ab[2]); ab[3] = fmaf(xr[j], wb.w, ab[3]);
    ar[0] = fmaf(xr[j], wr.x, ar[0]); ar[1] = fmaf(xr[j], wr.y, ar[1]);
    ar[2] = fmaf(xr[j], wr.z, ar[2]); ar[3] = fmaf(xr[j], wr.w, ar[3]);
  }
#pragma unroll
  for (int st = 32; st > 0; st >>= 1) {
#pragma unroll
    for (int n = 0; n < 4; ++n) { ab[n] += __shfl_xor(ab[n], st); ar[n] += __shfl_xor(ar[n], st); }
  }
  int w = tid >> 6;
  if ((tid & 63) == 0) {
#pragma unroll
    for (int n = 0; n < 4; ++n) { red[w][n] = ab[n]; red[w][n + 4] = ar[n]; }
  }
  __syncthreads();
  if (tid < 8) {
    float s = red[0][tid] + red[1][tid] + red[2][tid] + red[3][tid];
    if (tid < 4) beta[m * 4 + tid] = sigmf(s);
    else resg[m * 4 + tid - 4] = sigmf(s + bres[tid - 4]);
  }
}

// ---------------- fused QKV GEMM: C[8192][3072] -> b0/b1/b2 (contiguous), XCD swizzle ----------------
__global__ __launch_bounds__(256)
void gemm_qkv(const unsigned short* __restrict__ A, const unsigned short* __restrict__ Bt,
              float* __restrict__ C0) {
  __shared__ unsigned short Al[128 * 32];
  __shared__ unsigned short Bl[128 * 32];
  const int K = 1024;
  const int nBn = 24;
  int wgid = blockIdx.x;
  int xcd = wgid & 7;
  int local = wgid >> 3;
  int bm = (xcd * 8 + local / nBn) * 128;
  int bn = (local % nBn) * 128;
  float* Cd = C0 + (long)(bn >> 10) * BLD;
  int cbn = bn & 1023;
  int tid = threadIdx.x;
  int lane = tid & 63, wid = tid >> 6;
  int wr = wid >> 1, wc = wid & 1;
  int l15 = lane & 15, l4 = lane >> 4;
  f32x4 acc[4][4];
#pragma unroll
  for (int i = 0; i < 4; ++i)
#pragma unroll
    for (int j = 0; j < 4; ++j) { acc[i][j].x = 0.f; acc[i][j].y = 0.f; acc[i][j].z = 0.f; acc[i][j].w = 0.f; }
  for (int k0 = 0; k0 < K; k0 += 32) {
    __syncthreads();
#pragma unroll
    for (int i = 0; i < 2; ++i) {
      int idx = tid + i * 256;
      int r = idx >> 2, sl = idx & 3;
      int src = sl ^ ((r >> 1) & 3);
      __builtin_amdgcn_global_load_lds(
          (const __attribute__((address_space(1))) unsigned int*)&A[(long)(bm + r) * K + k0 + src * 8],
          (__attribute__((address_space(3))) unsigned int*)&Al[idx * 8], 16, 0, 0);
      __builtin_amdgcn_global_load_lds(
          (const __attribute__((address_space(1))) unsigned int*)&Bt[(long)(bn + r) * K + k0 + src * 8],
          (__attribute__((address_space(3))) unsigned int*)&Bl[idx * 8], 16, 0, 0);
    }
    __syncthreads();
    bf16x8 af[4], bfr[4];
#pragma unroll
    for (int fi = 0; fi < 4; ++fi) {
      int r = wr * 64 + fi * 16 + l15;
      af[fi] = *reinterpret_cast<const bf16x8*>(&Al[r * 32 + (l4 ^ ((r >> 1) & 3)) * 8]);
    }
#pragma unroll
    for (int fj = 0; fj < 4; ++fj) {
      int r = wc * 64 + fj * 16 + l15;
      bfr[fj] = *reinterpret_cast<const bf16x8*>(&Bl[r * 32 + (l4 ^ ((r >> 1) & 3)) * 8]);
    }
#pragma unroll
    for (int fi = 0; fi < 4; ++fi)
#pragma unroll
      for (int fj = 0; fj < 4; ++fj)
        acc[fi][fj] = __builtin_amdgcn_mfma_f32_16x16x32_bf16(af[fi], bfr[fj], acc[fi][fj], 0, 0, 0);
  }
#pragma unroll
  for (int fi = 0; fi < 4; ++fi) {
    int rb = bm + wr * 64 + fi * 16 + l4 * 4;
#pragma unroll
    for (int fj = 0; fj < 4; ++fj) {
      int cb = cbn + wc * 64 + fj * 16 + l15;
#pragma unroll
      for (int j = 0; j < 4; ++j)
        Cd[(long)(rb + j) * 1024 + cb] = acc[fi][fj][j];
    }
  }
}

// ---------------- fused gate+og GEMM: N=1536 (wtg1|wtog1 contiguous); dest split ----------------
__global__ __launch_bounds__(256)
void gemm_gateog(const unsigned short* __restrict__ A, const unsigned short* __restrict__ Bt,
                 float* __restrict__ Cg, float* __restrict__ Cog) {
  __shared__ unsigned short Al[128 * 32];
  __shared__ unsigned short Bl[128 * 32];
  const int K = 1024;
  const int nBn = 12;
  int wgid = blockIdx.x;
  int xcd = wgid & 7;
  int local = wgid >> 3;
  int bm = (xcd * 8 + local / nBn) * 128;
  int bn = (local % nBn) * 128;
  float* Cd; int stride, cbn;
  if (bn < 1024) { Cd = Cg; stride = 1024; cbn = bn; }
  else { Cd = Cog; stride = 512; cbn = bn - 1024; }
  int tid = threadIdx.x;
  int lane = tid & 63, wid = tid >> 6;
  int wr = wid >> 1, wc = wid & 1;
  int l15 = lane & 15, l4 = lane >> 4;
  f32x4 acc[4][4];
#pragma unroll
  for (int i = 0; i < 4; ++i)
#pragma unroll
    for (int j = 0; j < 4; ++j) { acc[i][j].x = 0.f; acc[i][j].y = 0.f; acc[i][j].z = 0.f; acc[i][j].w = 0.f; }
  for (int k0 = 0; k0 < K; k0 += 32) {
    __syncthreads();
#pragma unroll
    for (int i = 0; i < 2; ++i) {
      int idx = tid + i * 256;
      int r = idx >> 2, sl = idx & 3;
      int src = sl ^ ((r >> 1) & 3);
      __builtin_amdgcn_global_load_lds(
          (const __attribute__((address_space(1))) unsigned int*)&A[(long)(bm + r) * K + k0 + src * 8],
          (__attribute__((address_space(3))) unsigned int*)&Al[idx * 8], 16, 0, 0);
      __builtin_amdgcn_global_load_lds(
          (const __attribute__((address_space(1))) unsigned int*)&Bt[(long)(bn + r) * K + k0 + src * 8],
          (__attribute__((address_space(3))) unsigned int*)&Bl[idx * 8], 16, 0, 0);
    }
    __syncthreads();
    bf16x8 af[4], bfr[4];
#pragma unroll
    for (int fi = 0; fi < 4; ++fi) {
      int r = wr * 64 + fi * 16 + l15;
      af[fi] = *reinterpret_cast<const bf16x8*>(&Al[r * 32 + (l4 ^ ((r >> 1) & 3)) * 8]);
    }
#pragma unroll
    for (int fj = 0; fj < 4; ++fj) {
      int r = wc * 64 + fj * 16 + l15;
      bfr[fj] = *reinterpret_cast<const bf16x8*>(&Bl[r * 32 + (l4 ^ ((r >> 1) & 3)) * 8]);
    }
#pragma unroll
    for (int fi = 0; fi < 4; ++fi)
#pragma unroll
      for (int fj = 0; fj < 4; ++fj)
        acc[fi][fj] = __builtin_amdgcn_mfma_f32_16x16x32_bf16(af[fi], bfr[fj], acc[fi][fj], 0, 0, 0);
  }
#pragma unroll
  for (int fi = 0; fi < 4; ++fi) {
    int rb = bm + wr * 64 + fi * 16 + l4 * 4;
#pragma unroll
    for (int fj = 0; fj < 4; ++fj) {
      int cb = cbn + wc * 64 + fj * 16 + l15;
#pragma unroll
      for (int j = 0; j < 4; ++j)
        Cd[(long)(rb + j) * stride + cb] = acc[fi][fj][j];
    }
  }
}

// ---------------- bf16 MFMA GEMM with XCD-aware tile swizzle (final Wo) ----------------
__global__ __launch_bounds__(256)
void gemm_bf16(const unsigned short* __restrict__ A, const unsigned short* __restrict__ Bt,
               float* __restrict__ C, int N) {
  __shared__ unsigned short Al[128 * 32];
  __shared__ unsigned short Bl[128 * 32];
  const int K = 1024;
  int nBn = N >> 7;
  int wgid = blockIdx.x;
  int xcd = wgid & 7;
  int local = wgid >> 3;
  int bm = (xcd * 8 + local / nBn) * 128;
  int bn = (local % nBn) * 128;
  int tid = threadIdx.x;
  int lane = tid & 63, wid = tid >> 6;
  int wr = wid >> 1, wc = wid & 1;
  int l15 = lane & 15, l4 = lane >> 4;
  f32x4 acc[4][4];
#pragma unroll
  for (int i = 0; i < 4; ++i)
#pragma unroll
    for (int j = 0; j < 4; ++j) { acc[i][j].x = 0.f; acc[i][j].y = 0.f; acc[i][j].z = 0.f; acc[i][j].w = 0.f; }
  for (int k0 = 0; k0 < K; k0 += 32) {
    __syncthreads();
#pragma unroll
    for (int i = 0; i < 2; ++i) {
      int idx = tid + i * 256;
      int r = idx >> 2, sl = idx & 3;
      int src = sl ^ ((r >> 1) & 3);
      __builtin_amdgcn_global_load_lds(
          (const __attribute__((address_space(1))) unsigned int*)&A[(long)(bm + r) * K + k0 + src * 8],
          (__attribute__((address_space(3))) unsigned int*)&Al[idx * 8], 16, 0, 0);
      __builtin_amdgcn_global_load_lds(
          (const __attribute__((address_space(1))) unsigned int*)&Bt[(long)(bn + r) * K + k0 + src * 8],
          (__attribute__((address_space(3))) unsigned int*)&Bl[idx * 8], 16, 0, 0);
    }
    __syncthreads();
    bf16x8 af[4], bfr[4];
#pragma unroll
    for (int fi = 0; fi < 4; ++fi) {
      int r = wr * 64 + fi * 16 + l15;
      af[fi] = *reinterpret_cast<const bf16x8*>(&Al[r * 32 + (l4 ^ ((r >> 1) & 3)) * 8]);
    }
#pragma unroll
    for (int fj = 0; fj < 4; ++fj) {
      int r = wc * 64 + fj * 16 + l15;
      bfr[fj] = *reinterpret_cast<const bf16x8*>(&Bl[r * 32 + (l4 ^ ((r >> 1) & 3)) * 8]);
    }
#pragma unroll
    for (int fi = 0; fi < 4; ++fi)
#pragma unroll
      for (int fj = 0; fj < 4; ++fj)
        acc[fi][fj] = __builtin_amdgcn_mfma_f32_16x16x32_bf16(af[fi], bfr[fj], acc[fi][fj], 0, 0, 0);
  }
#pragma unroll
  for (int fi = 0; fi < 4; ++fi) {
    int rb = bm + wr * 64 + fi * 16 + l4 * 4;
#pragma unroll
    for (int fj = 0; fj < 4; ++fj) {
      int cb = bn + wc * 64 + fj * 16 + l15;
#pragma unroll
      for (int j = 0; j < 4; ++j)
        C[(long)(rb + j) * N + cb] = acc[fi][fj][j];
    }
  }
}

// ---------------- tiled depthwise causal conv, sliding-window ----------------
#define CTL 128
template<int K>
__global__ __launch_bounds__(256)
void dwconv_tiled(const float* __restrict__ x, const float* __restrict__ w,
                  float* __restrict__ y, int do_silu) {
  __shared__ float tile[(CTL + K - 1) * 64];
  int bid = blockIdx.x;
  int ct = bid & 15;
  int lt = (bid >> 4) & 31;
  int b  = bid >> 9;
  int c0 = ct * 64;
  int l0 = lt * CTL;
  int tid = threadIdx.x;
  const int rows = CTL + K - 1;
  for (int i = tid; i < rows * 16; i += 256) {
    int rr = i >> 4, c4 = i & 15;
    int l = l0 - (K - 1) + rr;
    float4 v = make_float4(0.f, 0.f, 0.f, 0.f);
    if (l >= 0) v = *reinterpret_cast<const float4*>(&x[((long)b * L_ + l) * D_ + c0 + c4 * 4]);
    *reinterpret_cast<float4*>(&tile[rr * 64 + c4 * 4]) = v;
  }
  __syncthreads();
  int c = tid & 63;
  int wv = tid >> 6;
  float wreg[K];
#pragma unroll
  for (int j = 0; j < K; ++j) wreg[j] = w[(long)(c0 + c) * K + j];
#pragma unroll
  for (int g = 0; g < 4; ++g) {
    int lo_base = g * 32 + wv * 8;
    float win[8];
#pragma unroll
    for (int r = 0; r < 8; ++r) win[r] = tile[(lo_base + r) * 64 + c];
    float acc[8] = {0.f, 0.f, 0.f, 0.f, 0.f, 0.f, 0.f, 0.f};
#pragma unroll
    for (int j = 0; j < K; ++j) {
#pragma unroll
      for (int r = 0; r < 8; ++r) acc[r] = fmaf(wreg[j], win[r], acc[r]);
      if (j < K - 1) {
#pragma unroll
        for (int r = 0; r < 7; ++r) win[r] = win[r + 1];
        win[7] = tile[(lo_base + j + 8) * 64 + c];
      }
    }
#pragma unroll
    for (int r = 0; r < 8; ++r) {
      float v = acc[r];
      if (do_silu) v = v * sigmf(v);
      y[((long)b * L_ + l0 + lo_base + r) * D_ + c0 + c] = v;
    }
  }
}

// ---------------- wave-parallel l2norm over TWO buffers in one launch ----------------
__global__ __launch_bounds__(256)
void l2norm_wave2(float* __restrict__ x0, float* __restrict__ x1) {
  int bid = blockIdx.x;
  const int half = BL * H_ / 4;   // 8192
  float* x = (bid < half) ? x0 : x1;
  int lb = (bid < half) ? bid : bid - half;
  long row = (long)lb * 4 + (threadIdx.x >> 6);
  int lane = threadIdx.x & 63;
  float4 v = *reinterpret_cast<const float4*>(&x[row * 256 + lane * 4]);
  float q = v.x * v.x + v.y * v.y + v.z * v.z + v.w * v.w;
#pragma unroll
  for (int st = 32; st > 0; st >>= 1) q += __shfl_xor(q, st);
  float inv = rsqrtf(q + 1e-6f);
  v.x *= inv; v.y *= inv; v.z *= inv; v.w *= inv;
  *reinterpret_cast<float4*>(&x[row * 256 + lane * 4]) = v;
}

// ---------------- per-chunk: inv, u, bf16 scan operands ----------------
__global__ __launch_bounds__(256)
void chunk_uw(const float* __restrict__ qn, const float* __restrict__ kn,
              const float* __restrict__ v, const float* __restrict__ beta,
              float* __restrict__ u,
              unsigned short* __restrict__ q_bf, unsigned short* __restrict__ w_bf,
              unsigned short* __restrict__ kT_bf, unsigned short* __restrict__ at_bf) {
  __shared__ float skT[256][33];
  __shared__ float sinv[32][33];
  __shared__ float sbeta[32];
  int blk = blockIdx.x;
  int ci = blk % NCH;
  int bh = blk / NCH;
  int h = bh % H_;
  int b = bh / H_;
  long base = ((long)b * L_ + (long)ci * CHUNKSZ) * D_ + h * DH;
  long brow = (long)b * L_ + (long)ci * CHUNKSZ;
  long obase = (long)blk * 8192;
  int tid = threadIdx.x;
  for (int i = tid; i < 32 * 256; i += 256) {
    int r = i >> 8, c = i & 255;
    skT[c][r] = kn[base + (long)r * D_ + c];
  }
  if (tid < 32) sbeta[tid] = beta[(brow + tid) * H_ + h];
  __syncthreads();
  for (int i = tid; i < 8192; i += 256)
    kT_bf[obase + i] = f2bf(skT[i >> 5][i & 31]);
  for (int i = tid; i < 8192; i += 256)
    q_bf[obase + i] = f2bf(qn[base + (long)(i >> 8) * D_ + (i & 255)]);
  int j = tid & 31, i0 = tid >> 5;
  for (int r = 0; r < 4; ++r) {
    int i = i0 + (r << 3);
    float acc = 0.f;
    for (int d = 0; d < 256; ++d) acc += skT[d][i] * skT[d][j];
    sinv[i][j] = (i > j) ? -acc * sbeta[i] : 0.f;
  }
  __syncthreads();
  for (int i = 1; i < 32; ++i) {
    float val = 0.f;
    if (tid < 32) {
      for (int t = 0; t < i; ++t) val += sinv[i][t] * sinv[t][tid];
    }
    __syncthreads();
    if (tid < 32) sinv[i][tid] += val;
    __syncthreads();
  }
  if (tid < 32) sinv[tid][tid] += 1.f;
  long abase = (long)blk * 1024;
  for (int r = 0; r < 4; ++r) {
    int i = i0 + (r << 3);
    const float* qrow = qn + base + (long)i * D_;
    float acc = 0.f;
    for (int d = 0; d < 256; ++d) acc += qrow[d] * skT[d][j];
    at_bf[abase + i * 32 + j] = f2bf((i >= j) ? acc : 0.f);
  }
  __syncthreads();
  int c = tid;
  float vt[32], kt[32];
#pragma unroll
  for (int t = 0; t < 32; ++t) {
    vt[t] = v[base + t * D_ + c] * sbeta[t];
    kt[t] = skT[c][t] * sbeta[t];
  }
#pragma unroll
  for (int i2 = 0; i2 < 32; ++i2) {
    float au = 0.f, aw = 0.f;
#pragma unroll
    for (int t = 0; t <= i2; ++t) {
      float f = sinv[i2][t];
      au += f * vt[t];
      aw += f * kt[t];
    }
    u[base + i2 * D_ + c] = au;
    w_bf[obase + i2 * 256 + c] = f2bf(aw);
  }
}

// ---------------- MFMA scan: 128 blocks x 1 wave, barrier-free ----------------
__global__ __launch_bounds__(64, 1)
void delta_scan(const unsigned short* __restrict__ qb, const unsigned short* __restrict__ wbf,
                const unsigned short* __restrict__ ktb, const unsigned short* __restrict__ atb,
                const float* __restrict__ u, float* __restrict__ out) {
  __shared__ unsigned short sB[16 * 264];
  __shared__ unsigned short su2[16 * 40];
  int blk = blockIdx.x;
  int bh = blk & 7, cg = blk >> 3;
  int h = bh & 3, b = bh >> 2;
  int lane = threadIdx.x;
  int l15 = lane & 15, l4 = lane >> 4;
  int colw = cg * 16;

  f32x4 zero4; zero4.x = 0.f; zero4.y = 0.f; zero4.z = 0.f; zero4.w = 0.f;
  f32x4 acc[16];
#pragma unroll
  for (int t = 0; t < 16; ++t) acc[t] = zero4;

  uint4 wf[2][8];
  float ru[2][4];
  uint4 qf[2][8];
  uint4 kfa[8], kfb[8];
  uint4 af[2];

#define LOAD_W(CI) do {                                                          \
    long o8_ = ((long)bh * NCH + (CI)) * 8192;                                   \
    _Pragma("unroll")                                                            \
    for (int m_ = 0; m_ < 2; ++m_)                                               \
      _Pragma("unroll")                                                          \
      for (int kc_ = 0; kc_ < 8; ++kc_)                                          \
        wf[m_][kc_] = *reinterpret_cast<const uint4*>(                           \
            &wbf[o8_ + (16 * m_ + l15) * 256 + kc_ * 32 + l4 * 8]);              \
  } while (0)

#define LOAD_U(CI) do {                                                          \
    long ub_ = ((long)b * L_ + (long)(CI) * CHUNKSZ) * D_ + h * DH + colw;       \
    _Pragma("unroll")                                                            \
    for (int m_ = 0; m_ < 2; ++m_)                                               \
      _Pragma("unroll")                                                          \
      for (int r_ = 0; r_ < 4; ++r_)                                             \
        ru[m_][r_] = u[ub_ + (long)(16 * m_ + 4 * l4 + r_) * D_ + l15];          \
  } while (0)

#define LOAD_Q(CI) do {                                                          \
    long o8_ = ((long)bh * NCH + (CI)) * 8192;                                   \
    _Pragma("unroll")                                                            \
    for (int m_ = 0; m_ < 2; ++m_)                                               \
      _Pragma("unroll")                                                          \
      for (int kc_ = 0; kc_ < 8; ++kc_)                                          \
        qf[m_][kc_] = *reinterpret_cast<const uint4*>(                           \
            &qb[o8_ + (16 * m_ + l15) * 256 + kc_ * 32 + l4 * 8]);               \
  } while (0)

#define LOAD_KA(CI) do {                                                         \
    long o8_ = ((long)bh * NCH + (CI)) * 8192;                                   \
    _Pragma("unroll")                                                            \
    for (int dt_ = 0; dt_ < 8; ++dt_)                                            \
      kfa[dt_] = *reinterpret_cast<const uint4*>(                                \
          &ktb[o8_ + (16 * dt_ + l15) * 32 + l4 * 8]);                           \
  } while (0)

#define LOAD_KB(CI) do {                                                         \
    long o8_ = ((long)bh * NCH + (CI)) * 8192;                                   \
    _Pragma("unroll")                                                            \
    for (int dt_ = 0; dt_ < 8; ++dt_)                                            \
      kfb[dt_] = *reinterpret_cast<const uint4*>(                                \
          &ktb[o8_ + (16 * (dt_ + 8) + l15) * 32 + l4 * 8]);                     \
  } while (0)

#define LOAD_A(CI) do {                                                          \
    long oa_ = ((long)bh * NCH + (CI)) * 1024;                                   \
    _Pragma("unroll")                                                            \
    for (int m_ = 0; m_ < 2; ++m_)                                               \
      af[m_] = *reinterpret_cast<const uint4*>(                                  \
          &atb[oa_ + (16 * m_ + l15) * 32 + l4 * 8]);                            \
  } while (0)

#define SCAN_BODY(CI, PF) do {                                                   \
    long ub = ((long)b * L_ + (long)(CI) * CHUNKSZ) * D_ + h * DH + colw;        \
    _Pragma("unroll")                                                            \
    for (int dt = 0; dt < 16; ++dt) {                                            \
      uint2 pv;                                                                  \
      pv.x = pk2bf(acc[dt].x, acc[dt].y);                                        \
      pv.y = pk2bf(acc[dt].z, acc[dt].w);                                        \
      *reinterpret_cast<uint2*>(&sB[l15 * 264 + dt * 16 + l4 * 4]) = pv;         \
    }                                                                            \
    bf16x8 sf[8];                                                                \
    _Pragma("unroll")                                                            \
    for (int kc = 0; kc < 8; ++kc)                                               \
      sf[kc] = *reinterpret_cast<const bf16x8*>(&sB[l15 * 264 + kc * 32 + l4 * 8]); \
    f32x4 wa[2][2];                                                              \
    wa[0][0] = zero4; wa[0][1] = zero4; wa[1][0] = zero4; wa[1][1] = zero4;      \
    _Pragma("unroll")                                                            \
    for (int kc = 0; kc < 8; ++kc) {                                             \
      _Pragma("unroll")                                                          \
      for (int m = 0; m < 2; ++m)                                                \
        wa[m][kc & 1] = __builtin_amdgcn_mfma_f32_16x16x32_bf16(                 \
            *reinterpret_cast<bf16x8*>(&wf[m][kc]), sf[kc], wa[m][kc & 1], 0, 0, 0); \
    }                                                                            \
    if (PF) LOAD_W((CI) + 1);                                                    \
    _Pragma("unroll")                                                            \
    for (int m = 0; m < 2; ++m) {                                                \
      f32x4 wsum = wa[m][0] + wa[m][1];                                          \
      uint2 pv;                                                                  \
      pv.x = pk2bf(ru[m][0] - wsum.x, ru[m][1] - wsum.y);                        \
      pv.y = pk2bf(ru[m][2] - wsum.z, ru[m][3] - wsum.w);                        \
      *reinterpret_cast<uint2*>(&su2[l15 * 40 + m * 16 + l4 * 4]) = pv;          \
    }                                                                            \
    if (PF) LOAD_U((CI) + 1);                                                    \
    bf16x8 u2f = *reinterpret_cast<const bf16x8*>(&su2[l15 * 40 + l4 * 8]);      \
    _Pragma("unroll")                                                            \
    for (int dt = 0; dt < 8; ++dt)                                               \
      acc[dt] = __builtin_amdgcn_mfma_f32_16x16x32_bf16(                         \
          *reinterpret_cast<bf16x8*>(&kfa[dt]), u2f, acc[dt], 0, 0, 0);          \
    if (PF) LOAD_KA((CI) + 1);                                                   \
    _Pragma("unroll")                                                            \
    for (int dt = 0; dt < 8; ++dt)                                               \
      acc[dt + 8] = __builtin_amdgcn_mfma_f32_16x16x32_bf16(                     \
          *reinterpret_cast<bf16x8*>(&kfb[dt]), u2f, acc[dt + 8], 0, 0, 0);      \
    if (PF) LOAD_KB((CI) + 1);                                                   \
    f32x4 qa[2][2];                                                              \
    qa[0][0] = zero4; qa[0][1] = zero4; qa[1][0] = zero4; qa[1][1] = zero4;      \
    _Pragma("unroll")                                                            \
    for (int kc = 0; kc < 8; ++kc) {                                             \
      _Pragma("unroll")                                                          \
      for (int m = 0; m < 2; ++m)                                                \
        qa[m][kc & 1] = __builtin_amdgcn_mfma_f32_16x16x32_bf16(                 \
            *reinterpret_cast<bf16x8*>(&qf[m][kc]), sf[kc], qa[m][kc & 1], 0, 0, 0); \
    }                                                                            \
    if (PF) LOAD_Q((CI) + 1);                                                    \
    _Pragma("unroll")                                                            \
    for (int m = 0; m < 2; ++m) {                                                \
      f32x4 qacc = qa[m][0] + qa[m][1];                                          \
      f32x4 dv = __builtin_amdgcn_mfma_f32_16x16x32_bf16(                        \
          *reinterpret_cast<bf16x8*>(&af[m]), u2f, qacc, 0, 0, 0);               \
      _Pragma("unroll")                                                          \
      for (int r = 0; r < 4; ++r)                                                \
        out[ub + (long)(16 * m + 4 * l4 + r) * D_ + l15] = dv[r];                \
    }                                                                            \
    if (PF) LOAD_A((CI) + 1);                                                    \
  } while (0)

  LOAD_W(0); LOAD_U(0); LOAD_Q(0); LOAD_KA(0); LOAD_KB(0); LOAD_A(0);

  for (int ci = 0; ci < NCH - 1; ++ci) {
    SCAN_BODY(ci, 1);
  }
  SCAN_BODY(NCH - 1, 0);

#undef LOAD_W
#undef LOAD_U
#undef LOAD_Q
#undef LOAD_KA
#undef LOAD_KB
#undef LOAD_A
#undef SCAN_BODY
}

// ---------------- fused head stats x4 tensors ----------------
__global__ __launch_bounds__(256)
void head_stats4(const float* __restrict__ t0, const float* __restrict__ t1,
                 const float* __restrict__ t2, const float* __restrict__ t3,
                 float* __restrict__ outp) {
  long bl = blockIdx.x;
  int w = threadIdx.x >> 6, lane = threadIdx.x & 63;
  const float* x = (w == 0) ? t0 : (w == 1) ? t1 : (w == 2) ? t2 : t3;
  float m = 0.f, vv = 0.f, am = 0.f, l2 = 0.f;
#pragma unroll
  for (int h = 0; h < 4; ++h) {
    float4 v = *reinterpret_cast<const float4*>(&x[bl * 1024 + h * 256 + lane * 4]);
    float s = v.x + v.y + v.z + v.w;
    float q = v.x * v.x + v.y * v.y + v.z * v.z + v.w * v.w;
    float a = fabsf(v.x) + fabsf(v.y) + fabsf(v.z) + fabsf(v.w);
#pragma unroll
    for (int st = 32; st > 0; st >>= 1) {
      s += __shfl_xor(s, st); q += __shfl_xor(q, st); a += __shfl_xor(a, st);
    }
    float mean = s * (1.f / 256.f);
    m += mean;
    vv += q * (1.f / 256.f) - mean * mean;
    am += a * (1.f / 256.f);
    l2 += sqrtf(q);
  }
  if (lane == 0) {
    float* o = outp + bl * 16 + w * 4;
    o[0] = m * 0.25f; o[1] = vv * 0.25f; o[2] = am * 0.25f; o[3] = l2 * 0.25f;
  }
}

// ---------------- gate fused ----------------
__global__ __launch_bounds__(256)
void gate_fused(const float* __restrict__ g, const float* __restrict__ stats,
                const float* __restrict__ Wg1t, const float* __restrict__ bg1,
                const float* __restrict__ Wg2, const float* __restrict__ bg2,
                const float* __restrict__ temp_in, float* __restrict__ p) {
  __shared__ float red[4][4];
  long m = blockIdx.x;
  int tid = threadIdx.x;
  int c0 = tid * 4;
  float4 gv = *reinterpret_cast<const float4*>(&g[m * 1024 + c0]);
  float st[16];
#pragma unroll
  for (int k = 0; k < 16; ++k) st[k] = stats[m * 16 + k];
  float la[4] = {0.f, 0.f, 0.f, 0.f};
  float gvv[4] = {gv.x, gv.y, gv.z, gv.w};
#pragma unroll
  for (int j = 0; j < 4; ++j) {
    int c = c0 + j;
    float s = gvv[j] + bg1[c];
#pragma unroll
    for (int k = 0; k < 16; ++k) s += st[k] * Wg1t[(long)k * 1024 + c];
    float ge = geluf(s);
#pragma unroll
    for (int n = 0; n < 4; ++n) la[n] += ge * Wg2[c * 4 + n];
  }
#pragma unroll
  for (int stp = 32; stp > 0; stp >>= 1)
#pragma unroll
    for (int n = 0; n < 4; ++n) la[n] += __shfl_xor(la[n], stp);
  int w = tid >> 6;
  if ((tid & 63) == 0) {
#pragma unroll
    for (int n = 0; n < 4; ++n) red[w][n] = la[n];
  }
  __syncthreads();
  if (tid == 0) {
    float temp = log1pf(expf(temp_in[0]));
    float l[4];
#pragma unroll
    for (int n = 0; n < 4; ++n)
      l[n] = (red[0][n] + red[1][n] + red[2][n] + red[3][n] + bg2[n]) / temp;
    float mx = fmaxf(fmaxf(l[0], l[1]), fmaxf(l[2], l[3]));
    float e[4], s = 0.f;
#pragma unroll
    for (int n = 0; n < 4; ++n) { e[n] = expf(l[n] - mx); s += e[n]; }
    float s2 = 0.f;
#pragma unroll
    for (int n = 0; n < 4; ++n) { e[n] = fmaxf(e[n] / s, 0.02f); s2 += e[n]; }
#pragma unroll
    for (int n = 0; n < 4; ++n) p[m * 4 + n] = e[n] / s2;
  }
}

// ---------------- combine + og stats fused ----------------
__global__ __launch_bounds__(256)
void combine_ogstats(const float* __restrict__ ls, const float* __restrict__ ll,
                     const float* __restrict__ dd, const float* __restrict__ vd,
                     const float* __restrict__ p, const float* __restrict__ resg,
                     const float* __restrict__ crl, float* __restrict__ o,
                     float* __restrict__ og8) {
  __shared__ float part[4][8];
  long bl = blockIdx.x;
  int h = threadIdx.x >> 6, lane = threadIdx.x & 63;
  long base = bl * 1024 + h * 256 + lane * 4;
  float4 lsv = *reinterpret_cast<const float4*>(&ls[base]);
  float4 llv = *reinterpret_cast<const float4*>(&ll[base]);
  float4 ddv = *reinterpret_cast<const float4*>(&dd[base]);
  float4 vdv = *reinterpret_cast<const float4*>(&vd[base]);
  float p0 = p[bl * 4 + 0], p1 = p[bl * 4 + 1], p2 = p[bl * 4 + 2], p3 = p[bl * 4 + 3];
  float sg = sigmf(crl[h]) * resg[bl * 4 + h];
  float c0 = p0 + sg;
  float4 ov;
  ov.x = c0 * lsv.x + p1 * llv.x + p2 * ddv.x + p3 * vdv.x;
  ov.y = c0 * lsv.y + p1 * llv.y + p2 * ddv.y + p3 * vdv.y;
  ov.z = c0 * lsv.z + p1 * llv.z + p2 * ddv.z + p3 * vdv.z;
  ov.w = c0 * lsv.w + p1 * llv.w + p2 * ddv.w + p3 * vdv.w;
  *reinterpret_cast<float4*>(&o[base]) = ov;
  float s = ov.x + ov.y + ov.z + ov.w;
  float q = ov.x * ov.x + ov.y * ov.y + ov.z * ov.z + ov.w * ov.w;
  float a = fabsf(ov.x) + fabsf(ov.y) + fabsf(ov.z) + fabsf(ov.w);
  float sv = vdv.x + vdv.y + vdv.z + vdv.w;
  float qv = vdv.x * vdv.x + vdv.y * vdv.y + vdv.z * vdv.z + vdv.w * vdv.w;
  float av = fabsf(vdv.x) + fabsf(vdv.y) + fabsf(vdv.z) + fabsf(vdv.w);
#pragma unroll
  for (int st = 32; st > 0; st >>= 1) {
    s += __shfl_xor(s, st); q += __shfl_xor(q, st); a += __shfl_xor(a, st);
    sv += __shfl_xor(sv, st); qv += __shfl_xor(qv, st); av += __shfl_xor(av, st);
  }
  if (lane == 0) {
    float mo = s * (1.f / 256.f), mv = sv * (1.f / 256.f);
    part[h][0] = mo; part[h][1] = q * (1.f / 256.f) - mo * mo;
    part[h][2] = a * (1.f / 256.f); part[h][3] = sqrtf(q);
    part[h][4] = mv; part[h][5] = qv * (1.f / 256.f) - mv * mv;
    part[h][6] = av * (1.f / 256.f); part[h][7] = sqrtf(qv);
  }
  __syncthreads();
  if (threadIdx.x < 8) {
    int t = threadIdx.x;
    og8[bl * 8 + t] = 0.25f * (part[0][t] + part[1][t] + part[2][t] + part[3][t]);
  }
}

// ---------------- og gate fused ----------------
__global__ __launch_bounds__(256)
void og_gate_fused(const float* __restrict__ g, const float* __restrict__ og8,
                   const float* __restrict__ Wog1t, const float* __restrict__ bog1,
                   const float* __restrict__ Wog2, const float* __restrict__ bog2,
                   float* __restrict__ ogv) {
  __shared__ float red[4];
  long m = blockIdx.x;
  int tid = threadIdx.x;
  int c0 = tid * 2;
  float2 gv = *reinterpret_cast<const float2*>(&g[m * 512 + c0]);
  float st[8];
#pragma unroll
  for (int k = 0; k < 8; ++k) st[k] = og8[m * 8 + k];
  float a = 0.f;
  float gvv[2] = {gv.x, gv.y};
#pragma unroll
  for (int j = 0; j < 2; ++j) {
    int c = c0 + j;
    float s = gvv[j] + bog1[c];
#pragma unroll
    for (int k = 0; k < 8; ++k) s += st[k] * Wog1t[(long)k * 512 + c];
    a += geluf(s) * Wog2[c];
  }
#pragma unroll
  for (int stp = 32; stp > 0; stp >>= 1) a += __shfl_xor(a, stp);
  int w = tid >> 6;
  if ((tid & 63) == 0) red[w] = a;
  __syncthreads();
  if (tid == 0) ogv[m] = sigmf(red[0] + red[1] + red[2] + red[3] + bog2[0]);
}

// ---------------- wave-parallel scale+rmsnorm -> bf16 ----------------
__global__ __launch_bounds__(256)
void scale_rmsnorm_bf16(const float* __restrict__ o, const float* __restrict__ og,
                        const float* __restrict__ nw, unsigned short* __restrict__ xb) {
  long row = (long)blockIdx.x * 4 + (threadIdx.x >> 6);
  long bl = row >> 2;
  int lane = threadIdx.x & 63;
  float g = og[bl];
  float4 v = *reinterpret_cast<const float4*>(&o[row * 256 + lane * 4]);
  v.x *= g; v.y *= g; v.z *= g; v.w *= g;
  float q = v.x * v.x + v.y * v.y + v.z * v.z + v.w * v.w;
#pragma unroll
  for (int st = 32; st > 0; st >>= 1) q += __shfl_xor(q, st);
  float scale = rsqrtf(q * (1.f / 256.f) + 1e-5f);
  float4 w4 = *reinterpret_cast<const float4*>(&nw[lane * 4]);
  ushort4 r;
  r.x = f2bf(v.x * scale * w4.x);
  r.y = f2bf(v.y * scale * w4.y);
  r.z = f2bf(v.z * scale * w4.z);
  r.w = f2bf(v.w * scale * w4.w);
  *reinterpret_cast<ushort4*>(&xb[row * 256 + lane * 4]) = r;
}

extern "C" void kernel_launch(void* const* d_in, const int* in_sizes, int n_in,
                              void* d_out, int out_size, void* d_ws, size_t ws_size,
                              hipStream_t stream) {
  const float* hs       = (const float*)d_in[0];
  const float* Wq       = (const float*)d_in[1];
  const float* Wk       = (const float*)d_in[2];
  const float* Wv       = (const float*)d_in[3];
  const float* Wb       = (const float*)d_in[4];
  const float* wq_conv  = (const float*)d_in[5];
  const float* wk_conv  = (const float*)d_in[6];
  const float* wv_conv  = (const float*)d_in[7];
  const float* fir_long = (const float*)d_in[8];
  const float* fir_short= (const float*)d_in[9];
  const float* Wg1      = (const float*)d_in[10];
  const float* bg1      = (const float*)d_in[11];
  const float* Wg2      = (const float*)d_in[12];
  const float* bg2      = (const float*)d_in[13];
  const float* logit_temp     = (const float*)d_in[14];
  const float* conv_res_logit = (const float*)d_in[15];
  const float* Wres     = (const float*)d_in[16];
  const float* bres     = (const float*)d_in[17];
  const float* Wog1     = (const float*)d_in[18];
  const float* bog1     = (const float*)d_in[19];
  const float* Wog2     = (const float*)d_in[20];
  const float* bog2     = (const float*)d_in[21];
  const float* norm_w   = (const float*)d_in[22];
  const float* Wo       = (const float*)d_in[23];
  float* out = (float*)d_out;
  float* ws = (float*)d_ws;

  float* b0 = ws;
  float* b1 = ws + 1L * BLD;
  float* b2 = ws + 2L * BLD;
  float* b3 = ws + 3L * BLD;
  float* b4 = ws + 4L * BLD;
  float* sm = ws + 5L * BLD;
  float* beta    = sm;
  float* resg    = beta + BL * H_;
  float* stats16 = resg + BL * H_;
  float* og8     = stats16 + BL * 16;
  float* logits  = og8 + BL * 8;
  float* pbuf    = logits + BL * 4;
  float* ogv     = pbuf + BL * 4;
  unsigned short* q_bfg  = (unsigned short*)(ogv + BL);
  unsigned short* kT_bfg = q_bfg + (long)BLD;
  unsigned short* at_bfg = kT_bfg + (long)BLD;
  unsigned short* hsb  = at_bfg + 1024L * 1024;
  unsigned short* wtq  = hsb + (long)BLD;
  unsigned short* wtk  = wtq + 1024L * 1024;
  unsigned short* wtv  = wtk + 1024L * 1024;
  unsigned short* wtg1 = wtv + 1024L * 1024;
  unsigned short* wtog1= wtg1 + 1024L * 1024;   // reordered: wtog1 follows wtg1
  unsigned short* wto  = wtog1 + 512L * 1024;
  unsigned short* w_bfg = (unsigned short*)b4;
  unsigned short* xb    = q_bfg;
  float* ogh = (float*)q_bfg;                   // og hidden (f32, 8192x512) in q_bf region

  size_t needed = (5L * BLD + BL * 41) * 4
                + (3L * BLD + 1024L * 1024 + 5L * 1024 * 1024 + 512L * 1024) * 2;
  if (ws_size < needed) return;

  dim3 blk(256);
  // 0. all weight transposes (1 launch) + hs->bf16 fused with beta/resg
  wconv_all<<<5632, blk, 0, stream>>>(Wq, Wk, Wv, Wg1, Wog1, Wo, wtq, wtk, wtv, wtg1, wtog1, wto);
  cvt_beta<<<BL, blk, 0, stream>>>(hs, hsb, Wb, Wres, bres, beta, resg);
  // 1. QKV projections (single fused launch, N=3072)
  gemm_qkv<<<1536, blk, 0, stream>>>(hsb, wtq, b0);
  // 2. conv + silu
  dwconv_tiled<4><<<1024, blk, 0, stream>>>(b0, wq_conv, b3, 1);
  dwconv_tiled<4><<<1024, blk, 0, stream>>>(b1, wk_conv, b0, 1);
  dwconv_tiled<4><<<1024, blk, 0, stream>>>(b2, wv_conv, b1, 1);
  // 3. l2norm (both buffers, one launch)
  l2norm_wave2<<<2 * BL * H_ / 4, blk, 0, stream>>>(b3, b0);
  // 4-5. delta rule
  chunk_uw<<<B_ * H_ * NCH, blk, 0, stream>>>(b3, b0, b1, beta, b2, q_bfg, w_bfg, kT_bfg, at_bfg);
  delta_scan<<<128, dim3(64), 0, stream>>>(q_bfg, w_bfg, kT_bfg, at_bfg, b2, b2);
  // 6. local convs
  dwconv_tiled<64><<<1024, blk, 0, stream>>>(b1, fir_long, b3, 0);
  dwconv_tiled<5><<<1024, blk, 0, stream>>>(b1, fir_short, b4, 0);
  // 7. stats16 fused
  head_stats4<<<BL, blk, 0, stream>>>(b4, b3, b2, b1, stats16);
  // 8. gate + og hidden GEMMs (single fused launch, N=1536; og hidden f32 -> ogh)
  gemm_gateog<<<768, blk, 0, stream>>>(hsb, wtg1, b0, ogh);
  gate_fused<<<BL, blk, 0, stream>>>(b0, stats16, Wg1 + 1024L * 1024, bg1, Wg2, bg2, logit_temp, pbuf);
  // 9. combine + og stats
  combine_ogstats<<<BL, blk, 0, stream>>>(b4, b3, b2, b1, pbuf, resg, conv_res_logit, b0, og8);
  // 10. og gate (reads ogh; ogh region is overwritten by xb only at step 11)
  og_gate_fused<<<BL, blk, 0, stream>>>(ogh, og8, Wog1 + 1024L * 512, bog1, Wog2, bog2, ogv);
  // 11. scale + rmsnorm -> bf16
  scale_rmsnorm_bf16<<<BL * H_ / 4, blk, 0, stream>>>(b0, ogv, norm_w, xb);
  // 12. final projection
  gemm_bf16<<<512, blk, 0, stream>>>(xb, wto, out, 1024);
}

// Round 18
// 777.424 us; speedup vs baseline: 3.5451x; 1.0375x over previous
//
#include <hip/hip_runtime.h>
#include <math.h>

#define B_ 2
#define L_ 4096
#define D_ 1024
#define H_ 4
#define DH 256
#define CHUNKSZ 32
#define NCH (L_/CHUNKSZ)      // 128
#define BL (B_*L_)            // 8192
#define BLD (B_*L_*D_)        // 8388608

typedef __attribute__((ext_vector_type(8))) short bf16x8;
typedef __attribute__((ext_vector_type(4))) float f32x4;

__device__ __forceinline__ float sigmf(float x) { return 1.f / (1.f + expf(-x)); }
__device__ __forceinline__ float geluf(float x) { return 0.5f * x * (1.f + erff(x * 0.70710678118654752f)); }
__device__ __forceinline__ unsigned short f2bf(float f) {
  unsigned int u = __float_as_uint(f);
  unsigned int r = (u + 0x7FFFu + ((u >> 16) & 1u)) >> 16;
  return (unsigned short)r;
}
__device__ __forceinline__ unsigned int pk2bf(float a, float b) {
  return ((unsigned int)f2bf(b) << 16) | (unsigned int)f2bf(a);
}

// ---------------- ALL weight transposes in one launch ----------------
__global__ __launch_bounds__(256)
void wconv_all(const float* __restrict__ Wq, const float* __restrict__ Wk,
               const float* __restrict__ Wv, const float* __restrict__ Wg1,
               const float* __restrict__ Wog1, const float* __restrict__ Wo,
               unsigned short* __restrict__ wtq, unsigned short* __restrict__ wtk,
               unsigned short* __restrict__ wtv, unsigned short* __restrict__ wtg1,
               unsigned short* __restrict__ wtog1, unsigned short* __restrict__ wto) {
  __shared__ float tile[32][33];
  int bid = blockIdx.x;
  const float* W; unsigned short* Wt; int N; int rem;
  if (bid < 5120) {
    int widx = bid >> 10; rem = bid & 1023; N = 1024;
    switch (widx) {
      case 0: W = Wq; Wt = wtq; break;
      case 1: W = Wk; Wt = wtk; break;
      case 2: W = Wv; Wt = wtv; break;
      case 3: W = Wg1; Wt = wtg1; break;
      default: W = Wo; Wt = wto; break;
    }
  } else { rem = bid - 5120; N = 512; W = Wog1; Wt = wtog1; }
  int nT = N >> 5;
  int nb = (rem % nT) * 32, kb = (rem / nT) * 32;
  int tx = threadIdx.x & 31, ty = threadIdx.x >> 5;
  for (int i = 0; i < 32; i += 8)
    tile[ty + i][tx] = W[(long)(kb + ty + i) * N + nb + tx];
  __syncthreads();
  for (int i = 0; i < 32; i += 8)
    Wt[(long)(nb + ty + i) * 1024 + kb + tx] = f2bf(tile[tx][ty + i]);
}

// ---------------- fused: hs->bf16 + beta/resg GEMV ----------------
__global__ __launch_bounds__(256)
void cvt_beta(const float* __restrict__ hs, unsigned short* __restrict__ hsb,
              const float* __restrict__ Wb, const float* __restrict__ Wres,
              const float* __restrict__ bres,
              float* __restrict__ beta, float* __restrict__ resg) {
  __shared__ float red[4][8];
  long m = blockIdx.x;
  int tid = threadIdx.x;
  int k0 = tid * 4;
  float4 x = *reinterpret_cast<const float4*>(&hs[m * 1024 + k0]);
  ushort4 o;
  o.x = f2bf(x.x); o.y = f2bf(x.y); o.z = f2bf(x.z); o.w = f2bf(x.w);
  *reinterpret_cast<ushort4*>(&hsb[m * 1024 + k0]) = o;
  float xr[4] = {x.x, x.y, x.z, x.w};
  float ab[4] = {0.f, 0.f, 0.f, 0.f}, ar[4] = {0.f, 0.f, 0.f, 0.f};
#pragma unroll
  for (int j = 0; j < 4; ++j) {
    float4 wb = *reinterpret_cast<const float4*>(&Wb[(long)(k0 + j) * 4]);
    float4 wr = *reinterpret_cast<const float4*>(&Wres[(long)(k0 + j) * 4]);
    ab[0] = fmaf(xr[j], wb.x, ab[0]); ab[1] = fmaf(xr[j], wb.y, ab[1]);
    ab[2] = fmaf(xr[j], wb.z, ab[2]); ab[3] = fmaf(xr[j], wb.w, ab[3]);
    ar[0] = fmaf(xr[j], wr.x, ar[0]); ar[1] = fmaf(xr[j], wr.y, ar[1]);
    ar[2] = fmaf(xr[j], wr.z, ar[2]); ar[3] = fmaf(xr[j], wr.w, ar[3]);
  }
#pragma unroll
  for (int st = 32; st > 0; st >>= 1) {
#pragma unroll
    for (int n = 0; n < 4; ++n) { ab[n] += __shfl_xor(ab[n], st); ar[n] += __shfl_xor(ar[n], st); }
  }
  int w = tid >> 6;
  if ((tid & 63) == 0) {
#pragma unroll
    for (int n = 0; n < 4; ++n) { red[w][n] = ab[n]; red[w][n + 4] = ar[n]; }
  }
  __syncthreads();
  if (tid < 8) {
    float s = red[0][tid] + red[1][tid] + red[2][tid] + red[3][tid];
    if (tid < 4) beta[m * 4 + tid] = sigmf(s);
    else resg[m * 4 + tid - 4] = sigmf(s + bres[tid - 4]);
  }
}

// ---------------- fused QKV GEMM: C[8192][3072] -> b0/b1/b2, XCD swizzle ----------------
__global__ __launch_bounds__(256)
void gemm_qkv(const unsigned short* __restrict__ A, const unsigned short* __restrict__ Bt,
              float* __restrict__ C0) {
  __shared__ unsigned short Al[128 * 32];
  __shared__ unsigned short Bl[128 * 32];
  const int K = 1024;
  const int nBn = 24;
  int wgid = blockIdx.x;
  int xcd = wgid & 7;
  int local = wgid >> 3;
  int bm = (xcd * 8 + local / nBn) * 128;
  int bn = (local % nBn) * 128;
  float* Cd = C0 + (long)(bn >> 10) * BLD;
  int cbn = bn & 1023;
  int tid = threadIdx.x;
  int lane = tid & 63, wid = tid >> 6;
  int wr = wid >> 1, wc = wid & 1;
  int l15 = lane & 15, l4 = lane >> 4;
  f32x4 acc[4][4];
#pragma unroll
  for (int i = 0; i < 4; ++i)
#pragma unroll
    for (int j = 0; j < 4; ++j) { acc[i][j].x = 0.f; acc[i][j].y = 0.f; acc[i][j].z = 0.f; acc[i][j].w = 0.f; }
  for (int k0 = 0; k0 < K; k0 += 32) {
    __syncthreads();
#pragma unroll
    for (int i = 0; i < 2; ++i) {
      int idx = tid + i * 256;
      int r = idx >> 2, sl = idx & 3;
      int src = sl ^ ((r >> 1) & 3);
      __builtin_amdgcn_global_load_lds(
          (const __attribute__((address_space(1))) unsigned int*)&A[(long)(bm + r) * K + k0 + src * 8],
          (__attribute__((address_space(3))) unsigned int*)&Al[idx * 8], 16, 0, 0);
      __builtin_amdgcn_global_load_lds(
          (const __attribute__((address_space(1))) unsigned int*)&Bt[(long)(bn + r) * K + k0 + src * 8],
          (__attribute__((address_space(3))) unsigned int*)&Bl[idx * 8], 16, 0, 0);
    }
    __syncthreads();
    bf16x8 af[4], bfr[4];
#pragma unroll
    for (int fi = 0; fi < 4; ++fi) {
      int r = wr * 64 + fi * 16 + l15;
      af[fi] = *reinterpret_cast<const bf16x8*>(&Al[r * 32 + (l4 ^ ((r >> 1) & 3)) * 8]);
    }
#pragma unroll
    for (int fj = 0; fj < 4; ++fj) {
      int r = wc * 64 + fj * 16 + l15;
      bfr[fj] = *reinterpret_cast<const bf16x8*>(&Bl[r * 32 + (l4 ^ ((r >> 1) & 3)) * 8]);
    }
#pragma unroll
    for (int fi = 0; fi < 4; ++fi)
#pragma unroll
      for (int fj = 0; fj < 4; ++fj)
        acc[fi][fj] = __builtin_amdgcn_mfma_f32_16x16x32_bf16(af[fi], bfr[fj], acc[fi][fj], 0, 0, 0);
  }
#pragma unroll
  for (int fi = 0; fi < 4; ++fi) {
    int rb = bm + wr * 64 + fi * 16 + l4 * 4;
#pragma unroll
    for (int fj = 0; fj < 4; ++fj) {
      int cb = cbn + wc * 64 + fj * 16 + l15;
#pragma unroll
      for (int j = 0; j < 4; ++j)
        Cd[(long)(rb + j) * 1024 + cb] = acc[fi][fj][j];
    }
  }
}

// ---------------- fused gate+og GEMM ----------------
__global__ __launch_bounds__(256)
void gemm_gateog(const unsigned short* __restrict__ A, const unsigned short* __restrict__ Bt,
                 float* __restrict__ Cg, float* __restrict__ Cog) {
  __shared__ unsigned short Al[128 * 32];
  __shared__ unsigned short Bl[128 * 32];
  const int K = 1024;
  const int nBn = 12;
  int wgid = blockIdx.x;
  int xcd = wgid & 7;
  int local = wgid >> 3;
  int bm = (xcd * 8 + local / nBn) * 128;
  int bn = (local % nBn) * 128;
  float* Cd; int stride, cbn;
  if (bn < 1024) { Cd = Cg; stride = 1024; cbn = bn; }
  else { Cd = Cog; stride = 512; cbn = bn - 1024; }
  int tid = threadIdx.x;
  int lane = tid & 63, wid = tid >> 6;
  int wr = wid >> 1, wc = wid & 1;
  int l15 = lane & 15, l4 = lane >> 4;
  f32x4 acc[4][4];
#pragma unroll
  for (int i = 0; i < 4; ++i)
#pragma unroll
    for (int j = 0; j < 4; ++j) { acc[i][j].x = 0.f; acc[i][j].y = 0.f; acc[i][j].z = 0.f; acc[i][j].w = 0.f; }
  for (int k0 = 0; k0 < K; k0 += 32) {
    __syncthreads();
#pragma unroll
    for (int i = 0; i < 2; ++i) {
      int idx = tid + i * 256;
      int r = idx >> 2, sl = idx & 3;
      int src = sl ^ ((r >> 1) & 3);
      __builtin_amdgcn_global_load_lds(
          (const __attribute__((address_space(1))) unsigned int*)&A[(long)(bm + r) * K + k0 + src * 8],
          (__attribute__((address_space(3))) unsigned int*)&Al[idx * 8], 16, 0, 0);
      __builtin_amdgcn_global_load_lds(
          (const __attribute__((address_space(1))) unsigned int*)&Bt[(long)(bn + r) * K + k0 + src * 8],
          (__attribute__((address_space(3))) unsigned int*)&Bl[idx * 8], 16, 0, 0);
    }
    __syncthreads();
    bf16x8 af[4], bfr[4];
#pragma unroll
    for (int fi = 0; fi < 4; ++fi) {
      int r = wr * 64 + fi * 16 + l15;
      af[fi] = *reinterpret_cast<const bf16x8*>(&Al[r * 32 + (l4 ^ ((r >> 1) & 3)) * 8]);
    }
#pragma unroll
    for (int fj = 0; fj < 4; ++fj) {
      int r = wc * 64 + fj * 16 + l15;
      bfr[fj] = *reinterpret_cast<const bf16x8*>(&Bl[r * 32 + (l4 ^ ((r >> 1) & 3)) * 8]);
    }
#pragma unroll
    for (int fi = 0; fi < 4; ++fi)
#pragma unroll
      for (int fj = 0; fj < 4; ++fj)
        acc[fi][fj] = __builtin_amdgcn_mfma_f32_16x16x32_bf16(af[fi], bfr[fj], acc[fi][fj], 0, 0, 0);
  }
#pragma unroll
  for (int fi = 0; fi < 4; ++fi) {
    int rb = bm + wr * 64 + fi * 16 + l4 * 4;
#pragma unroll
    for (int fj = 0; fj < 4; ++fj) {
      int cb = cbn + wc * 64 + fj * 16 + l15;
#pragma unroll
      for (int j = 0; j < 4; ++j)
        Cd[(long)(rb + j) * stride + cb] = acc[fi][fj][j];
    }
  }
}

// ---------------- bf16 MFMA GEMM with XCD swizzle (final Wo) ----------------
__global__ __launch_bounds__(256)
void gemm_bf16(const unsigned short* __restrict__ A, const unsigned short* __restrict__ Bt,
               float* __restrict__ C, int N) {
  __shared__ unsigned short Al[128 * 32];
  __shared__ unsigned short Bl[128 * 32];
  const int K = 1024;
  int nBn = N >> 7;
  int wgid = blockIdx.x;
  int xcd = wgid & 7;
  int local = wgid >> 3;
  int bm = (xcd * 8 + local / nBn) * 128;
  int bn = (local % nBn) * 128;
  int tid = threadIdx.x;
  int lane = tid & 63, wid = tid >> 6;
  int wr = wid >> 1, wc = wid & 1;
  int l15 = lane & 15, l4 = lane >> 4;
  f32x4 acc[4][4];
#pragma unroll
  for (int i = 0; i < 4; ++i)
#pragma unroll
    for (int j = 0; j < 4; ++j) { acc[i][j].x = 0.f; acc[i][j].y = 0.f; acc[i][j].z = 0.f; acc[i][j].w = 0.f; }
  for (int k0 = 0; k0 < K; k0 += 32) {
    __syncthreads();
#pragma unroll
    for (int i = 0; i < 2; ++i) {
      int idx = tid + i * 256;
      int r = idx >> 2, sl = idx & 3;
      int src = sl ^ ((r >> 1) & 3);
      __builtin_amdgcn_global_load_lds(
          (const __attribute__((address_space(1))) unsigned int*)&A[(long)(bm + r) * K + k0 + src * 8],
          (__attribute__((address_space(3))) unsigned int*)&Al[idx * 8], 16, 0, 0);
      __builtin_amdgcn_global_load_lds(
          (const __attribute__((address_space(1))) unsigned int*)&Bt[(long)(bn + r) * K + k0 + src * 8],
          (__attribute__((address_space(3))) unsigned int*)&Bl[idx * 8], 16, 0, 0);
    }
    __syncthreads();
    bf16x8 af[4], bfr[4];
#pragma unroll
    for (int fi = 0; fi < 4; ++fi) {
      int r = wr * 64 + fi * 16 + l15;
      af[fi] = *reinterpret_cast<const bf16x8*>(&Al[r * 32 + (l4 ^ ((r >> 1) & 3)) * 8]);
    }
#pragma unroll
    for (int fj = 0; fj < 4; ++fj) {
      int r = wc * 64 + fj * 16 + l15;
      bfr[fj] = *reinterpret_cast<const bf16x8*>(&Bl[r * 32 + (l4 ^ ((r >> 1) & 3)) * 8]);
    }
#pragma unroll
    for (int fi = 0; fi < 4; ++fi)
#pragma unroll
      for (int fj = 0; fj < 4; ++fj)
        acc[fi][fj] = __builtin_amdgcn_mfma_f32_16x16x32_bf16(af[fi], bfr[fj], acc[fi][fj], 0, 0, 0);
  }
#pragma unroll
  for (int fi = 0; fi < 4; ++fi) {
    int rb = bm + wr * 64 + fi * 16 + l4 * 4;
#pragma unroll
    for (int fj = 0; fj < 4; ++fj) {
      int cb = bn + wc * 64 + fj * 16 + l15;
#pragma unroll
      for (int j = 0; j < 4; ++j)
        C[(long)(rb + j) * N + cb] = acc[fi][fj][j];
    }
  }
}

// ---------------- depthwise causal conv body (sliding-window) ----------------
#define CTL 128
template<int K>
__device__ __forceinline__ void dwconv_body(const float* __restrict__ x, const float* __restrict__ w,
                                            float* __restrict__ y, int rem, float* tile, int do_silu) {
  int ct = rem & 15;
  int lt = (rem >> 4) & 31;
  int b  = rem >> 9;
  int c0 = ct * 64;
  int l0 = lt * CTL;
  int tid = threadIdx.x;
  const int rows = CTL + K - 1;
  for (int i = tid; i < rows * 16; i += 256) {
    int rr = i >> 4, c4 = i & 15;
    int l = l0 - (K - 1) + rr;
    float4 v = make_float4(0.f, 0.f, 0.f, 0.f);
    if (l >= 0) v = *reinterpret_cast<const float4*>(&x[((long)b * L_ + l) * D_ + c0 + c4 * 4]);
    *reinterpret_cast<float4*>(&tile[rr * 64 + c4 * 4]) = v;
  }
  __syncthreads();
  int c = tid & 63;
  int wv = tid >> 6;
  float wreg[K];
#pragma unroll
  for (int j = 0; j < K; ++j) wreg[j] = w[(long)(c0 + c) * K + j];
#pragma unroll
  for (int g = 0; g < 4; ++g) {
    int lo_base = g * 32 + wv * 8;
    float win[8];
#pragma unroll
    for (int r = 0; r < 8; ++r) win[r] = tile[(lo_base + r) * 64 + c];
    float acc[8] = {0.f, 0.f, 0.f, 0.f, 0.f, 0.f, 0.f, 0.f};
#pragma unroll
    for (int j = 0; j < K; ++j) {
#pragma unroll
      for (int r = 0; r < 8; ++r) acc[r] = fmaf(wreg[j], win[r], acc[r]);
      if (j < K - 1) {
#pragma unroll
        for (int r = 0; r < 7; ++r) win[r] = win[r + 1];
        win[7] = tile[(lo_base + j + 8) * 64 + c];
      }
    }
#pragma unroll
    for (int r = 0; r < 8; ++r) {
      float v = acc[r];
      if (do_silu) v = v * sigmf(v);
      y[((long)b * L_ + l0 + lo_base + r) * D_ + c0 + c] = v;
    }
  }
}

// ---------------- merged QKV convs (3072 blocks, disjoint outputs) ----------------
__global__ __launch_bounds__(256)
void dwconv_qkv(const float* __restrict__ xq, const float* __restrict__ xk,
                const float* __restrict__ xv,
                const float* __restrict__ wq, const float* __restrict__ wk,
                const float* __restrict__ wv,
                float* __restrict__ yq, float* __restrict__ yk, float* __restrict__ yv) {
  __shared__ float tile[(CTL + 3) * 64];
  int bid = blockIdx.x;
  int sel = bid >> 10, rem = bid & 1023;
  const float* x = (sel == 0) ? xq : (sel == 1) ? xk : xv;
  const float* w = (sel == 0) ? wq : (sel == 1) ? wk : wv;
  float* y = (sel == 0) ? yq : (sel == 1) ? yk : yv;
  dwconv_body<4>(x, w, y, rem, tile, 1);
}

// ---------------- merged fir convs (2048 blocks) ----------------
__global__ __launch_bounds__(256)
void dwconv_fir(const float* __restrict__ v, const float* __restrict__ wl,
                const float* __restrict__ ws5, float* __restrict__ yl, float* __restrict__ ys) {
  __shared__ float tile[(CTL + 63) * 64];
  int bid = blockIdx.x;
  if (bid < 1024) dwconv_body<64>(v, wl, yl, bid, tile, 0);
  else dwconv_body<5>(v, ws5, ys, bid - 1024, tile, 0);
}

// ---------------- per-chunk: l2norm (fused) + inv + u + bf16 scan operands ----------------
// Takes RAW conv outputs; computes per-row q/k norms in-kernel and scales dots post-hoc:
// (k_hat_i . k_hat_j) = knorm_i*knorm_j*(k_i.k_j) -- mathematically identical to ref order.
__global__ __launch_bounds__(256)
void chunk_uw(const float* __restrict__ qn, const float* __restrict__ kn,
              const float* __restrict__ v, const float* __restrict__ beta,
              float* __restrict__ u,
              unsigned short* __restrict__ q_bf, unsigned short* __restrict__ w_bf,
              unsigned short* __restrict__ kT_bf, unsigned short* __restrict__ at_bf) {
  __shared__ float skT[256][33];
  __shared__ float sinv[32][33];
  __shared__ float sbeta[32];
  __shared__ float knorm[32], qnorm[32];
  int blk = blockIdx.x;
  int ci = blk % NCH;
  int bh = blk / NCH;
  int h = bh % H_;
  int b = bh / H_;
  long base = ((long)b * L_ + (long)ci * CHUNKSZ) * D_ + h * DH;
  long brow = (long)b * L_ + (long)ci * CHUNKSZ;
  long obase = (long)blk * 8192;
  int tid = threadIdx.x;
  for (int i = tid; i < 32 * 256; i += 256) {
    int r = i >> 8, c = i & 255;
    skT[c][r] = kn[base + (long)r * D_ + c];
  }
  if (tid < 32) sbeta[tid] = beta[(brow + tid) * H_ + h];
  __syncthreads();
  // per-row norms: 8 lanes per row (lanes contiguous within wave)
  {
    int row = tid >> 3, seg = tid & 7;
    float s = 0.f;
    for (int c2 = seg * 32; c2 < seg * 32 + 32; ++c2) { float xv = skT[c2][row]; s = fmaf(xv, xv, s); }
    s += __shfl_xor(s, 1); s += __shfl_xor(s, 2); s += __shfl_xor(s, 4);
    if (seg == 0) knorm[row] = rsqrtf(s + 1e-6f);
    const float* qr = qn + base + (long)row * D_;
    float sq = 0.f;
    for (int c2 = seg * 32; c2 < seg * 32 + 32; ++c2) { float xv = qr[c2]; sq = fmaf(xv, xv, sq); }
    sq += __shfl_xor(sq, 1); sq += __shfl_xor(sq, 2); sq += __shfl_xor(sq, 4);
    if (seg == 0) qnorm[row] = rsqrtf(sq + 1e-6f);
  }
  __syncthreads();
  for (int i = tid; i < 8192; i += 256)
    kT_bf[obase + i] = f2bf(skT[i >> 5][i & 31] * knorm[i & 31]);
  for (int i = tid; i < 8192; i += 256) {
    int r = i >> 8, c = i & 255;
    q_bf[obase + i] = f2bf(qn[base + (long)r * D_ + c] * qnorm[r]);
  }
  int j = tid & 31, i0 = tid >> 5;
  for (int r = 0; r < 4; ++r) {
    int i = i0 + (r << 3);
    float acc = 0.f;
    for (int d = 0; d < 256; ++d) acc += skT[d][i] * skT[d][j];
    sinv[i][j] = (i > j) ? -acc * knorm[i] * knorm[j] * sbeta[i] : 0.f;
  }
  __syncthreads();
  for (int i = 1; i < 32; ++i) {
    float val = 0.f;
    if (tid < 32) {
      for (int t = 0; t < i; ++t) val += sinv[i][t] * sinv[t][tid];
    }
    __syncthreads();
    if (tid < 32) sinv[i][tid] += val;
    __syncthreads();
  }
  if (tid < 32) sinv[tid][tid] += 1.f;
  long abase = (long)blk * 1024;
  for (int r = 0; r < 4; ++r) {
    int i = i0 + (r << 3);
    const float* qrow = qn + base + (long)i * D_;
    float acc = 0.f;
    for (int d = 0; d < 256; ++d) acc += qrow[d] * skT[d][j];
    at_bf[abase + i * 32 + j] = f2bf((i >= j) ? acc * qnorm[i] * knorm[j] : 0.f);
  }
  __syncthreads();
  int c = tid;
  float vt[32], kt[32];
#pragma unroll
  for (int t = 0; t < 32; ++t) {
    vt[t] = v[base + t * D_ + c] * sbeta[t];
    kt[t] = skT[c][t] * knorm[t] * sbeta[t];
  }
#pragma unroll
  for (int i2 = 0; i2 < 32; ++i2) {
    float au = 0.f, aw = 0.f;
#pragma unroll
    for (int t = 0; t <= i2; ++t) {
      float f = sinv[i2][t];
      au += f * vt[t];
      aw += f * kt[t];
    }
    u[base + i2 * D_ + c] = au;
    w_bf[obase + i2 * 256 + c] = f2bf(aw);
  }
}

// ---------------- MFMA scan: 128 blocks x 1 wave, barrier-free ----------------
__global__ __launch_bounds__(64, 1)
void delta_scan(const unsigned short* __restrict__ qb, const unsigned short* __restrict__ wbf,
                const unsigned short* __restrict__ ktb, const unsigned short* __restrict__ atb,
                const float* __restrict__ u, float* __restrict__ out) {
  __shared__ unsigned short sB[16 * 264];
  __shared__ unsigned short su2[16 * 40];
  int blk = blockIdx.x;
  int bh = blk & 7, cg = blk >> 3;
  int h = bh & 3, b = bh >> 2;
  int lane = threadIdx.x;
  int l15 = lane & 15, l4 = lane >> 4;
  int colw = cg * 16;

  f32x4 zero4; zero4.x = 0.f; zero4.y = 0.f; zero4.z = 0.f; zero4.w = 0.f;
  f32x4 acc[16];
#pragma unroll
  for (int t = 0; t < 16; ++t) acc[t] = zero4;

  uint4 wf[2][8];
  float ru[2][4];
  uint4 qf[2][8];
  uint4 kfa[8], kfb[8];
  uint4 af[2];

#define LOAD_W(CI) do {                                                          \
    long o8_ = ((long)bh * NCH + (CI)) * 8192;                                   \
    _Pragma("unroll")                                                            \
    for (int m_ = 0; m_ < 2; ++m_)                                               \
      _Pragma("unroll")                                                          \
      for (int kc_ = 0; kc_ < 8; ++kc_)                                          \
        wf[m_][kc_] = *reinterpret_cast<const uint4*>(                           \
            &wbf[o8_ + (16 * m_ + l15) * 256 + kc_ * 32 + l4 * 8]);              \
  } while (0)

#define LOAD_U(CI) do {                                                          \
    long ub_ = ((long)b * L_ + (long)(CI) * CHUNKSZ) * D_ + h * DH + colw;       \
    _Pragma("unroll")                                                            \
    for (int m_ = 0; m_ < 2; ++m_)                                               \
      _Pragma("unroll")                                                          \
      for (int r_ = 0; r_ < 4; ++r_)                                             \
        ru[m_][r_] = u[ub_ + (long)(16 * m_ + 4 * l4 + r_) * D_ + l15];          \
  } while (0)

#define LOAD_Q(CI) do {                                                          \
    long o8_ = ((long)bh * NCH + (CI)) * 8192;                                   \
    _Pragma("unroll")                                                            \
    for (int m_ = 0; m_ < 2; ++m_)                                               \
      _Pragma("unroll")                                                          \
      for (int kc_ = 0; kc_ < 8; ++kc_)                                          \
        qf[m_][kc_] = *reinterpret_cast<const uint4*>(                           \
            &qb[o8_ + (16 * m_ + l15) * 256 + kc_ * 32 + l4 * 8]);               \
  } while (0)

#define LOAD_KA(CI) do {                                                         \
    long o8_ = ((long)bh * NCH + (CI)) * 8192;                                   \
    _Pragma("unroll")                                                            \
    for (int dt_ = 0; dt_ < 8; ++dt_)                                            \
      kfa[dt_] = *reinterpret_cast<const uint4*>(                                \
          &ktb[o8_ + (16 * dt_ + l15) * 32 + l4 * 8]);                           \
  } while (0)

#define LOAD_KB(CI) do {                                                         \
    long o8_ = ((long)bh * NCH + (CI)) * 8192;                                   \
    _Pragma("unroll")                                                            \
    for (int dt_ = 0; dt_ < 8; ++dt_)                                            \
      kfb[dt_] = *reinterpret_cast<const uint4*>(                                \
          &ktb[o8_ + (16 * (dt_ + 8) + l15) * 32 + l4 * 8]);                     \
  } while (0)

#define LOAD_A(CI) do {                                                          \
    long oa_ = ((long)bh * NCH + (CI)) * 1024;                                   \
    _Pragma("unroll")                                                            \
    for (int m_ = 0; m_ < 2; ++m_)                                               \
      af[m_] = *reinterpret_cast<const uint4*>(                                  \
          &atb[oa_ + (16 * m_ + l15) * 32 + l4 * 8]);                            \
  } while (0)

#define SCAN_BODY(CI, PF) do {                                                   \
    long ub = ((long)b * L_ + (long)(CI) * CHUNKSZ) * D_ + h * DH + colw;        \
    _Pragma("unroll")                                                            \
    for (int dt = 0; dt < 16; ++dt) {                                            \
      uint2 pv;                                                                  \
      pv.x = pk2bf(acc[dt].x, acc[dt].y);                                        \
      pv.y = pk2bf(acc[dt].z, acc[dt].w);                                        \
      *reinterpret_cast<uint2*>(&sB[l15 * 264 + dt * 16 + l4 * 4]) = pv;         \
    }                                                                            \
    bf16x8 sf[8];                                                                \
    _Pragma("unroll")                                                            \
    for (int kc = 0; kc < 8; ++kc)                                               \
      sf[kc] = *reinterpret_cast<const bf16x8*>(&sB[l15 * 264 + kc * 32 + l4 * 8]); \
    f32x4 wa[2][2];                                                              \
    wa[0][0] = zero4; wa[0][1] = zero4; wa[1][0] = zero4; wa[1][1] = zero4;      \
    _Pragma("unroll")                                                            \
    for (int kc = 0; kc < 8; ++kc) {                                             \
      _Pragma("unroll")                                                          \
      for (int m = 0; m < 2; ++m)                                                \
        wa[m][kc & 1] = __builtin_amdgcn_mfma_f32_16x16x32_bf16(                 \
            *reinterpret_cast<bf16x8*>(&wf[m][kc]), sf[kc], wa[m][kc & 1], 0, 0, 0); \
    }                                                                            \
    if (PF) LOAD_W((CI) + 1);                                                    \
    _Pragma("unroll")                                                            \
    for (int m = 0; m < 2; ++m) {                                                \
      f32x4 wsum = wa[m][0] + wa[m][1];                                          \
      uint2 pv;                                                                  \
      pv.x = pk2bf(ru[m][0] - wsum.x, ru[m][1] - wsum.y);                        \
      pv.y = pk2bf(ru[m][2] - wsum.z, ru[m][3] - wsum.w);                        \
      *reinterpret_cast<uint2*>(&su2[l15 * 40 + m * 16 + l4 * 4]) = pv;          \
    }                                                                            \
    if (PF) LOAD_U((CI) + 1);                                                    \
    bf16x8 u2f = *reinterpret_cast<const bf16x8*>(&su2[l15 * 40 + l4 * 8]);      \
    _Pragma("unroll")                                                            \
    for (int dt = 0; dt < 8; ++dt)                                               \
      acc[dt] = __builtin_amdgcn_mfma_f32_16x16x32_bf16(                         \
          *reinterpret_cast<bf16x8*>(&kfa[dt]), u2f, acc[dt], 0, 0, 0);          \
    if (PF) LOAD_KA((CI) + 1);                                                   \
    _Pragma("unroll")                                                            \
    for (int dt = 0; dt < 8; ++dt)                                               \
      acc[dt + 8] = __builtin_amdgcn_mfma_f32_16x16x32_bf16(                     \
          *reinterpret_cast<bf16x8*>(&kfb[dt]), u2f, acc[dt + 8], 0, 0, 0);      \
    if (PF) LOAD_KB((CI) + 1);                                                   \
    f32x4 qa[2][2];                                                              \
    qa[0][0] = zero4; qa[0][1] = zero4; qa[1][0] = zero4; qa[1][1] = zero4;      \
    _Pragma("unroll")                                                            \
    for (int kc = 0; kc < 8; ++kc) {                                             \
      _Pragma("unroll")                                                          \
      for (int m = 0; m < 2; ++m)                                                \
        qa[m][kc & 1] = __builtin_amdgcn_mfma_f32_16x16x32_bf16(                 \
            *reinterpret_cast<bf16x8*>(&qf[m][kc]), sf[kc], qa[m][kc & 1], 0, 0, 0); \
    }                                                                            \
    if (PF) LOAD_Q((CI) + 1);                                                    \
    _Pragma("unroll")                                                            \
    for (int m = 0; m < 2; ++m) {                                                \
      f32x4 qacc = qa[m][0] + qa[m][1];                                          \
      f32x4 dv = __builtin_amdgcn_mfma_f32_16x16x32_bf16(                        \
          *reinterpret_cast<bf16x8*>(&af[m]), u2f, qacc, 0, 0, 0);               \
      _Pragma("unroll")                                                          \
      for (int r = 0; r < 4; ++r)                                                \
        out[ub + (long)(16 * m + 4 * l4 + r) * D_ + l15] = dv[r];                \
    }                                                                            \
    if (PF) LOAD_A((CI) + 1);                                                    \
  } while (0)

  LOAD_W(0); LOAD_U(0); LOAD_Q(0); LOAD_KA(0); LOAD_KB(0); LOAD_A(0);

  for (int ci = 0; ci < NCH - 1; ++ci) {
    SCAN_BODY(ci, 1);
  }
  SCAN_BODY(NCH - 1, 0);

#undef LOAD_W
#undef LOAD_U
#undef LOAD_Q
#undef LOAD_KA
#undef LOAD_KB
#undef LOAD_A
#undef SCAN_BODY
}

// ---------------- fused head stats x4 tensors ----------------
__global__ __launch_bounds__(256)
void head_stats4(const float* __restrict__ t0, const float* __restrict__ t1,
                 const float* __restrict__ t2, const float* __restrict__ t3,
                 float* __restrict__ outp) {
  long bl = blockIdx.x;
  int w = threadIdx.x >> 6, lane = threadIdx.x & 63;
  const float* x = (w == 0) ? t0 : (w == 1) ? t1 : (w == 2) ? t2 : t3;
  float m = 0.f, vv = 0.f, am = 0.f, l2 = 0.f;
#pragma unroll
  for (int h = 0; h < 4; ++h) {
    float4 v = *reinterpret_cast<const float4*>(&x[bl * 1024 + h * 256 + lane * 4]);
    float s = v.x + v.y + v.z + v.w;
    float q = v.x * v.x + v.y * v.y + v.z * v.z + v.w * v.w;
    float a = fabsf(v.x) + fabsf(v.y) + fabsf(v.z) + fabsf(v.w);
#pragma unroll
    for (int st = 32; st > 0; st >>= 1) {
      s += __shfl_xor(s, st); q += __shfl_xor(q, st); a += __shfl_xor(a, st);
    }
    float mean = s * (1.f / 256.f);
    m += mean;
    vv += q * (1.f / 256.f) - mean * mean;
    am += a * (1.f / 256.f);
    l2 += sqrtf(q);
  }
  if (lane == 0) {
    float* o = outp + bl * 16 + w * 4;
    o[0] = m * 0.25f; o[1] = vv * 0.25f; o[2] = am * 0.25f; o[3] = l2 * 0.25f;
  }
}

// ---------------- gate fused ----------------
__global__ __launch_bounds__(256)
void gate_fused(const float* __restrict__ g, const float* __restrict__ stats,
                const float* __restrict__ Wg1t, const float* __restrict__ bg1,
                const float* __restrict__ Wg2, const float* __restrict__ bg2,
                const float* __restrict__ temp_in, float* __restrict__ p) {
  __shared__ float red[4][4];
  long m = blockIdx.x;
  int tid = threadIdx.x;
  int c0 = tid * 4;
  float4 gv = *reinterpret_cast<const float4*>(&g[m * 1024 + c0]);
  float st[16];
#pragma unroll
  for (int k = 0; k < 16; ++k) st[k] = stats[m * 16 + k];
  float la[4] = {0.f, 0.f, 0.f, 0.f};
  float gvv[4] = {gv.x, gv.y, gv.z, gv.w};
#pragma unroll
  for (int j = 0; j < 4; ++j) {
    int c = c0 + j;
    float s = gvv[j] + bg1[c];
#pragma unroll
    for (int k = 0; k < 16; ++k) s += st[k] * Wg1t[(long)k * 1024 + c];
    float ge = geluf(s);
#pragma unroll
    for (int n = 0; n < 4; ++n) la[n] += ge * Wg2[c * 4 + n];
  }
#pragma unroll
  for (int stp = 32; stp > 0; stp >>= 1)
#pragma unroll
    for (int n = 0; n < 4; ++n) la[n] += __shfl_xor(la[n], stp);
  int w = tid >> 6;
  if ((tid & 63) == 0) {
#pragma unroll
    for (int n = 0; n < 4; ++n) red[w][n] = la[n];
  }
  __syncthreads();
  if (tid == 0) {
    float temp = log1pf(expf(temp_in[0]));
    float l[4];
#pragma unroll
    for (int n = 0; n < 4; ++n)
      l[n] = (red[0][n] + red[1][n] + red[2][n] + red[3][n] + bg2[n]) / temp;
    float mx = fmaxf(fmaxf(l[0], l[1]), fmaxf(l[2], l[3]));
    float e[4], s = 0.f;
#pragma unroll
    for (int n = 0; n < 4; ++n) { e[n] = expf(l[n] - mx); s += e[n]; }
    float s2 = 0.f;
#pragma unroll
    for (int n = 0; n < 4; ++n) { e[n] = fmaxf(e[n] / s, 0.02f); s2 += e[n]; }
#pragma unroll
    for (int n = 0; n < 4; ++n) p[m * 4 + n] = e[n] / s2;
  }
}

// ---------------- combine + og stats fused ----------------
__global__ __launch_bounds__(256)
void combine_ogstats(const float* __restrict__ ls, const float* __restrict__ ll,
                     const float* __restrict__ dd, const float* __restrict__ vd,
                     const float* __restrict__ p, const float* __restrict__ resg,
                     const float* __restrict__ crl, float* __restrict__ o,
                     float* __restrict__ og8) {
  __shared__ float part[4][8];
  long bl = blockIdx.x;
  int h = threadIdx.x >> 6, lane = threadIdx.x & 63;
  long base = bl * 1024 + h * 256 + lane * 4;
  float4 lsv = *reinterpret_cast<const float4*>(&ls[base]);
  float4 llv = *reinterpret_cast<const float4*>(&ll[base]);
  float4 ddv = *reinterpret_cast<const float4*>(&dd[base]);
  float4 vdv = *reinterpret_cast<const float4*>(&vd[base]);
  float p0 = p[bl * 4 + 0], p1 = p[bl * 4 + 1], p2 = p[bl * 4 + 2], p3 = p[bl * 4 + 3];
  float sg = sigmf(crl[h]) * resg[bl * 4 + h];
  float c0 = p0 + sg;
  float4 ov;
  ov.x = c0 * lsv.x + p1 * llv.x + p2 * ddv.x + p3 * vdv.x;
  ov.y = c0 * lsv.y + p1 * llv.y + p2 * ddv.y + p3 * vdv.y;
  ov.z = c0 * lsv.z + p1 * llv.z + p2 * ddv.z + p3 * vdv.z;
  ov.w = c0 * lsv.w + p1 * llv.w + p2 * ddv.w + p3 * vdv.w;
  *reinterpret_cast<float4*>(&o[base]) = ov;
  float s = ov.x + ov.y + ov.z + ov.w;
  float q = ov.x * ov.x + ov.y * ov.y + ov.z * ov.z + ov.w * ov.w;
  float a = fabsf(ov.x) + fabsf(ov.y) + fabsf(ov.z) + fabsf(ov.w);
  float sv = vdv.x + vdv.y + vdv.z + vdv.w;
  float qv = vdv.x * vdv.x + vdv.y * vdv.y + vdv.z * vdv.z + vdv.w * vdv.w;
  float av = fabsf(vdv.x) + fabsf(vdv.y) + fabsf(vdv.z) + fabsf(vdv.w);
#pragma unroll
  for (int st = 32; st > 0; st >>= 1) {
    s += __shfl_xor(s, st); q += __shfl_xor(q, st); a += __shfl_xor(a, st);
    sv += __shfl_xor(sv, st); qv += __shfl_xor(qv, st); av += __shfl_xor(av, st);
  }
  if (lane == 0) {
    float mo = s * (1.f / 256.f), mv = sv * (1.f / 256.f);
    part[h][0] = mo; part[h][1] = q * (1.f / 256.f) - mo * mo;
    part[h][2] = a * (1.f / 256.f); part[h][3] = sqrtf(q);
    part[h][4] = mv; part[h][5] = qv * (1.f / 256.f) - mv * mv;
    part[h][6] = av * (1.f / 256.f); part[h][7] = sqrtf(qv);
  }
  __syncthreads();
  if (threadIdx.x < 8) {
    int t = threadIdx.x;
    og8[bl * 8 + t] = 0.25f * (part[0][t] + part[1][t] + part[2][t] + part[3][t]);
  }
}

// ---------------- og gate fused ----------------
__global__ __launch_bounds__(256)
void og_gate_fused(const float* __restrict__ g, const float* __restrict__ og8,
                   const float* __restrict__ Wog1t, const float* __restrict__ bog1,
                   const float* __restrict__ Wog2, const float* __restrict__ bog2,
                   float* __restrict__ ogv) {
  __shared__ float red[4];
  long m = blockIdx.x;
  int tid = threadIdx.x;
  int c0 = tid * 2;
  float2 gv = *reinterpret_cast<const float2*>(&g[m * 512 + c0]);
  float st[8];
#pragma unroll
  for (int k = 0; k < 8; ++k) st[k] = og8[m * 8 + k];
  float a = 0.f;
  float gvv[2] = {gv.x, gv.y};
#pragma unroll
  for (int j = 0; j < 2; ++j) {
    int c = c0 + j;
    float s = gvv[j] + bog1[c];
#pragma unroll
    for (int k = 0; k < 8; ++k) s += st[k] * Wog1t[(long)k * 512 + c];
    a += geluf(s) * Wog2[c];
  }
#pragma unroll
  for (int stp = 32; stp > 0; stp >>= 1) a += __shfl_xor(a, stp);
  int w = tid >> 6;
  if ((tid & 63) == 0) red[w] = a;
  __syncthreads();
  if (tid == 0) ogv[m] = sigmf(red[0] + red[1] + red[2] + red[3] + bog2[0]);
}

// ---------------- wave-parallel scale+rmsnorm -> bf16 ----------------
__global__ __launch_bounds__(256)
void scale_rmsnorm_bf16(const float* __restrict__ o, const float* __restrict__ og,
                        const float* __restrict__ nw, unsigned short* __restrict__ xb) {
  long row = (long)blockIdx.x * 4 + (threadIdx.x >> 6);
  long bl = row >> 2;
  int lane = threadIdx.x & 63;
  float g = og[bl];
  float4 v = *reinterpret_cast<const float4*>(&o[row * 256 + lane * 4]);
  v.x *= g; v.y *= g; v.z *= g; v.w *= g;
  float q = v.x * v.x + v.y * v.y + v.z * v.z + v.w * v.w;
#pragma unroll
  for (int st = 32; st > 0; st >>= 1) q += __shfl_xor(q, st);
  float scale = rsqrtf(q * (1.f / 256.f) + 1e-5f);
  float4 w4 = *reinterpret_cast<const float4*>(&nw[lane * 4]);
  ushort4 r;
  r.x = f2bf(v.x * scale * w4.x);
  r.y = f2bf(v.y * scale * w4.y);
  r.z = f2bf(v.z * scale * w4.z);
  r.w = f2bf(v.w * scale * w4.w);
  *reinterpret_cast<ushort4*>(&xb[row * 256 + lane * 4]) = r;
}

extern "C" void kernel_launch(void* const* d_in, const int* in_sizes, int n_in,
                              void* d_out, int out_size, void* d_ws, size_t ws_size,
                              hipStream_t stream) {
  const float* hs       = (const float*)d_in[0];
  const float* Wq       = (const float*)d_in[1];
  const float* Wk       = (const float*)d_in[2];
  const float* Wv       = (const float*)d_in[3];
  const float* Wb       = (const float*)d_in[4];
  const float* wq_conv  = (const float*)d_in[5];
  const float* wk_conv  = (const float*)d_in[6];
  const float* wv_conv  = (const float*)d_in[7];
  const float* fir_long = (const float*)d_in[8];
  const float* fir_short= (const float*)d_in[9];
  const float* Wg1      = (const float*)d_in[10];
  const float* bg1      = (const float*)d_in[11];
  const float* Wg2      = (const float*)d_in[12];
  const float* bg2      = (const float*)d_in[13];
  const float* logit_temp     = (const float*)d_in[14];
  const float* conv_res_logit = (const float*)d_in[15];
  const float* Wres     = (const float*)d_in[16];
  const float* bres     = (const float*)d_in[17];
  const float* Wog1     = (const float*)d_in[18];
  const float* bog1     = (const float*)d_in[19];
  const float* Wog2     = (const float*)d_in[20];
  const float* bog2     = (const float*)d_in[21];
  const float* norm_w   = (const float*)d_in[22];
  const float* Wo       = (const float*)d_in[23];
  float* out = (float*)d_out;
  float* ws = (float*)d_ws;

  // b0: qlin -> w_bf(bf16) -> o_mix ; b1: klin -> local_short ; b2: vlin -> u -> delta_out
  // b3: q_in(raw) -> local_long ; b4: k_in(raw) -> gate_hidden ; out: v_in scratch -> final
  float* b0 = ws;
  float* b1 = ws + 1L * BLD;
  float* b2 = ws + 2L * BLD;
  float* b3 = ws + 3L * BLD;
  float* b4 = ws + 4L * BLD;
  float* sm = ws + 5L * BLD;
  float* beta    = sm;
  float* resg    = beta + BL * H_;
  float* stats16 = resg + BL * H_;
  float* og8     = stats16 + BL * 16;
  float* logits  = og8 + BL * 8;
  float* pbuf    = logits + BL * 4;
  float* ogv     = pbuf + BL * 4;
  unsigned short* q_bfg  = (unsigned short*)(ogv + BL);
  unsigned short* kT_bfg = q_bfg + (long)BLD;
  unsigned short* at_bfg = kT_bfg + (long)BLD;
  unsigned short* hsb  = at_bfg + 1024L * 1024;
  unsigned short* wtq  = hsb + (long)BLD;
  unsigned short* wtk  = wtq + 1024L * 1024;
  unsigned short* wtv  = wtk + 1024L * 1024;
  unsigned short* wtg1 = wtv + 1024L * 1024;
  unsigned short* wtog1= wtg1 + 1024L * 1024;
  unsigned short* wto  = wtog1 + 512L * 1024;
  unsigned short* w_bfg = (unsigned short*)b0;   // w_bf in b0 (qlin dead after conv)
  unsigned short* xb    = q_bfg;
  float* ogh = (float*)q_bfg;                    // og hidden f32 in q_bf region
  float* vsc = out;                              // v_in lives in d_out until combine

  size_t needed = (5L * BLD + BL * 41) * 4
                + (3L * BLD + 1024L * 1024 + 5L * 1024 * 1024 + 512L * 1024) * 2;
  if (ws_size < needed) return;

  dim3 blk(256);
  // 0. weight transposes + hs->bf16/beta/resg
  wconv_all<<<5632, blk, 0, stream>>>(Wq, Wk, Wv, Wg1, Wog1, Wo, wtq, wtk, wtv, wtg1, wtog1, wto);
  cvt_beta<<<BL, blk, 0, stream>>>(hs, hsb, Wb, Wres, bres, beta, resg);
  // 1. QKV projections (one launch)
  gemm_qkv<<<1536, blk, 0, stream>>>(hsb, wtq, b0);
  // 2. QKV convs (one launch, disjoint outputs: q->b3, k->b4, v->out scratch)
  dwconv_qkv<<<3072, blk, 0, stream>>>(b0, b1, b2, wq_conv, wk_conv, wv_conv, b3, b4, vsc);
  // 3-4. delta rule (l2norm fused into chunk_uw; u->b2; scan in-place)
  chunk_uw<<<B_ * H_ * NCH, blk, 0, stream>>>(b3, b4, vsc, beta, b2, q_bfg, w_bfg, kT_bfg, at_bfg);
  delta_scan<<<128, dim3(64), 0, stream>>>(q_bfg, w_bfg, kT_bfg, at_bfg, b2, b2);
  // 5. fir convs (one launch: long->b3, short->b1)
  dwconv_fir<<<2048, blk, 0, stream>>>(vsc, fir_long, fir_short, b3, b1);
  // 6. stats16 (ls=b1, ll=b3, dd=b2, vd=vsc)
  head_stats4<<<BL, blk, 0, stream>>>(b1, b3, b2, vsc, stats16);
  // 7. gate + og hidden GEMMs (one launch: gate->b4, og hidden->ogh)
  gemm_gateog<<<768, blk, 0, stream>>>(hsb, wtg1, b4, ogh);
  gate_fused<<<BL, blk, 0, stream>>>(b4, stats16, Wg1 + 1024L * 1024, bg1, Wg2, bg2, logit_temp, pbuf);
  // 8. combine + og stats -> o in b0 (w_bf dead after scan)
  combine_ogstats<<<BL, blk, 0, stream>>>(b1, b3, b2, vsc, pbuf, resg, conv_res_logit, b0, og8);
  // 9. og gate
  og_gate_fused<<<BL, blk, 0, stream>>>(ogh, og8, Wog1 + 1024L * 512, bog1, Wog2, bog2, ogv);
  // 10. scale + rmsnorm -> bf16 (overwrites ogh region, already consumed)
  scale_rmsnorm_bf16<<<BL * H_ / 4, blk, 0, stream>>>(b0, ogv, norm_w, xb);
  // 11. final projection (overwrites out; v scratch dead after combine)
  gemm_bf16<<<512, blk, 0, stream>>>(xb, wto, out, 1024);
}